// Round 3
// baseline (27462.637 us; speedup 1.0000x reference)
//
#include <hip/hip_runtime.h>
#include <stdint.h>

#define BB 4
#define NN 9216
#define CC 384
#define HH 8
#define DH 48
#define EE 4
#define N3 3072
#define MAXTOT 960

typedef unsigned long long u64;

// ---------------- wave helpers (wave64) ----------------
__device__ __forceinline__ float wave_sum(float v){
#pragma unroll
  for(int m=32;m>0;m>>=1) v += __shfl_xor(v,m,64);
  return v;
}
__device__ __forceinline__ double wave_sum_d(double v){
#pragma unroll
  for(int m=32;m>0;m>>=1) v += __shfl_xor(v,m,64);
  return v;
}
__device__ __forceinline__ u64 wave_min_u64(u64 k){
#pragma unroll
  for(int m=32;m>0;m>>=1){
    unsigned lo = __shfl_xor((unsigned)k, m, 64);
    unsigned hi = __shfl_xor((unsigned)(k>>32), m, 64);
    u64 o = ((u64)hi<<32)|lo;
    if(o < k) k = o;
  }
  return k;
}
__device__ __forceinline__ u64 wave_max_u64(u64 k){
#pragma unroll
  for(int m=32;m>0;m>>=1){
    unsigned lo = __shfl_xor((unsigned)k, m, 64);
    unsigned hi = __shfl_xor((unsigned)(k>>32), m, 64);
    u64 o = ((u64)hi<<32)|lo;
    if(o > k) k = o;
  }
  return k;
}

// exact f64 distance between token rows i,j of xr (f32 storage promoted)
__device__ double dist64(const float* __restrict__ xr, int i, int j){
  const float* a = xr + (size_t)i*CC;
  const float* b = xr + (size_t)j*CC;
  double s = 0.0;
  for(int c=0;c<CC;c++){
    double d = (double)a[c] - (double)b[c];
    s += d*d;
  }
  if(!(s > 0.0)) return 0.0;
  return sqrt(s) / 19.595917942265423;   // / sqrt(384), double
}

// ---------------- JAX threefry2x32 (20 rounds), bit-exact ----------------
__device__ __forceinline__ void threefry(uint32_t k0, uint32_t k1, uint32_t x0, uint32_t x1,
                                         uint32_t& o0, uint32_t& o1){
  const uint32_t ks0=k0, ks1=k1, ks2=k0^k1^0x1BD11BDAu;
  const int rotA[4]={13,15,26,6}, rotB[4]={17,29,16,24};
  x0 += ks0; x1 += ks1;
#pragma unroll
  for(int g=0; g<5; g++){
    const int* rot = (g&1)? rotB : rotA;
#pragma unroll
    for(int i=0;i<4;i++){
      x0 += x1;
      x1 = (x1<<rot[i])|(x1>>(32-rot[i]));
      x1 ^= x0;
    }
    uint32_t a = (g%3==0)?ks1:((g%3==1)?ks2:ks0);          // ks[(g+1)%3]
    uint32_t b = (g%3==0)?ks2:((g%3==1)?ks0:ks1);          // ks[(g+2)%3]
    x0 += a; x1 += b + (uint32_t)(g+1);
  }
  o0=x0; o1=x1;
}

// ---------------- score (f64) + sort keys ----------------
__global__ void k_score(const float* __restrict__ x, const float* __restrict__ sw,
                        const float* __restrict__ sb, double* __restrict__ score_d,
                        u64* __restrict__ keys){
  int row = blockIdx.x*4 + (threadIdx.x>>6);
  int lane = threadIdx.x & 63;
  const float* xr = x + (size_t)row*CC;
  double s = 0.0;
  for(int c=lane;c<CC;c+=64) s += (double)xr[c]*(double)sw[c];
  s = wave_sum_d(s);
  if(lane==0){
    double sc = exp(s + (double)sb[0]);    // > 0 -> double bits monotone
    score_d[row] = sc;
    keys[row] = (u64)__double_as_longlong(sc);
  }
}

// rank = stable-ascending position (score asc, index asc)
__global__ void k_rank(const u64* __restrict__ keys, const double* __restrict__ score_d,
                       int* __restrict__ order, double* __restrict__ ss_d,
                       float* __restrict__ ss_f){
  int b = blockIdx.y;
  int i = blockIdx.x*256 + threadIdx.x;
  __shared__ u64 tile[256];
  u64 ki = keys[(size_t)b*NN + i];
  int rank = 0;
  for(int j0=0;j0<NN;j0+=256){
    tile[threadIdx.x] = keys[(size_t)b*NN + j0 + threadIdx.x];
    __syncthreads();
#pragma unroll 8
    for(int jj=0;jj<256;jj++){
      u64 kj = tile[jj]; int j=j0+jj;
      rank += (kj < ki) || (kj == ki && j < i);
    }
    __syncthreads();
  }
  double sd = score_d[(size_t)b*NN + i];
  order[(size_t)b*NN + rank] = i;
  ss_d[(size_t)b*NN + rank] = sd;
  ss_f[(size_t)b*NN + rank] = (float)sd;
}

__global__ void k_gather(const float* __restrict__ x, const int* __restrict__ order,
                         float* __restrict__ xs){
  size_t idx = (size_t)blockIdx.x*256 + threadIdx.x;
  int c4 = (int)(idx % 96);
  size_t row = idx / 96;
  int b = (int)(row / NN);
  int src = order[row];
  ((float4*)xs)[row*96 + c4] = ((const float4*)x)[((size_t)b*NN + src)*96 + c4];
}

__global__ void k_zero(float* __restrict__ p, int n){
  int i = blockIdx.x*256 + threadIdx.x;
  if(i<n) p[i]=0.f;
}
__global__ void k_zero_d(double* __restrict__ p, int n){
  int i = blockIdx.x*256 + threadIdx.x;
  if(i<n) p[i]=0.0;
}

__global__ void k_meanx(const float* __restrict__ x, double* __restrict__ meanx){
  int b = blockIdx.x >> 4, chunk = blockIdx.x & 15;
  int c = threadIdx.x;   // 384 threads
  const float* base = x + ((size_t)b*NN + (size_t)chunk*576)*CC + c;
  double s=0.0;
  for(int n=0;n<576;n++) s += (double)base[(size_t)n*CC];
  atomicAdd(&meanx[b*CC+c], s);
}

__global__ void k_scales(const double* __restrict__ ss_d, const float* __restrict__ rw,
                         const float* __restrict__ rb, double* __restrict__ scales){
  int b = blockIdx.x/3, r = blockIdx.x%3;
  double s=0.0;
  for(int t=threadIdx.x;t<N3;t+=256) s += ss_d[(size_t)b*NN + r*N3 + t]*(double)rw[r*N3+t];
  __shared__ double red[4];
  s = wave_sum_d(s);
  if((threadIdx.x&63)==0) red[threadIdx.x>>6]=s;
  __syncthreads();
  if(threadIdx.x==0) scales[b*3+r] = red[0]+red[1]+red[2]+red[3] + (double)rb[r];
}

__global__ void k_aggnum(const double* __restrict__ scales, int* aggnum, int* kknum,
                         int* offs, int* numtot){
  int b = threadIdx.x;
  if(b >= BB) return;
  double s0=scales[b*3+0], s1=scales[b*3+1], s2=scales[b*3+2];
  double m = fmax(s0, fmax(s1,s2));
  double e0=exp(s0-m), e1=exp(s1-m), e2=exp(s2-m);
  double den=e0+e1+e2;
  int off=0;
  for(int r=0;r<3;r++){
    double e = (r==0)?e0:((r==1)?e1:e2);
    double v = 320.0*(e/den);
    v = fmin(fmax(v,16.0),320.0);
    int num=(int)v;                      // trunc toward 0, positive
    int kk=(int)sqrt((double)num);
    while((kk+1)*(kk+1)<=num) kk++;
    while(kk>1 && kk*kk>num) kk--;
    if(kk<1) kk=1;
    aggnum[b*3+r]=num; kknum[b*3+r]=kk; offs[b*3+r]=off; off+=num;
  }
  numtot[b]=off;
}

__global__ void k_weights(const double* __restrict__ meanx, const float* __restrict__ route_w,
                          const float* __restrict__ route_b, float* __restrict__ wts,
                          int* __restrict__ topk){
  __shared__ double wd[BB*EE];
  int t = threadIdx.x;
  if(t < BB*EE){
    int b=t/EE, e=t%EE;
    double s=0.0;
    for(int c=0;c<CC;c++) s += (meanx[b*CC+c]*(1.0/NN))*(double)route_w[e*CC+c];
    double w = 1.0/(1.0+exp(-(s+(double)route_b[e])));
    wd[t]=w;
    wts[t]=(float)w;
  }
  __syncthreads();
  if(t<BB){
    int b=t; int i1=0; double best=-1e300;
    for(int e=0;e<EE;e++){ double w=wd[b*EE+e]; if(w>best){best=w;i1=e;} }
    int i2=-1; double b2=-1e300;
    for(int e=0;e<EE;e++){ if(e==i1) continue; double w=wd[b*EE+e]; if(w>b2){b2=w;i2=e;} }
    topk[b*2]=i1; topk[b*2+1]=i2;
  }
}

// ---------------- generic fp32 C = A * W^T (+bias) ----------------
__device__ __forceinline__ void gemm_abt_tile(const float* __restrict__ A, const float* __restrict__ W,
    const float* __restrict__ bias, float* __restrict__ Cm,
    int M, int Nn, int K, int bx, int by){
  __shared__ float As[16][68];
  __shared__ float Ws[16][68];
  const int tx = threadIdx.x & 15, ty = threadIdx.x >> 4;
  const int tm = bx*64, tn = by*64;
  float acc[4][4];
#pragma unroll
  for(int i=0;i<4;i++)
#pragma unroll
    for(int j=0;j<4;j++) acc[i][j]=0.f;
  for(int k0=0;k0<K;k0+=16){
#pragma unroll
    for(int t=0;t<4;t++){
      int l = threadIdx.x + t*256;
      int r = l>>4, kk=l&15;
      int gm = tm+r;
      As[kk][r] = (gm<M)? A[(size_t)gm*K + k0+kk] : 0.f;
    }
#pragma unroll
    for(int t=0;t<4;t++){
      int l = threadIdx.x + t*256;
      int r=l>>4, kk=l&15;
      int gn = tn+r;
      Ws[kk][r] = (gn<Nn)? W[(size_t)gn*K + k0+kk] : 0.f;
    }
    __syncthreads();
#pragma unroll
    for(int kk=0;kk<16;kk++){
      float a0=As[kk][ty*4+0],a1=As[kk][ty*4+1],a2=As[kk][ty*4+2],a3=As[kk][ty*4+3];
      float b0=Ws[kk][tx*4+0],b1=Ws[kk][tx*4+1],b2=Ws[kk][tx*4+2],b3=Ws[kk][tx*4+3];
      acc[0][0]+=a0*b0; acc[0][1]+=a0*b1; acc[0][2]+=a0*b2; acc[0][3]+=a0*b3;
      acc[1][0]+=a1*b0; acc[1][1]+=a1*b1; acc[1][2]+=a1*b2; acc[1][3]+=a1*b3;
      acc[2][0]+=a2*b0; acc[2][1]+=a2*b1; acc[2][2]+=a2*b2; acc[2][3]+=a2*b3;
      acc[3][0]+=a3*b0; acc[3][1]+=a3*b1; acc[3][2]+=a3*b2; acc[3][3]+=a3*b3;
    }
    __syncthreads();
  }
#pragma unroll
  for(int i=0;i<4;i++){
    int gm=tm+ty*4+i; if(gm>=M) continue;
#pragma unroll
    for(int j=0;j<4;j++){
      int gn=tn+tx*4+j; if(gn>=Nn) continue;
      float v=acc[i][j];
      if(bias) v += bias[gn];
      Cm[(size_t)gm*Nn+gn]=v;
    }
  }
}

__global__ void k_gemm(const float* __restrict__ A, const float* __restrict__ W,
                       const float* __restrict__ bias, float* __restrict__ Cm,
                       int M, int Nn, int K){
  gemm_abt_tile(A,W,bias,Cm,M,Nn,K,blockIdx.x,blockIdx.y);
}

__global__ void k_gemm_kv(const float* __restrict__ agg, const float* __restrict__ kv_w,
                          const int* __restrict__ topk, float* __restrict__ kvb){
  int z = blockIdx.z;                  // b*2+j
  int e = topk[z];
  gemm_abt_tile(agg + (size_t)(z>>1)*MAXTOT*CC, kv_w + (size_t)e*768*CC, nullptr,
                kvb + (size_t)z*MAXTOT*768, MAXTOT, 768, CC, blockIdx.x, blockIdx.y);
}

// ---------------- region clustering ----------------
__global__ void k_region_init(u64* __restrict__ dmaxkey, float* __restrict__ allw){
  int t = threadIdx.x;
  if(t==0) *dmaxkey = 0ull;
  if(t<320) allw[t]=0.f;
}

__global__ void k_sumsq(const float* __restrict__ xr, float* __restrict__ sumsq){
  int row = blockIdx.x*4 + (threadIdx.x>>6);
  int lane = threadIdx.x & 63;
  const float* p = xr + (size_t)row*CC;
  float s=0.f;
  for(int c=lane;c<CC;c+=64){ float v=p[c]; s+=v*v; }
  s = wave_sum(s);
  if(lane==0) sumsq[row]=s;
}

__global__ void k_dist(float* __restrict__ G, const float* __restrict__ sumsq,
                       u64* __restrict__ dmaxkey){
  int idx = blockIdx.x*256+threadIdx.x;
  int i = idx / N3, jj = idx % N3;
  float g = G[idx];
  float d2 = (sumsq[i]+sumsq[jj]) - 2.f*g;
  d2 = fmaxf(d2, 0.f);
  float dv = (d2 > 0.f) ? (sqrtf(d2) / 19.595917942265423f) : 0.f;  // /sqrt(384)
  G[idx]=dv;
  u64 key = (((u64)__float_as_uint(dv))<<32) | (unsigned)idx;
  key = wave_max_u64(key);
  if((threadIdx.x&63)==0) atomicMax(dmaxkey, key);
}

__global__ void k_dmax_fix(const u64* __restrict__ dmaxkey, const float* __restrict__ xr,
                           double* __restrict__ dmaxd){
  if(threadIdx.x!=0) return;
  unsigned pair = (unsigned)(*dmaxkey & 0xFFFFFFFFull);
  int i = pair / N3, j = pair % N3;
  *dmaxd = dist64(xr, i, j);
}

// wave per row: kk-NN via f32 keys, exact f64 recompute of selected distances
__global__ void k_knn(const float* __restrict__ dist, const float* __restrict__ xr,
                      const int* __restrict__ kkptr, double* __restrict__ dens, int foldval){
  int row = blockIdx.x*4 + (threadIdx.x>>6);
  int lane = threadIdx.x & 63;
  int kk = *kkptr;
  const float* dr = dist + (size_t)row*N3;
  u64 loc[17];
#pragma unroll
  for(int i=0;i<17;i++) loc[i]=~0ull;
  for(int j=lane;j<N3;j+=64){
    u64 key = (((u64)__float_as_uint(dr[j]))<<32) | (unsigned)j;
    if(key < loc[16]){
      u64 cur=key;
#pragma unroll
      for(int p=0;p<17;p++){
        u64 old=loc[p];
        bool ins = cur<old;
        loc[p] = ins?cur:old;
        cur    = ins?old:cur;
      }
    }
  }
  int myj = -1;
  for(int it=0; it<kk; it++){
    u64 k = wave_min_u64(loc[0]);
    int owner = (int)(k & 63u);          // j was loaded by lane j%64
    if(lane==owner){
#pragma unroll
      for(int p=0;p<16;p++) loc[p]=loc[p+1];
      loc[16]=~0ull;
    }
    if(it==lane) myj = (int)(k & 0xFFFFFFFFull);
  }
  double nd2 = 0.0;
  if(lane < kk && myj >= 0){
    double dd = dist64(xr, row, myj);
    nd2 = dd*dd;
  }
  double ssum = wave_sum_d(nd2);
  if(lane==0){
    double mean = ssum/(double)kk;
    double d = exp(-mean);
    // jax.random.uniform(fold_in(key(42), foldval), (3072,), f32)[row] * 1e-6
    // modern JAX: jax_threefry_partitionable=True ->
    //   bits[i] = o0 ^ o1 of threefry(key', (hi(i), lo(i))) = threefry(key', (0, i))
    uint32_t k0,k1,o0,o1;
    threefry(0u,42u, 0u,(uint32_t)foldval, k0,k1);   // fold_in(key(42), foldval)
    threefry(k0,k1, 0u,(uint32_t)row, o0,o1);
    uint32_t bits = o0 ^ o1;
    float u = __uint_as_float((bits>>9)|0x3F800000u) - 1.0f;
    dens[row] = d + (double)u*1e-6;
  }
}

__global__ void k_dmin(const float* __restrict__ dist, const float* __restrict__ xr,
                       const double* __restrict__ dens, const double* __restrict__ dmaxd,
                       double* __restrict__ scorec){
  int row = blockIdx.x*4+(threadIdx.x>>6);
  int lane = threadIdx.x & 63;
  double di = dens[row];
  const float* dr = dist + (size_t)row*N3;
  u64 best = ~0ull;
  for(int j=lane;j<N3;j+=64){
    if(dens[j] > di){
      u64 key = (((u64)__float_as_uint(dr[j]))<<32) | (unsigned)j;
      if(key < best) best = key;
    }
  }
  best = wave_min_u64(best);
  if(lane==0){
    double dm;
    if(best == ~0ull) dm = *dmaxd;
    else dm = dist64(xr, row, (int)(best & 0xFFFFFFFFull));
    scorec[row] = dm*di;
  }
}

// rank among scores (desc, tie -> lower index) == lax.top_k order
__global__ void k_centers(const double* __restrict__ scorec, const int* __restrict__ numptr,
                          int* __restrict__ centers){
  int t = blockIdx.x*256+threadIdx.x;
  int num = *numptr;
  double si = scorec[t];
  __shared__ double tile[256];
  int rank=0;
  for(int j0=0;j0<N3;j0+=256){
    tile[threadIdx.x]=scorec[j0+threadIdx.x];
    __syncthreads();
#pragma unroll 8
    for(int jj=0;jj<256;jj++){
      double sj=tile[jj]; int j=j0+jj;
      rank += (sj>si) || (sj==si && j<t);
    }
    __syncthreads();
  }
  if(rank<num) centers[rank]=t;
}

__global__ void k_assign(const float* __restrict__ dist, const float* __restrict__ xr,
                         const int* __restrict__ centers, const int* __restrict__ numptr,
                         int* __restrict__ idxc){
  int t = blockIdx.x*256+threadIdx.x;
  int num=*numptr;
  float bd=3.4e38f; int bc=0;
  float rd=3.4e38f; int rc=-1;
  for(int c=0;c<num;c++){
    float v = dist[(size_t)centers[c]*N3 + t];
    if(v<bd){ rd=bd; rc=bc; bd=v; bc=c; }
    else if(v<rd){ rd=v; rc=c; }
  }
  // f64 refine: compare best vs runner-up exactly (argmin-first semantics)
  if(rc>=0 && (rd-bd) < 1e-3f){
    double d1 = dist64(xr, centers[bc], t);
    double d2 = dist64(xr, centers[rc], t);
    if(d2 < d1 || (d2==d1 && rc<bc)) bc = rc;
  }
  idxc[t]=bc;
}

__global__ void k_fixcenters(const int* __restrict__ centers, const int* __restrict__ numptr,
                             int* __restrict__ idxc){
  int c = blockIdx.x*256+threadIdx.x;
  if(c < *numptr) idxc[centers[c]]=c;
}

__global__ void k_allw(const int* __restrict__ idxc, const float* __restrict__ tw,
                       float* __restrict__ allw){
  int t = blockIdx.x*256+threadIdx.x;
  atomicAdd(&allw[idxc[t]], tw[t]);
}

__global__ void k_scatter(const float* __restrict__ xr, const int* __restrict__ idxc,
                          const float* __restrict__ tw, const float* __restrict__ allw,
                          float* __restrict__ aggb, const int* __restrict__ offptr){
  int idx = blockIdx.x*256+threadIdx.x;
  int t = idx / CC, c = idx % CC;
  int cl = idxc[t];
  float wgt = tw[t]/(allw[cl]+1e-6f);
  atomicAdd(&aggb[(size_t)(*offptr + cl)*CC + c], xr[idx]*wgt);
}

// ---------------- attention: thread = (b,h,n), online softmax over <=960 keys ----------------
__global__ void k_attn(const float* __restrict__ q, const float* __restrict__ kv,
                       const int* __restrict__ numtot, const float* __restrict__ wts,
                       const int* __restrict__ topk, float* __restrict__ res){
  int b = blockIdx.z, h = blockIdx.y;
  int n = blockIdx.x*256 + threadIdx.x;
  int ntot = numtot[b];
  __shared__ float4 kt4[32][12];
  __shared__ float4 vt4[32][12];
  float qv[48];
  const float* qp = q + ((size_t)b*NN + n)*CC + h*DH;
#pragma unroll
  for(int d=0;d<48;d++) qv[d]=qp[d];
  float outa[48];
#pragma unroll
  for(int d=0;d<48;d++) outa[d]=0.f;
  const float sc = 0.14433756729740643f;   // 48^-0.5
  for(int j=0;j<2;j++){
    const float* kvb = kv + (size_t)(b*2+j)*MAXTOT*768;
    float wexp = wts[b*EE + topk[b*2+j]];
    float mrun=-3.4e38f, lrun=0.f;
    float acc[48];
#pragma unroll
    for(int d=0;d<48;d++) acc[d]=0.f;
    for(int m0=0;m0<ntot;m0+=32){
      __syncthreads();
      for(int l=threadIdx.x;l<384;l+=256){
        int mm=l/12, d4=l%12;
        int m=m0+mm;
        float4 kf=make_float4(0,0,0,0), vf=make_float4(0,0,0,0);
        if(m<ntot){
          kf = *(const float4*)(kvb + (size_t)m*768 + h*DH + 4*d4);
          vf = *(const float4*)(kvb + (size_t)m*768 + 384 + h*DH + 4*d4);
        }
        kt4[mm][d4]=kf; vt4[mm][d4]=vf;
      }
      __syncthreads();
      int mcnt = min(32, ntot-m0);
      for(int mm=0;mm<mcnt;mm++){
        float s=0.f;
#pragma unroll
        for(int d4=0;d4<12;d4++){
          float4 kf = kt4[mm][d4];
          s += qv[4*d4+0]*kf.x; s += qv[4*d4+1]*kf.y;
          s += qv[4*d4+2]*kf.z; s += qv[4*d4+3]*kf.w;
        }
        s *= sc;
        if(s > mrun){
          float rs = expf(mrun - s);
          lrun *= rs;
#pragma unroll
          for(int d=0;d<48;d++) acc[d]*=rs;
          mrun = s;
        }
        float p = expf(s - mrun);
        lrun += p;
#pragma unroll
        for(int d4=0;d4<12;d4++){
          float4 vf = vt4[mm][d4];
          acc[4*d4+0]+=p*vf.x; acc[4*d4+1]+=p*vf.y;
          acc[4*d4+2]+=p*vf.z; acc[4*d4+3]+=p*vf.w;
        }
      }
    }
    float inv = 1.f/lrun;
#pragma unroll
    for(int d=0;d<48;d++) outa[d] += wexp*(acc[d]*inv);
  }
  float* rp = res + ((size_t)b*NN + n)*CC + h*DH;
#pragma unroll
  for(int d=0;d<48;d++) rp[d]=outa[d];
}

// ---------------- host ----------------
extern "C" void kernel_launch(void* const* d_in, const int* in_sizes, int n_in,
                              void* d_out, int out_size, void* d_ws, size_t ws_size,
                              hipStream_t stream){
  (void)in_sizes; (void)n_in; (void)out_size;
  const float* x       = (const float*)d_in[0];
  const float* q_w     = (const float*)d_in[1];
  const float* kv_w    = (const float*)d_in[2];
  const float* route_w = (const float*)d_in[3];
  const float* route_b = (const float*)d_in[4];
  const float* score_w = (const float*)d_in[5];
  const float* score_b = (const float*)d_in[6];
  const float* rscale_w= (const float*)d_in[7];
  const float* rscale_b= (const float*)d_in[8];
  const float* proj_w  = (const float*)d_in[9];
  const float* proj_b  = (const float*)d_in[10];
  float* out = (float*)d_out;

  char* w = (char*)d_ws;
  size_t o = 0;
  auto carve = [&](size_t bytes)->char*{
    char* p = w + o;
    o += (bytes + 255) & ~(size_t)255;
    return p;
  };
  double* score_d = (double*)carve((size_t)BB*NN*8);
  u64*   keys    = (u64*)carve((size_t)BB*NN*8);
  int*   order   = (int*)carve((size_t)BB*NN*4);
  double* ss_d   = (double*)carve((size_t)BB*NN*8);
  float* ss_f    = (float*)carve((size_t)BB*NN*4);
  double* meanx  = (double*)carve((size_t)BB*CC*8);
  double* scales = (double*)carve(12*8);
  int*   aggnum  = (int*)carve(12*4);
  int*   kknum   = (int*)carve(12*4);
  int*   offs    = (int*)carve(12*4);
  int*   numtot  = (int*)carve(BB*4);
  float* wts     = (float*)carve(BB*EE*4);
  int*   topk    = (int*)carve(BB*2*4);
  u64*   dmaxkey = (u64*)carve(8);
  double* dmaxd  = (double*)carve(8);
  float* sumsq   = (float*)carve(N3*4);
  double* dens   = (double*)carve(N3*8);
  double* scorec = (double*)carve(N3*8);
  int*   centers = (int*)carve(320*4);
  int*   idxc    = (int*)carve(N3*4);
  float* allw    = (float*)carve(320*4);
  float* agg     = (float*)carve((size_t)BB*MAXTOT*CC*4);
  float* kvb     = (float*)carve((size_t)BB*2*MAXTOT*768*4);
  float* xs      = (float*)carve((size_t)BB*NN*CC*4);
  float* qbuf    = (float*)carve((size_t)BB*NN*CC*4);
  float* res     = (float*)carve((size_t)BB*NN*CC*4);
  float* dist    = res;                    // dist (37.7MB) used only before attention
  if(o > ws_size) return;                  // workspace too small -> visible failure

  dim3 b256(256);
  k_score <<<dim3(BB*NN/4), b256, 0, stream>>>(x, score_w, score_b, score_d, keys);
  k_rank  <<<dim3(NN/256, BB), b256, 0, stream>>>(keys, score_d, order, ss_d, ss_f);
  k_gather<<<dim3((unsigned)((size_t)BB*NN*96/256)), b256, 0, stream>>>(x, order, xs);
  k_zero_d<<<dim3((BB*CC+255)/256), b256, 0, stream>>>(meanx, BB*CC);
  k_meanx <<<dim3(BB*16), dim3(CC), 0, stream>>>(x, meanx);
  k_scales<<<dim3(12), b256, 0, stream>>>(ss_d, rscale_w, rscale_b, scales);
  k_aggnum<<<dim3(1), dim3(64), 0, stream>>>(scales, aggnum, kknum, offs, numtot);
  k_weights<<<dim3(1), dim3(64), 0, stream>>>(meanx, route_w, route_b, wts, topk);
  k_zero  <<<dim3((BB*MAXTOT*CC+255)/256), b256, 0, stream>>>(agg, BB*MAXTOT*CC);

  for(int b=0;b<BB;b++){
    for(int r=0;r<3;r++){
      int fi = b*3+r;
      const float* xr = xs + ((size_t)b*NN + (size_t)r*N3)*CC;
      const float* tw = ss_f + (size_t)b*NN + (size_t)r*N3;
      k_region_init<<<dim3(1), dim3(384), 0, stream>>>(dmaxkey, allw);
      k_sumsq  <<<dim3(N3/4), b256, 0, stream>>>(xr, sumsq);
      k_gemm   <<<dim3(N3/64, N3/64), b256, 0, stream>>>(xr, xr, nullptr, dist, N3, N3, CC);
      k_dist   <<<dim3(N3*N3/256), b256, 0, stream>>>(dist, sumsq, dmaxkey);
      k_dmax_fix<<<dim3(1), dim3(64), 0, stream>>>(dmaxkey, xr, dmaxd);
      k_knn    <<<dim3(N3/4), b256, 0, stream>>>(dist, xr, kknum+fi, dens, fi);
      k_dmin   <<<dim3(N3/4), b256, 0, stream>>>(dist, xr, dens, dmaxd, scorec);
      k_centers<<<dim3(N3/256), b256, 0, stream>>>(scorec, aggnum+fi, centers);
      k_assign <<<dim3(N3/256), b256, 0, stream>>>(dist, xr, centers, aggnum+fi, idxc);
      k_fixcenters<<<dim3(2), b256, 0, stream>>>(centers, aggnum+fi, idxc);
      k_allw   <<<dim3(N3/256), b256, 0, stream>>>(idxc, tw, allw);
      k_scatter<<<dim3(N3*CC/256), b256, 0, stream>>>(xr, idxc, tw, allw,
                  agg + (size_t)b*MAXTOT*CC, offs+fi);
    }
  }
  k_gemm   <<<dim3(BB*NN/64, CC/64), b256, 0, stream>>>(x, q_w, nullptr, qbuf, BB*NN, CC, CC);
  k_gemm_kv<<<dim3(MAXTOT/64, 768/64, BB*2), b256, 0, stream>>>(agg, kv_w, topk, kvb);
  k_attn   <<<dim3(NN/256, HH, BB), b256, 0, stream>>>(qbuf, kvb, numtot, wts, topk, res);
  k_gemm   <<<dim3(BB*NN/64, CC/64), b256, 0, stream>>>(res, proj_w, proj_b, out, BB*NN, CC, CC);
}

// Round 4
// 6930.581 us; speedup vs baseline: 3.9625x; 3.9625x over previous
//
#include <hip/hip_runtime.h>
#include <stdint.h>

#define BB 4
#define NN 9216
#define CC 384
#define HH 8
#define DH 48
#define EE 4
#define N3 3072
#define MAXTOT 960

typedef unsigned long long u64;

// ---------------- wave helpers (wave64) ----------------
__device__ __forceinline__ float wave_sum(float v){
#pragma unroll
  for(int m=32;m>0;m>>=1) v += __shfl_xor(v,m,64);
  return v;
}
__device__ __forceinline__ double wave_sum_d(double v){
#pragma unroll
  for(int m=32;m>0;m>>=1) v += __shfl_xor(v,m,64);
  return v;
}
__device__ __forceinline__ u64 wave_min_u64(u64 k){
#pragma unroll
  for(int m=32;m>0;m>>=1){
    unsigned lo = __shfl_xor((unsigned)k, m, 64);
    unsigned hi = __shfl_xor((unsigned)(k>>32), m, 64);
    u64 o = ((u64)hi<<32)|lo;
    if(o < k) k = o;
  }
  return k;
}
__device__ __forceinline__ u64 wave_max_u64(u64 k){
#pragma unroll
  for(int m=32;m>0;m>>=1){
    unsigned lo = __shfl_xor((unsigned)k, m, 64);
    unsigned hi = __shfl_xor((unsigned)(k>>32), m, 64);
    u64 o = ((u64)hi<<32)|lo;
    if(o > k) k = o;
  }
  return k;
}

// exact f64 distance between token rows i,j of xr (f32 storage promoted)
__device__ double dist64(const float* __restrict__ xr, int i, int j){
  const float* a = xr + (size_t)i*CC;
  const float* b = xr + (size_t)j*CC;
  double s = 0.0;
  for(int c=0;c<CC;c++){
    double d = (double)a[c] - (double)b[c];
    s += d*d;
  }
  if(!(s > 0.0)) return 0.0;
  return sqrt(s) / 19.595917942265423;   // / sqrt(384), double
}

// ---------------- JAX threefry2x32 (20 rounds), bit-exact ----------------
__device__ __forceinline__ void threefry(uint32_t k0, uint32_t k1, uint32_t x0, uint32_t x1,
                                         uint32_t& o0, uint32_t& o1){
  const uint32_t ks0=k0, ks1=k1, ks2=k0^k1^0x1BD11BDAu;
  const int rotA[4]={13,15,26,6}, rotB[4]={17,29,16,24};
  x0 += ks0; x1 += ks1;
#pragma unroll
  for(int g=0; g<5; g++){
    const int* rot = (g&1)? rotB : rotA;
#pragma unroll
    for(int i=0;i<4;i++){
      x0 += x1;
      x1 = (x1<<rot[i])|(x1>>(32-rot[i]));
      x1 ^= x0;
    }
    uint32_t a = (g%3==0)?ks1:((g%3==1)?ks2:ks0);          // ks[(g+1)%3]
    uint32_t b = (g%3==0)?ks2:((g%3==1)?ks0:ks1);          // ks[(g+2)%3]
    x0 += a; x1 += b + (uint32_t)(g+1);
  }
  o0=x0; o1=x1;
}

// ---------------- score (f64) + sort keys ----------------
__global__ void k_score(const float* __restrict__ x, const float* __restrict__ sw,
                        const float* __restrict__ sb, double* __restrict__ score_d,
                        u64* __restrict__ keys){
  int row = blockIdx.x*4 + (threadIdx.x>>6);
  int lane = threadIdx.x & 63;
  const float* xr = x + (size_t)row*CC;
  double s = 0.0;
  for(int c=lane;c<CC;c+=64) s += (double)xr[c]*(double)sw[c];
  s = wave_sum_d(s);
  if(lane==0){
    double sc = exp(s + (double)sb[0]);    // > 0 -> double bits monotone
    score_d[row] = sc;
    keys[row] = (u64)__double_as_longlong(sc);
  }
}

// rank = stable-ascending position (score asc, index asc)
__global__ void k_rank(const u64* __restrict__ keys, const double* __restrict__ score_d,
                       int* __restrict__ order, double* __restrict__ ss_d,
                       float* __restrict__ ss_f){
  int b = blockIdx.y;
  int i = blockIdx.x*256 + threadIdx.x;
  __shared__ u64 tile[256];
  u64 ki = keys[(size_t)b*NN + i];
  int rank = 0;
  for(int j0=0;j0<NN;j0+=256){
    tile[threadIdx.x] = keys[(size_t)b*NN + j0 + threadIdx.x];
    __syncthreads();
#pragma unroll 8
    for(int jj=0;jj<256;jj++){
      u64 kj = tile[jj]; int j=j0+jj;
      rank += (kj < ki) || (kj == ki && j < i);
    }
    __syncthreads();
  }
  double sd = score_d[(size_t)b*NN + i];
  order[(size_t)b*NN + rank] = i;
  ss_d[(size_t)b*NN + rank] = sd;
  ss_f[(size_t)b*NN + rank] = (float)sd;
}

__global__ void k_gather(const float* __restrict__ x, const int* __restrict__ order,
                         float* __restrict__ xs){
  size_t idx = (size_t)blockIdx.x*256 + threadIdx.x;
  int c4 = (int)(idx % 96);
  size_t row = idx / 96;
  int b = (int)(row / NN);
  int src = order[row];
  ((float4*)xs)[row*96 + c4] = ((const float4*)x)[((size_t)b*NN + src)*96 + c4];
}

__global__ void k_zero(float* __restrict__ p, int n){
  int i = blockIdx.x*256 + threadIdx.x;
  if(i<n) p[i]=0.f;
}
__global__ void k_zero_d(double* __restrict__ p, int n){
  int i = blockIdx.x*256 + threadIdx.x;
  if(i<n) p[i]=0.0;
}

__global__ void k_meanx(const float* __restrict__ x, double* __restrict__ meanx){
  int b = blockIdx.x >> 4, chunk = blockIdx.x & 15;
  int c = threadIdx.x;   // 384 threads
  const float* base = x + ((size_t)b*NN + (size_t)chunk*576)*CC + c;
  double s=0.0;
  for(int n=0;n<576;n++) s += (double)base[(size_t)n*CC];
  atomicAdd(&meanx[b*CC+c], s);
}

__global__ void k_scales(const double* __restrict__ ss_d, const float* __restrict__ rw,
                         const float* __restrict__ rb, double* __restrict__ scales){
  int b = blockIdx.x/3, r = blockIdx.x%3;
  double s=0.0;
  for(int t=threadIdx.x;t<N3;t+=256) s += ss_d[(size_t)b*NN + r*N3 + t]*(double)rw[r*N3+t];
  __shared__ double red[4];
  s = wave_sum_d(s);
  if((threadIdx.x&63)==0) red[threadIdx.x>>6]=s;
  __syncthreads();
  if(threadIdx.x==0) scales[b*3+r] = red[0]+red[1]+red[2]+red[3] + (double)rb[r];
}

__global__ void k_aggnum(const double* __restrict__ scales, int* aggnum, int* kknum,
                         int* offs, int* numtot){
  int b = threadIdx.x;
  if(b >= BB) return;
  double s0=scales[b*3+0], s1=scales[b*3+1], s2=scales[b*3+2];
  double m = fmax(s0, fmax(s1,s2));
  double e0=exp(s0-m), e1=exp(s1-m), e2=exp(s2-m);
  double den=e0+e1+e2;
  int off=0;
  for(int r=0;r<3;r++){
    double e = (r==0)?e0:((r==1)?e1:e2);
    double v = 320.0*(e/den);
    v = fmin(fmax(v,16.0),320.0);
    int num=(int)v;                      // trunc toward 0, positive
    int kk=(int)sqrt((double)num);
    while((kk+1)*(kk+1)<=num) kk++;
    while(kk>1 && kk*kk>num) kk--;
    if(kk<1) kk=1;
    aggnum[b*3+r]=num; kknum[b*3+r]=kk; offs[b*3+r]=off; off+=num;
  }
  numtot[b]=off;
}

__global__ void k_weights(const double* __restrict__ meanx, const float* __restrict__ route_w,
                          const float* __restrict__ route_b, float* __restrict__ wts,
                          int* __restrict__ topk){
  __shared__ double wd[BB*EE];
  int t = threadIdx.x;
  if(t < BB*EE){
    int b=t/EE, e=t%EE;
    double s=0.0;
    for(int c=0;c<CC;c++) s += (meanx[b*CC+c]*(1.0/NN))*(double)route_w[e*CC+c];
    double w = 1.0/(1.0+exp(-(s+(double)route_b[e])));
    wd[t]=w;
    wts[t]=(float)w;
  }
  __syncthreads();
  if(t<BB){
    int b=t; int i1=0; double best=-1e300;
    for(int e=0;e<EE;e++){ double w=wd[b*EE+e]; if(w>best){best=w;i1=e;} }
    int i2=-1; double b2=-1e300;
    for(int e=0;e<EE;e++){ if(e==i1) continue; double w=wd[b*EE+e]; if(w>b2){b2=w;i2=e;} }
    topk[b*2]=i1; topk[b*2+1]=i2;
  }
}

// ---------------- generic fp32 C = A * W^T (+bias) ----------------
__device__ __forceinline__ void gemm_abt_tile(const float* __restrict__ A, const float* __restrict__ W,
    const float* __restrict__ bias, float* __restrict__ Cm,
    int M, int Nn, int K, int bx, int by){
  __shared__ float As[16][68];
  __shared__ float Ws[16][68];
  const int tx = threadIdx.x & 15, ty = threadIdx.x >> 4;
  const int tm = bx*64, tn = by*64;
  float acc[4][4];
#pragma unroll
  for(int i=0;i<4;i++)
#pragma unroll
    for(int j=0;j<4;j++) acc[i][j]=0.f;
  for(int k0=0;k0<K;k0+=16){
#pragma unroll
    for(int t=0;t<4;t++){
      int l = threadIdx.x + t*256;
      int r = l>>4, kk=l&15;
      int gm = tm+r;
      As[kk][r] = (gm<M)? A[(size_t)gm*K + k0+kk] : 0.f;
    }
#pragma unroll
    for(int t=0;t<4;t++){
      int l = threadIdx.x + t*256;
      int r=l>>4, kk=l&15;
      int gn = tn+r;
      Ws[kk][r] = (gn<Nn)? W[(size_t)gn*K + k0+kk] : 0.f;
    }
    __syncthreads();
#pragma unroll
    for(int kk=0;kk<16;kk++){
      float a0=As[kk][ty*4+0],a1=As[kk][ty*4+1],a2=As[kk][ty*4+2],a3=As[kk][ty*4+3];
      float b0=Ws[kk][tx*4+0],b1=Ws[kk][tx*4+1],b2=Ws[kk][tx*4+2],b3=Ws[kk][tx*4+3];
      acc[0][0]+=a0*b0; acc[0][1]+=a0*b1; acc[0][2]+=a0*b2; acc[0][3]+=a0*b3;
      acc[1][0]+=a1*b0; acc[1][1]+=a1*b1; acc[1][2]+=a1*b2; acc[1][3]+=a1*b3;
      acc[2][0]+=a2*b0; acc[2][1]+=a2*b1; acc[2][2]+=a2*b2; acc[2][3]+=a2*b3;
      acc[3][0]+=a3*b0; acc[3][1]+=a3*b1; acc[3][2]+=a3*b2; acc[3][3]+=a3*b3;
    }
    __syncthreads();
  }
#pragma unroll
  for(int i=0;i<4;i++){
    int gm=tm+ty*4+i; if(gm>=M) continue;
#pragma unroll
    for(int j=0;j<4;j++){
      int gn=tn+tx*4+j; if(gn>=Nn) continue;
      float v=acc[i][j];
      if(bias) v += bias[gn];
      Cm[(size_t)gm*Nn+gn]=v;
    }
  }
}

__global__ void k_gemm(const float* __restrict__ A, const float* __restrict__ W,
                       const float* __restrict__ bias, float* __restrict__ Cm,
                       int M, int Nn, int K){
  gemm_abt_tile(A,W,bias,Cm,M,Nn,K,blockIdx.x,blockIdx.y);
}

__global__ void k_gemm_kv(const float* __restrict__ agg, const float* __restrict__ kv_w,
                          const int* __restrict__ topk, float* __restrict__ kvb){
  int z = blockIdx.z;                  // b*2+j
  int e = topk[z];
  gemm_abt_tile(agg + (size_t)(z>>1)*MAXTOT*CC, kv_w + (size_t)e*768*CC, nullptr,
                kvb + (size_t)z*MAXTOT*768, MAXTOT, 768, CC, blockIdx.x, blockIdx.y);
}

// ---------------- fused Gram -> distance (+ block-reduced pair-max) ----------------
// Same f32 arithmetic & order as r3's k_gemm+k_dist -> bit-identical dist values,
// but 64 atomics/region -> 1 atomic/block (2304/region) and one less 37.7MB round trip.
__global__ void k_gram(const float* __restrict__ xr, const float* __restrict__ sumsq,
                       float* __restrict__ dist, u64* __restrict__ dmaxkey){
  __shared__ float As[16][68];
  __shared__ float Ws[16][68];
  const int tx = threadIdx.x & 15, ty = threadIdx.x >> 4;
  const int tm = blockIdx.x*64, tn = blockIdx.y*64;
  float acc[4][4];
#pragma unroll
  for(int i=0;i<4;i++)
#pragma unroll
    for(int j=0;j<4;j++) acc[i][j]=0.f;
  for(int k0=0;k0<CC;k0+=16){
#pragma unroll
    for(int t=0;t<4;t++){
      int l = threadIdx.x + t*256;
      int r = l>>4, kk=l&15;
      As[kk][r] = xr[(size_t)(tm+r)*CC + k0+kk];
    }
#pragma unroll
    for(int t=0;t<4;t++){
      int l = threadIdx.x + t*256;
      int r=l>>4, kk=l&15;
      Ws[kk][r] = xr[(size_t)(tn+r)*CC + k0+kk];
    }
    __syncthreads();
#pragma unroll
    for(int kk=0;kk<16;kk++){
      float a0=As[kk][ty*4+0],a1=As[kk][ty*4+1],a2=As[kk][ty*4+2],a3=As[kk][ty*4+3];
      float b0=Ws[kk][tx*4+0],b1=Ws[kk][tx*4+1],b2=Ws[kk][tx*4+2],b3=Ws[kk][tx*4+3];
      acc[0][0]+=a0*b0; acc[0][1]+=a0*b1; acc[0][2]+=a0*b2; acc[0][3]+=a0*b3;
      acc[1][0]+=a1*b0; acc[1][1]+=a1*b1; acc[1][2]+=a1*b2; acc[1][3]+=a1*b3;
      acc[2][0]+=a2*b0; acc[2][1]+=a2*b1; acc[2][2]+=a2*b2; acc[2][3]+=a2*b3;
      acc[3][0]+=a3*b0; acc[3][1]+=a3*b1; acc[3][2]+=a3*b2; acc[3][3]+=a3*b3;
    }
    __syncthreads();
  }
  u64 best = 0ull;
#pragma unroll
  for(int i=0;i<4;i++){
    int gm = tm+ty*4+i;
    float sq_m = sumsq[gm];
#pragma unroll
    for(int j=0;j<4;j++){
      int gn = tn+tx*4+j;
      float d2 = (sq_m + sumsq[gn]) - 2.f*acc[i][j];
      d2 = fmaxf(d2, 0.f);
      float dv = (d2 > 0.f) ? (sqrtf(d2) / 19.595917942265423f) : 0.f;
      unsigned idx = (unsigned)(gm*N3 + gn);
      dist[(size_t)gm*N3 + gn] = dv;
      u64 key = (((u64)__float_as_uint(dv))<<32) | idx;
      if(key > best) best = key;
    }
  }
  best = wave_max_u64(best);
  __shared__ u64 red[4];
  if((threadIdx.x&63)==0) red[threadIdx.x>>6]=best;
  __syncthreads();
  if(threadIdx.x==0){
    u64 m = red[0];
    if(red[1]>m) m=red[1];
    if(red[2]>m) m=red[2];
    if(red[3]>m) m=red[3];
    atomicMax(dmaxkey, m);
  }
}

// ---------------- region clustering ----------------
__global__ void k_region_init(u64* __restrict__ dmaxkey, float* __restrict__ allw){
  int t = threadIdx.x;
  if(t==0) *dmaxkey = 0ull;
  if(t<320) allw[t]=0.f;
}

__global__ void k_sumsq(const float* __restrict__ xr, float* __restrict__ sumsq){
  int row = blockIdx.x*4 + (threadIdx.x>>6);
  int lane = threadIdx.x & 63;
  const float* p = xr + (size_t)row*CC;
  float s=0.f;
  for(int c=lane;c<CC;c+=64){ float v=p[c]; s+=v*v; }
  s = wave_sum(s);
  if(lane==0) sumsq[row]=s;
}

__global__ void k_dmax_fix(const u64* __restrict__ dmaxkey, const float* __restrict__ xr,
                           double* __restrict__ dmaxd){
  if(threadIdx.x!=0) return;
  unsigned pair = (unsigned)(*dmaxkey & 0xFFFFFFFFull);
  int i = pair / N3, j = pair % N3;
  *dmaxd = dist64(xr, i, j);
}

// wave per row: kk-NN via f32 keys, exact f64 recompute of selected distances
__global__ void k_knn(const float* __restrict__ dist, const float* __restrict__ xr,
                      const int* __restrict__ kkptr, double* __restrict__ dens, int foldval){
  int row = blockIdx.x*4 + (threadIdx.x>>6);
  int lane = threadIdx.x & 63;
  int kk = *kkptr;
  const float* dr = dist + (size_t)row*N3;
  u64 loc[17];
#pragma unroll
  for(int i=0;i<17;i++) loc[i]=~0ull;
  for(int j=lane;j<N3;j+=64){
    u64 key = (((u64)__float_as_uint(dr[j]))<<32) | (unsigned)j;
    if(key < loc[16]){
      u64 cur=key;
#pragma unroll
      for(int p=0;p<17;p++){
        u64 old=loc[p];
        bool ins = cur<old;
        loc[p] = ins?cur:old;
        cur    = ins?old:cur;
      }
    }
  }
  int myj = -1;
  for(int it=0; it<kk; it++){
    u64 k = wave_min_u64(loc[0]);
    int owner = (int)(k & 63u);          // j was loaded by lane j%64
    if(lane==owner){
#pragma unroll
      for(int p=0;p<16;p++) loc[p]=loc[p+1];
      loc[16]=~0ull;
    }
    if(it==lane) myj = (int)(k & 0xFFFFFFFFull);
  }
  double nd2 = 0.0;
  if(lane < kk && myj >= 0){
    double dd = dist64(xr, row, myj);
    nd2 = dd*dd;
  }
  double ssum = wave_sum_d(nd2);
  if(lane==0){
    double mean = ssum/(double)kk;
    double d = exp(-mean);
    // jax.random.uniform(fold_in(key(42), foldval), (3072,), f32)[row] * 1e-6
    // modern JAX (jax_threefry_partitionable=True): bits[i] = o0 ^ o1,
    // (o0,o1) = threefry(key', (0, i))
    uint32_t k0,k1,o0,o1;
    threefry(0u,42u, 0u,(uint32_t)foldval, k0,k1);   // fold_in(key(42), foldval)
    threefry(k0,k1, 0u,(uint32_t)row, o0,o1);
    uint32_t bits = o0 ^ o1;
    float u = __uint_as_float((bits>>9)|0x3F800000u) - 1.0f;
    dens[row] = d + (double)u*1e-6;
  }
}

__global__ void k_dmin(const float* __restrict__ dist, const float* __restrict__ xr,
                       const double* __restrict__ dens, const double* __restrict__ dmaxd,
                       double* __restrict__ scorec){
  int row = blockIdx.x*4+(threadIdx.x>>6);
  int lane = threadIdx.x & 63;
  double di = dens[row];
  const float* dr = dist + (size_t)row*N3;
  u64 best = ~0ull;
  for(int j=lane;j<N3;j+=64){
    if(dens[j] > di){
      u64 key = (((u64)__float_as_uint(dr[j]))<<32) | (unsigned)j;
      if(key < best) best = key;
    }
  }
  best = wave_min_u64(best);
  if(lane==0){
    double dm;
    if(best == ~0ull) dm = *dmaxd;
    else dm = dist64(xr, row, (int)(best & 0xFFFFFFFFull));
    scorec[row] = dm*di;
  }
}

// rank among scores (desc, tie -> lower index) == lax.top_k order
__global__ void k_centers(const double* __restrict__ scorec, const int* __restrict__ numptr,
                          int* __restrict__ centers){
  int t = blockIdx.x*256+threadIdx.x;
  int num = *numptr;
  double si = scorec[t];
  __shared__ double tile[256];
  int rank=0;
  for(int j0=0;j0<N3;j0+=256){
    tile[threadIdx.x]=scorec[j0+threadIdx.x];
    __syncthreads();
#pragma unroll 8
    for(int jj=0;jj<256;jj++){
      double sj=tile[jj]; int j=j0+jj;
      rank += (sj>si) || (sj==si && j<t);
    }
    __syncthreads();
  }
  if(rank<num) centers[rank]=t;
}

__global__ void k_assign(const float* __restrict__ dist, const float* __restrict__ xr,
                         const int* __restrict__ centers, const int* __restrict__ numptr,
                         int* __restrict__ idxc){
  int t = blockIdx.x*256+threadIdx.x;
  int num=*numptr;
  float bd=3.4e38f; int bc=0;
  float rd=3.4e38f; int rc=-1;
  for(int c=0;c<num;c++){
    float v = dist[(size_t)centers[c]*N3 + t];
    if(v<bd){ rd=bd; rc=bc; bd=v; bc=c; }
    else if(v<rd){ rd=v; rc=c; }
  }
  // f64 refine: compare best vs runner-up exactly (argmin-first semantics)
  if(rc>=0 && (rd-bd) < 1e-3f){
    double d1 = dist64(xr, centers[bc], t);
    double d2 = dist64(xr, centers[rc], t);
    if(d2 < d1 || (d2==d1 && rc<bc)) bc = rc;
  }
  idxc[t]=bc;
}

__global__ void k_fixcenters(const int* __restrict__ centers, const int* __restrict__ numptr,
                             int* __restrict__ idxc){
  int c = blockIdx.x*256+threadIdx.x;
  if(c < *numptr) idxc[centers[c]]=c;
}

__global__ void k_allw(const int* __restrict__ idxc, const float* __restrict__ tw,
                       float* __restrict__ allw){
  int t = blockIdx.x*256+threadIdx.x;
  atomicAdd(&allw[idxc[t]], tw[t]);
}

__global__ void k_scatter(const float* __restrict__ xr, const int* __restrict__ idxc,
                          const float* __restrict__ tw, const float* __restrict__ allw,
                          float* __restrict__ aggb, const int* __restrict__ offptr){
  int idx = blockIdx.x*256+threadIdx.x;
  int t = idx / CC, c = idx % CC;
  int cl = idxc[t];
  float wgt = tw[t]/(allw[cl]+1e-6f);
  atomicAdd(&aggb[(size_t)(*offptr + cl)*CC + c], xr[idx]*wgt);
}

// ---------------- attention: thread = (b,h,n), online softmax over <=960 keys ----------------
__global__ void k_attn(const float* __restrict__ q, const float* __restrict__ kv,
                       const int* __restrict__ numtot, const float* __restrict__ wts,
                       const int* __restrict__ topk, float* __restrict__ res){
  int b = blockIdx.z, h = blockIdx.y;
  int n = blockIdx.x*256 + threadIdx.x;
  int ntot = numtot[b];
  __shared__ float4 kt4[32][12];
  __shared__ float4 vt4[32][12];
  float qv[48];
  const float* qp = q + ((size_t)b*NN + n)*CC + h*DH;
#pragma unroll
  for(int d=0;d<48;d++) qv[d]=qp[d];
  float outa[48];
#pragma unroll
  for(int d=0;d<48;d++) outa[d]=0.f;
  const float sc = 0.14433756729740643f;   // 48^-0.5
  for(int j=0;j<2;j++){
    const float* kvb = kv + (size_t)(b*2+j)*MAXTOT*768;
    float wexp = wts[b*EE + topk[b*2+j]];
    float mrun=-3.4e38f, lrun=0.f;
    float acc[48];
#pragma unroll
    for(int d=0;d<48;d++) acc[d]=0.f;
    for(int m0=0;m0<ntot;m0+=32){
      __syncthreads();
      for(int l=threadIdx.x;l<384;l+=256){
        int mm=l/12, d4=l%12;
        int m=m0+mm;
        float4 kf=make_float4(0,0,0,0), vf=make_float4(0,0,0,0);
        if(m<ntot){
          kf = *(const float4*)(kvb + (size_t)m*768 + h*DH + 4*d4);
          vf = *(const float4*)(kvb + (size_t)m*768 + 384 + h*DH + 4*d4);
        }
        kt4[mm][d4]=kf; vt4[mm][d4]=vf;
      }
      __syncthreads();
      int mcnt = min(32, ntot-m0);
      for(int mm=0;mm<mcnt;mm++){
        float s=0.f;
#pragma unroll
        for(int d4=0;d4<12;d4++){
          float4 kf = kt4[mm][d4];
          s += qv[4*d4+0]*kf.x; s += qv[4*d4+1]*kf.y;
          s += qv[4*d4+2]*kf.z; s += qv[4*d4+3]*kf.w;
        }
        s *= sc;
        if(s > mrun){
          float rs = expf(mrun - s);
          lrun *= rs;
#pragma unroll
          for(int d=0;d<48;d++) acc[d]*=rs;
          mrun = s;
        }
        float p = expf(s - mrun);
        lrun += p;
#pragma unroll
        for(int d4=0;d4<12;d4++){
          float4 vf = vt4[mm][d4];
          acc[4*d4+0]+=p*vf.x; acc[4*d4+1]+=p*vf.y;
          acc[4*d4+2]+=p*vf.z; acc[4*d4+3]+=p*vf.w;
        }
      }
    }
    float inv = 1.f/lrun;
#pragma unroll
    for(int d=0;d<48;d++) outa[d] += wexp*(acc[d]*inv);
  }
  float* rp = res + ((size_t)b*NN + n)*CC + h*DH;
#pragma unroll
  for(int d=0;d<48;d++) rp[d]=outa[d];
}

// ---------------- host ----------------
extern "C" void kernel_launch(void* const* d_in, const int* in_sizes, int n_in,
                              void* d_out, int out_size, void* d_ws, size_t ws_size,
                              hipStream_t stream){
  (void)in_sizes; (void)n_in; (void)out_size;
  const float* x       = (const float*)d_in[0];
  const float* q_w     = (const float*)d_in[1];
  const float* kv_w    = (const float*)d_in[2];
  const float* route_w = (const float*)d_in[3];
  const float* route_b = (const float*)d_in[4];
  const float* score_w = (const float*)d_in[5];
  const float* score_b = (const float*)d_in[6];
  const float* rscale_w= (const float*)d_in[7];
  const float* rscale_b= (const float*)d_in[8];
  const float* proj_w  = (const float*)d_in[9];
  const float* proj_b  = (const float*)d_in[10];
  float* out = (float*)d_out;

  char* w = (char*)d_ws;
  size_t o = 0;
  auto carve = [&](size_t bytes)->char*{
    char* p = w + o;
    o += (bytes + 255) & ~(size_t)255;
    return p;
  };
  double* score_d = (double*)carve((size_t)BB*NN*8);
  u64*   keys    = (u64*)carve((size_t)BB*NN*8);
  int*   order   = (int*)carve((size_t)BB*NN*4);
  double* ss_d   = (double*)carve((size_t)BB*NN*8);
  float* ss_f    = (float*)carve((size_t)BB*NN*4);
  double* meanx  = (double*)carve((size_t)BB*CC*8);
  double* scales = (double*)carve(12*8);
  int*   aggnum  = (int*)carve(12*4);
  int*   kknum   = (int*)carve(12*4);
  int*   offs    = (int*)carve(12*4);
  int*   numtot  = (int*)carve(BB*4);
  float* wts     = (float*)carve(BB*EE*4);
  int*   topk    = (int*)carve(BB*2*4);
  u64*   dmaxkey = (u64*)carve(8);
  double* dmaxd  = (double*)carve(8);
  float* sumsq   = (float*)carve(N3*4);
  double* dens   = (double*)carve(N3*8);
  double* scorec = (double*)carve(N3*8);
  int*   centers = (int*)carve(320*4);
  int*   idxc    = (int*)carve(N3*4);
  float* allw    = (float*)carve(320*4);
  float* agg     = (float*)carve((size_t)BB*MAXTOT*CC*4);
  float* kvb     = (float*)carve((size_t)BB*2*MAXTOT*768*4);
  float* xs      = (float*)carve((size_t)BB*NN*CC*4);
  float* qbuf    = (float*)carve((size_t)BB*NN*CC*4);
  float* res     = (float*)carve((size_t)BB*NN*CC*4);
  float* dist    = res;                    // dist (37.7MB) used only before attention
  if(o > ws_size) return;                  // workspace too small -> visible failure

  dim3 b256(256);
  k_score <<<dim3(BB*NN/4), b256, 0, stream>>>(x, score_w, score_b, score_d, keys);
  k_rank  <<<dim3(NN/256, BB), b256, 0, stream>>>(keys, score_d, order, ss_d, ss_f);
  k_gather<<<dim3((unsigned)((size_t)BB*NN*96/256)), b256, 0, stream>>>(x, order, xs);
  k_zero_d<<<dim3((BB*CC+255)/256), b256, 0, stream>>>(meanx, BB*CC);
  k_meanx <<<dim3(BB*16), dim3(CC), 0, stream>>>(x, meanx);
  k_scales<<<dim3(12), b256, 0, stream>>>(ss_d, rscale_w, rscale_b, scales);
  k_aggnum<<<dim3(1), dim3(64), 0, stream>>>(scales, aggnum, kknum, offs, numtot);
  k_weights<<<dim3(1), dim3(64), 0, stream>>>(meanx, route_w, route_b, wts, topk);
  k_zero  <<<dim3((BB*MAXTOT*CC+255)/256), b256, 0, stream>>>(agg, BB*MAXTOT*CC);

  for(int b=0;b<BB;b++){
    for(int r=0;r<3;r++){
      int fi = b*3+r;
      const float* xr = xs + ((size_t)b*NN + (size_t)r*N3)*CC;
      const float* tw = ss_f + (size_t)b*NN + (size_t)r*N3;
      k_region_init<<<dim3(1), dim3(384), 0, stream>>>(dmaxkey, allw);
      k_sumsq  <<<dim3(N3/4), b256, 0, stream>>>(xr, sumsq);
      k_gram   <<<dim3(N3/64, N3/64), b256, 0, stream>>>(xr, sumsq, dist, dmaxkey);
      k_dmax_fix<<<dim3(1), dim3(64), 0, stream>>>(dmaxkey, xr, dmaxd);
      k_knn    <<<dim3(N3/4), b256, 0, stream>>>(dist, xr, kknum+fi, dens, fi);
      k_dmin   <<<dim3(N3/4), b256, 0, stream>>>(dist, xr, dens, dmaxd, scorec);
      k_centers<<<dim3(N3/256), b256, 0, stream>>>(scorec, aggnum+fi, centers);
      k_assign <<<dim3(N3/256), b256, 0, stream>>>(dist, xr, centers, aggnum+fi, idxc);
      k_fixcenters<<<dim3(2), b256, 0, stream>>>(centers, aggnum+fi, idxc);
      k_allw   <<<dim3(N3/256), b256, 0, stream>>>(idxc, tw, allw);
      k_scatter<<<dim3(N3*CC/256), b256, 0, stream>>>(xr, idxc, tw, allw,
                  agg + (size_t)b*MAXTOT*CC, offs+fi);
    }
  }
  k_gemm   <<<dim3(BB*NN/64, CC/64), b256, 0, stream>>>(x, q_w, nullptr, qbuf, BB*NN, CC, CC);
  k_gemm_kv<<<dim3(MAXTOT/64, 768/64, BB*2), b256, 0, stream>>>(agg, kv_w, topk, kvb);
  k_attn   <<<dim3(NN/256, HH, BB), b256, 0, stream>>>(qbuf, kvb, numtot, wts, topk, res);
  k_gemm   <<<dim3(BB*NN/64, CC/64), b256, 0, stream>>>(res, proj_w, proj_b, out, BB*NN, CC, CC);
}

// Round 6
// 4086.179 us; speedup vs baseline: 6.7209x; 1.6961x over previous
//
#include <hip/hip_runtime.h>
#include <stdint.h>

#define BB 4
#define NN 9216
#define CC 384
#define HH 8
#define DH 48
#define EE 4
#define N3 3072
#define MAXTOT 960
#define NT3 24          // N3/128
#define NTRI 300        // NT3*(NT3+1)/2

typedef unsigned long long u64;

// ---------------- wave helpers (wave64) ----------------
__device__ __forceinline__ float wave_sum(float v){
#pragma unroll
  for(int m=32;m>0;m>>=1) v += __shfl_xor(v,m,64);
  return v;
}
__device__ __forceinline__ double wave_sum_d(double v){
#pragma unroll
  for(int m=32;m>0;m>>=1) v += __shfl_xor(v,m,64);
  return v;
}
__device__ __forceinline__ u64 wave_min_u64(u64 k){
#pragma unroll
  for(int m=32;m>0;m>>=1){
    unsigned lo = __shfl_xor((unsigned)k, m, 64);
    unsigned hi = __shfl_xor((unsigned)(k>>32), m, 64);
    u64 o = ((u64)hi<<32)|lo;
    if(o < k) k = o;
  }
  return k;
}
__device__ __forceinline__ u64 wave_max_u64(u64 k){
#pragma unroll
  for(int m=32;m>0;m>>=1){
    unsigned lo = __shfl_xor((unsigned)k, m, 64);
    unsigned hi = __shfl_xor((unsigned)(k>>32), m, 64);
    u64 o = ((u64)hi<<32)|lo;
    if(o > k) k = o;
  }
  return k;
}

// exact f64 distance between token rows i,j of xr (f32 storage promoted)
__device__ double dist64(const float* __restrict__ xr, int i, int j){
  const float* a = xr + (size_t)i*CC;
  const float* b = xr + (size_t)j*CC;
  double s = 0.0;
  for(int c=0;c<CC;c++){
    double d = (double)a[c] - (double)b[c];
    s += d*d;
  }
  if(!(s > 0.0)) return 0.0;
  return sqrt(s) / 19.595917942265423;   // / sqrt(384), double
}

// ---------------- JAX threefry2x32 (20 rounds), bit-exact ----------------
__device__ __forceinline__ void threefry(uint32_t k0, uint32_t k1, uint32_t x0, uint32_t x1,
                                         uint32_t& o0, uint32_t& o1){
  const uint32_t ks0=k0, ks1=k1, ks2=k0^k1^0x1BD11BDAu;
  const int rotA[4]={13,15,26,6}, rotB[4]={17,29,16,24};
  x0 += ks0; x1 += ks1;
#pragma unroll
  for(int g=0; g<5; g++){
    const int* rot = (g&1)? rotB : rotA;
#pragma unroll
    for(int i=0;i<4;i++){
      x0 += x1;
      x1 = (x1<<rot[i])|(x1>>(32-rot[i]));
      x1 ^= x0;
    }
    uint32_t a = (g%3==0)?ks1:((g%3==1)?ks2:ks0);          // ks[(g+1)%3]
    uint32_t b = (g%3==0)?ks2:((g%3==1)?ks0:ks1);          // ks[(g+2)%3]
    x0 += a; x1 += b + (uint32_t)(g+1);
  }
  o0=x0; o1=x1;
}

// ---------------- score (f64) + sort keys ----------------
__global__ void k_score(const float* __restrict__ x, const float* __restrict__ sw,
                        const float* __restrict__ sb, double* __restrict__ score_d,
                        u64* __restrict__ keys){
  int row = blockIdx.x*4 + (threadIdx.x>>6);
  int lane = threadIdx.x & 63;
  const float* xr = x + (size_t)row*CC;
  double s = 0.0;
  for(int c=lane;c<CC;c+=64) s += (double)xr[c]*(double)sw[c];
  s = wave_sum_d(s);
  if(lane==0){
    double sc = exp(s + (double)sb[0]);    // > 0 -> double bits monotone
    score_d[row] = sc;
    keys[row] = (u64)__double_as_longlong(sc);
  }
}

// rank = stable-ascending position (score asc, index asc)
__global__ void k_rank(const u64* __restrict__ keys, const double* __restrict__ score_d,
                       int* __restrict__ order, double* __restrict__ ss_d,
                       float* __restrict__ ss_f){
  int b = blockIdx.y;
  int i = blockIdx.x*256 + threadIdx.x;
  __shared__ u64 tile[256];
  u64 ki = keys[(size_t)b*NN + i];
  int rank = 0;
  for(int j0=0;j0<NN;j0+=256){
    tile[threadIdx.x] = keys[(size_t)b*NN + j0 + threadIdx.x];
    __syncthreads();
#pragma unroll 8
    for(int jj=0;jj<256;jj++){
      u64 kj = tile[jj]; int j=j0+jj;
      rank += (kj < ki) || (kj == ki && j < i);
    }
    __syncthreads();
  }
  double sd = score_d[(size_t)b*NN + i];
  order[(size_t)b*NN + rank] = i;
  ss_d[(size_t)b*NN + rank] = sd;
  ss_f[(size_t)b*NN + rank] = (float)sd;
}

__global__ void k_gather(const float* __restrict__ x, const int* __restrict__ order,
                         float* __restrict__ xs){
  size_t idx = (size_t)blockIdx.x*256 + threadIdx.x;
  int c4 = (int)(idx % 96);
  size_t row = idx / 96;
  int b = (int)(row / NN);
  int src = order[row];
  ((float4*)xs)[row*96 + c4] = ((const float4*)x)[((size_t)b*NN + src)*96 + c4];
}

__global__ void k_zero(float* __restrict__ p, int n){
  int i = blockIdx.x*256 + threadIdx.x;
  if(i<n) p[i]=0.f;
}
__global__ void k_zero_d(double* __restrict__ p, int n){
  int i = blockIdx.x*256 + threadIdx.x;
  if(i<n) p[i]=0.0;
}

__global__ void k_meanx(const float* __restrict__ x, double* __restrict__ meanx){
  int b = blockIdx.x >> 4, chunk = blockIdx.x & 15;
  int c = threadIdx.x;   // 384 threads
  const float* base = x + ((size_t)b*NN + (size_t)chunk*576)*CC + c;
  double s=0.0;
  for(int n=0;n<576;n++) s += (double)base[(size_t)n*CC];
  atomicAdd(&meanx[b*CC+c], s);
}

__global__ void k_scales(const double* __restrict__ ss_d, const float* __restrict__ rw,
                         const float* __restrict__ rb, double* __restrict__ scales){
  int b = blockIdx.x/3, r = blockIdx.x%3;
  double s=0.0;
  for(int t=threadIdx.x;t<N3;t+=256) s += ss_d[(size_t)b*NN + r*N3 + t]*(double)rw[r*N3+t];
  __shared__ double red[4];
  s = wave_sum_d(s);
  if((threadIdx.x&63)==0) red[threadIdx.x>>6]=s;
  __syncthreads();
  if(threadIdx.x==0) scales[b*3+r] = red[0]+red[1]+red[2]+red[3] + (double)rb[r];
}

__global__ void k_aggnum(const double* __restrict__ scales, int* aggnum, int* kknum,
                         int* offs, int* numtot){
  int b = threadIdx.x;
  if(b >= BB) return;
  double s0=scales[b*3+0], s1=scales[b*3+1], s2=scales[b*3+2];
  double m = fmax(s0, fmax(s1,s2));
  double e0=exp(s0-m), e1=exp(s1-m), e2=exp(s2-m);
  double den=e0+e1+e2;
  int off=0;
  for(int r=0;r<3;r++){
    double e = (r==0)?e0:((r==1)?e1:e2);
    double v = 320.0*(e/den);
    v = fmin(fmax(v,16.0),320.0);
    int num=(int)v;                      // trunc toward 0, positive
    int kk=(int)sqrt((double)num);
    while((kk+1)*(kk+1)<=num) kk++;
    while(kk>1 && kk*kk>num) kk--;
    if(kk<1) kk=1;
    aggnum[b*3+r]=num; kknum[b*3+r]=kk; offs[b*3+r]=off; off+=num;
  }
  numtot[b]=off;
}

__global__ void k_weights(const double* __restrict__ meanx, const float* __restrict__ route_w,
                          const float* __restrict__ route_b, float* __restrict__ wts,
                          int* __restrict__ topk){
  __shared__ double wd[BB*EE];
  int t = threadIdx.x;
  if(t < BB*EE){
    int b=t/EE, e=t%EE;
    double s=0.0;
    for(int c=0;c<CC;c++) s += (meanx[b*CC+c]*(1.0/NN))*(double)route_w[e*CC+c];
    double w = 1.0/(1.0+exp(-(s+(double)route_b[e])));
    wd[t]=w;
    wts[t]=(float)w;
  }
  __syncthreads();
  if(t<BB){
    int b=t; int i1=0; double best=-1e300;
    for(int e=0;e<EE;e++){ double w=wd[b*EE+e]; if(w>best){best=w;i1=e;} }
    int i2=-1; double b2=-1e300;
    for(int e=0;e<EE;e++){ if(e==i1) continue; double w=wd[b*EE+e]; if(w>b2){b2=w;i2=e;} }
    topk[b*2]=i1; topk[b*2+1]=i2;
  }
}

// ---------------- small fp32 C = A * W^T (64 tile, guarded) ----------------
__device__ __forceinline__ void gemm_abt_tile(const float* __restrict__ A, const float* __restrict__ W,
    const float* __restrict__ bias, float* __restrict__ Cm,
    int M, int Nn, int K, int bx, int by){
  __shared__ float As[16][68];
  __shared__ float Ws[16][68];
  const int tx = threadIdx.x & 15, ty = threadIdx.x >> 4;
  const int tm = bx*64, tn = by*64;
  float acc[4][4];
#pragma unroll
  for(int i=0;i<4;i++)
#pragma unroll
    for(int j=0;j<4;j++) acc[i][j]=0.f;
  for(int k0=0;k0<K;k0+=16){
#pragma unroll
    for(int t=0;t<4;t++){
      int l = threadIdx.x + t*256;
      int r = l>>4, kk=l&15;
      int gm = tm+r;
      As[kk][r] = (gm<M)? A[(size_t)gm*K + k0+kk] : 0.f;
    }
#pragma unroll
    for(int t=0;t<4;t++){
      int l = threadIdx.x + t*256;
      int r=l>>4, kk=l&15;
      int gn = tn+r;
      Ws[kk][r] = (gn<Nn)? W[(size_t)gn*K + k0+kk] : 0.f;
    }
    __syncthreads();
#pragma unroll
    for(int kk=0;kk<16;kk++){
      float a0=As[kk][ty*4+0],a1=As[kk][ty*4+1],a2=As[kk][ty*4+2],a3=As[kk][ty*4+3];
      float b0=Ws[kk][tx*4+0],b1=Ws[kk][tx*4+1],b2=Ws[kk][tx*4+2],b3=Ws[kk][tx*4+3];
      acc[0][0]+=a0*b0; acc[0][1]+=a0*b1; acc[0][2]+=a0*b2; acc[0][3]+=a0*b3;
      acc[1][0]+=a1*b0; acc[1][1]+=a1*b1; acc[1][2]+=a1*b2; acc[1][3]+=a1*b3;
      acc[2][0]+=a2*b0; acc[2][1]+=a2*b1; acc[2][2]+=a2*b2; acc[2][3]+=a2*b3;
      acc[3][0]+=a3*b0; acc[3][1]+=a3*b1; acc[3][2]+=a3*b2; acc[3][3]+=a3*b3;
    }
    __syncthreads();
  }
#pragma unroll
  for(int i=0;i<4;i++){
    int gm=tm+ty*4+i; if(gm>=M) continue;
#pragma unroll
    for(int j=0;j<4;j++){
      int gn=tn+tx*4+j; if(gn>=Nn) continue;
      float v=acc[i][j];
      if(bias) v += bias[gn];
      Cm[(size_t)gm*Nn+gn]=v;
    }
  }
}

__global__ void k_gemm_kv(const float* __restrict__ agg, const float* __restrict__ kv_w,
                          const int* __restrict__ topk, float* __restrict__ kvb){
  int z = blockIdx.z;                  // b*2+j
  int e = topk[z];
  gemm_abt_tile(agg + (size_t)(z>>1)*MAXTOT*CC, kv_w + (size_t)e*768*CC, nullptr,
                kvb + (size_t)z*MAXTOT*768, MAXTOT, 768, CC, blockIdx.x, blockIdx.y);
}

// ---------------- big fp32 GEMM: 128x128 tile, dims must be multiples ----------------
__global__ void k_gemm128(const float* __restrict__ A, const float* __restrict__ W,
                          const float* __restrict__ bias, float* __restrict__ Cm,
                          int Nn, int K){
  __shared__ float As[16][132];
  __shared__ float Ws[16][132];
  const int tx = threadIdx.x & 15, ty = threadIdx.x >> 4;
  const int tm = blockIdx.x*128, tn = blockIdx.y*128;
  const int lrow = threadIdx.x >> 1;
  const int lk = (threadIdx.x & 1)*8;
  float acc[8][8];
#pragma unroll
  for(int i=0;i<8;i++)
#pragma unroll
    for(int j=0;j<8;j++) acc[i][j]=0.f;
  for(int k0=0;k0<K;k0+=16){
    float4 a0 = *(const float4*)(A + (size_t)(tm+lrow)*K + k0+lk);
    float4 a1 = *(const float4*)(A + (size_t)(tm+lrow)*K + k0+lk+4);
    float4 b0 = *(const float4*)(W + (size_t)(tn+lrow)*K + k0+lk);
    float4 b1 = *(const float4*)(W + (size_t)(tn+lrow)*K + k0+lk+4);
    __syncthreads();
    As[lk+0][lrow]=a0.x; As[lk+1][lrow]=a0.y; As[lk+2][lrow]=a0.z; As[lk+3][lrow]=a0.w;
    As[lk+4][lrow]=a1.x; As[lk+5][lrow]=a1.y; As[lk+6][lrow]=a1.z; As[lk+7][lrow]=a1.w;
    Ws[lk+0][lrow]=b0.x; Ws[lk+1][lrow]=b0.y; Ws[lk+2][lrow]=b0.z; Ws[lk+3][lrow]=b0.w;
    Ws[lk+4][lrow]=b1.x; Ws[lk+5][lrow]=b1.y; Ws[lk+6][lrow]=b1.z; Ws[lk+7][lrow]=b1.w;
    __syncthreads();
#pragma unroll
    for(int kk=0;kk<16;kk++){
      float a[8], b[8];
#pragma unroll
      for(int i=0;i<8;i++) a[i]=As[kk][ty*8+i];
#pragma unroll
      for(int j=0;j<8;j++) b[j]=Ws[kk][tx*8+j];
#pragma unroll
      for(int i=0;i<8;i++)
#pragma unroll
        for(int j=0;j<8;j++) acc[i][j]+=a[i]*b[j];
    }
  }
  float bs[8];
#pragma unroll
  for(int j=0;j<8;j++) bs[j] = bias? bias[tn+tx*8+j] : 0.f;
#pragma unroll
  for(int i=0;i<8;i++){
    int gm = tm+ty*8+i;
    float* cp = Cm + (size_t)gm*Nn + tn + tx*8;
    *(float4*)(cp)   = make_float4(acc[i][0]+bs[0],acc[i][1]+bs[1],acc[i][2]+bs[2],acc[i][3]+bs[3]);
    *(float4*)(cp+4) = make_float4(acc[i][4]+bs[4],acc[i][5]+bs[5],acc[i][6]+bs[6],acc[i][7]+bs[7]);
  }
}

// ---------------- batched clustering ----------------
__global__ void k_init12(u64* __restrict__ dmaxkey12, float* __restrict__ allw12){
  int t = blockIdx.x*256 + threadIdx.x;
  if(t < 12) dmaxkey12[t] = 0ull;
  if(t < 12*320) allw12[t] = 0.f;
}

__global__ void k_sumsq_all(const float* __restrict__ xs, float* __restrict__ sumsq12, int fi0){
  int fi = fi0 + blockIdx.y;
  int row = blockIdx.x*4 + (threadIdx.x>>6);
  int lane = threadIdx.x & 63;
  const float* p = xs + (size_t)fi*N3*CC + (size_t)row*CC;
  float s=0.f;
  for(int c=lane;c<CC;c+=64){ float v=p[c]; s+=v*v; }
  s = wave_sum(s);
  if(lane==0) sumsq12[(size_t)fi*N3 + row]=s;
}

// fused symmetric Gram -> distance; upper-triangular 128-blocks, mirrored writes.
// Accumulation over k in the same order as before -> dist values bit-identical.
__global__ void k_gram_all(const float* __restrict__ xs, const float* __restrict__ sumsq12,
                           float* __restrict__ dist_base, u64* __restrict__ dmaxkey12, int fi0){
  const int fiL = blockIdx.y, fi = fi0 + fiL;
  const float* xr = xs + (size_t)fi*N3*CC;
  const float* sq = sumsq12 + (size_t)fi*N3;
  float* dist = dist_base + (size_t)fiL*N3*N3;
  int t = blockIdx.x, bi = 0;
  while(t >= NT3 - bi){ t -= NT3 - bi; bi++; }
  const int bj = bi + t;
  const int tm = bi*128, tn = bj*128;
  __shared__ float As[16][132];
  __shared__ float Ws[16][132];
  const int tx = threadIdx.x & 15, ty = threadIdx.x >> 4;
  const int lrow = threadIdx.x >> 1;
  const int lk = (threadIdx.x & 1)*8;
  float acc[8][8];
#pragma unroll
  for(int i=0;i<8;i++)
#pragma unroll
    for(int j=0;j<8;j++) acc[i][j]=0.f;
  for(int k0=0;k0<CC;k0+=16){
    float4 a0 = *(const float4*)(xr + (size_t)(tm+lrow)*CC + k0+lk);
    float4 a1 = *(const float4*)(xr + (size_t)(tm+lrow)*CC + k0+lk+4);
    float4 b0 = *(const float4*)(xr + (size_t)(tn+lrow)*CC + k0+lk);
    float4 b1 = *(const float4*)(xr + (size_t)(tn+lrow)*CC + k0+lk+4);
    __syncthreads();
    As[lk+0][lrow]=a0.x; As[lk+1][lrow]=a0.y; As[lk+2][lrow]=a0.z; As[lk+3][lrow]=a0.w;
    As[lk+4][lrow]=a1.x; As[lk+5][lrow]=a1.y; As[lk+6][lrow]=a1.z; As[lk+7][lrow]=a1.w;
    Ws[lk+0][lrow]=b0.x; Ws[lk+1][lrow]=b0.y; Ws[lk+2][lrow]=b0.z; Ws[lk+3][lrow]=b0.w;
    Ws[lk+4][lrow]=b1.x; Ws[lk+5][lrow]=b1.y; Ws[lk+6][lrow]=b1.z; Ws[lk+7][lrow]=b1.w;
    __syncthreads();
#pragma unroll
    for(int kk=0;kk<16;kk++){
      float a[8], b[8];
#pragma unroll
      for(int i=0;i<8;i++) a[i]=As[kk][ty*8+i];
#pragma unroll
      for(int j=0;j<8;j++) b[j]=Ws[kk][tx*8+j];
#pragma unroll
      for(int i=0;i<8;i++)
#pragma unroll
        for(int j=0;j<8;j++) acc[i][j]+=a[i]*b[j];
    }
  }
  u64 best = 0ull;
  float sqn[8];
#pragma unroll
  for(int j=0;j<8;j++) sqn[j] = sq[tn+tx*8+j];
#pragma unroll
  for(int i=0;i<8;i++){
    int gm = tm+ty*8+i;
    float sqm = sq[gm];
    float row[8];
#pragma unroll
    for(int j=0;j<8;j++){
      int gn = tn+tx*8+j;
      float d2 = (sqm + sqn[j]) - 2.f*acc[i][j];
      d2 = fmaxf(d2, 0.f);
      float dv = (d2 > 0.f) ? (sqrtf(d2) / 19.595917942265423f) : 0.f;
      row[j]=dv;
      unsigned u1=(unsigned)(gm*N3+gn), u2=(unsigned)(gn*N3+gm);
      u64 key = (((u64)__float_as_uint(dv))<<32) | (u1>u2?u1:u2);
      if(key > best) best = key;
    }
    float* dp = dist + (size_t)gm*N3 + tn + tx*8;
    *(float4*)(dp)   = make_float4(row[0],row[1],row[2],row[3]);
    *(float4*)(dp+4) = make_float4(row[4],row[5],row[6],row[7]);
  }
  if(bi != bj){
#pragma unroll
    for(int j=0;j<8;j++){
      int gn = tn+tx*8+j;
      float col[8];
#pragma unroll
      for(int i=0;i<8;i++){
        float d2 = (sq[tm+ty*8+i] + sqn[j]) - 2.f*acc[i][j];
        d2 = fmaxf(d2, 0.f);
        col[i] = (d2 > 0.f) ? (sqrtf(d2) / 19.595917942265423f) : 0.f;
      }
      float* dp = dist + (size_t)gn*N3 + tm + ty*8;
      *(float4*)(dp)   = make_float4(col[0],col[1],col[2],col[3]);
      *(float4*)(dp+4) = make_float4(col[4],col[5],col[6],col[7]);
    }
  }
  best = wave_max_u64(best);
  __shared__ u64 red[4];
  if((threadIdx.x&63)==0) red[threadIdx.x>>6]=best;
  __syncthreads();
  if(threadIdx.x==0){
    u64 m = red[0];
    if(red[1]>m) m=red[1];
    if(red[2]>m) m=red[2];
    if(red[3]>m) m=red[3];
    atomicMax(&dmaxkey12[fi], m);
  }
}

__global__ void k_dmax_fix_all(const u64* __restrict__ dmaxkey12, const float* __restrict__ xs,
                               double* __restrict__ dmaxd12, int fi0){
  if(threadIdx.x!=0) return;
  int fi = fi0 + blockIdx.x;
  unsigned pair = (unsigned)(dmaxkey12[fi] & 0xFFFFFFFFull);
  int i = pair / N3, j = pair % N3;
  dmaxd12[fi] = dist64(xs + (size_t)fi*N3*CC, i, j);
}

// wave per row: kk-NN via f32 keys, exact f64 recompute of selected distances
__global__ void k_knn_all(const float* __restrict__ dist_base, const float* __restrict__ xs,
                          const int* __restrict__ kknum, double* __restrict__ dens12, int fi0){
  const int fiL = blockIdx.y, fi = fi0 + fiL;
  const float* xr = xs + (size_t)fi*N3*CC;
  const float* dist = dist_base + (size_t)fiL*N3*N3;
  int row = blockIdx.x*4 + (threadIdx.x>>6);
  int lane = threadIdx.x & 63;
  int kk = kknum[fi];
  const float* dr = dist + (size_t)row*N3;
  u64 loc[17];
#pragma unroll
  for(int i=0;i<17;i++) loc[i]=~0ull;
  for(int j=lane;j<N3;j+=64){
    u64 key = (((u64)__float_as_uint(dr[j]))<<32) | (unsigned)j;
    if(key < loc[16]){
      u64 cur=key;
#pragma unroll
      for(int p=0;p<17;p++){
        u64 old=loc[p];
        bool ins = cur<old;
        loc[p] = ins?cur:old;
        cur    = ins?old:cur;
      }
    }
  }
  int myj = -1;
  for(int it=0; it<kk; it++){
    u64 k = wave_min_u64(loc[0]);
    int owner = (int)(k & 63u);          // j was loaded by lane j%64
    if(lane==owner){
#pragma unroll
      for(int p=0;p<16;p++) loc[p]=loc[p+1];
      loc[16]=~0ull;
    }
    if(it==lane) myj = (int)(k & 0xFFFFFFFFull);
  }
  double nd2 = 0.0;
  if(lane < kk && myj >= 0){
    double dd = dist64(xr, row, myj);
    nd2 = dd*dd;
  }
  double ssum = wave_sum_d(nd2);
  if(lane==0){
    double mean = ssum/(double)kk;
    double d = exp(-mean);
    // modern JAX (jax_threefry_partitionable=True): bits[i] = o0 ^ o1,
    // (o0,o1) = threefry(fold_in(key(42), fi), (0, i))
    uint32_t k0,k1,o0,o1;
    threefry(0u,42u, 0u,(uint32_t)fi, k0,k1);
    threefry(k0,k1, 0u,(uint32_t)row, o0,o1);
    uint32_t bits = o0 ^ o1;
    float u = __uint_as_float((bits>>9)|0x3F800000u) - 1.0f;
    dens12[(size_t)fi*N3 + row] = d + (double)u*1e-6;
  }
}

__global__ void k_dmin_all(const float* __restrict__ dist_base, const float* __restrict__ xs,
                           const double* __restrict__ dens12, const double* __restrict__ dmaxd12,
                           double* __restrict__ scorec12, int fi0){
  const int fiL = blockIdx.y, fi = fi0 + fiL;
  const float* xr = xs + (size_t)fi*N3*CC;
  const float* dist = dist_base + (size_t)fiL*N3*N3;
  const double* dens = dens12 + (size_t)fi*N3;
  int row = blockIdx.x*4+(threadIdx.x>>6);
  int lane = threadIdx.x & 63;
  double di = dens[row];
  const float* dr = dist + (size_t)row*N3;
  u64 best = ~0ull;
  for(int j=lane;j<N3;j+=64){
    if(dens[j] > di){
      u64 key = (((u64)__float_as_uint(dr[j]))<<32) | (unsigned)j;
      if(key < best) best = key;
    }
  }
  best = wave_min_u64(best);
  if(lane==0){
    double dm;
    if(best == ~0ull) dm = dmaxd12[fi];
    else dm = dist64(xr, row, (int)(best & 0xFFFFFFFFull));
    scorec12[(size_t)fi*N3 + row] = dm*di;
  }
}

// rank among scores (desc, tie -> lower index) == lax.top_k order
__global__ void k_centers_all(const double* __restrict__ scorec12, const int* __restrict__ aggnum,
                              int* __restrict__ centers12, int fi0){
  const int fi = fi0 + blockIdx.y;
  const double* scorec = scorec12 + (size_t)fi*N3;
  int t = blockIdx.x*256+threadIdx.x;
  int num = aggnum[fi];
  double si = scorec[t];
  __shared__ double tile[256];
  int rank=0;
  for(int j0=0;j0<N3;j0+=256){
    tile[threadIdx.x]=scorec[j0+threadIdx.x];
    __syncthreads();
#pragma unroll 8
    for(int jj=0;jj<256;jj++){
      double sj=tile[jj]; int j=j0+jj;
      rank += (sj>si) || (sj==si && j<t);
    }
    __syncthreads();
  }
  if(rank<num) centers12[fi*320 + rank]=t;
}

__global__ void k_assign_all(const float* __restrict__ dist_base, const float* __restrict__ xs,
                             const int* __restrict__ centers12, const int* __restrict__ aggnum,
                             int* __restrict__ idxc12, int fi0){
  const int fiL = blockIdx.y, fi = fi0 + fiL;
  const float* xr = xs + (size_t)fi*N3*CC;
  const float* dist = dist_base + (size_t)fiL*N3*N3;
  const int* centers = centers12 + fi*320;
  int t = blockIdx.x*256+threadIdx.x;
  int num = aggnum[fi];
  float bd=3.4e38f; int bc=0;
  float rd=3.4e38f; int rc=-1;
  for(int c=0;c<num;c++){
    float v = dist[(size_t)centers[c]*N3 + t];
    if(v<bd){ rd=bd; rc=bc; bd=v; bc=c; }
    else if(v<rd){ rd=v; rc=c; }
  }
  // f64 refine: compare best vs runner-up exactly (argmin-first semantics)
  if(rc>=0 && (rd-bd) < 1e-3f){
    double d1 = dist64(xr, centers[bc], t);
    double d2 = dist64(xr, centers[rc], t);
    if(d2 < d1 || (d2==d1 && rc<bc)) bc = rc;
  }
  idxc12[(size_t)fi*N3 + t]=bc;
}

__global__ void k_fixcenters_all(const int* __restrict__ centers12, const int* __restrict__ aggnum,
                                 int* __restrict__ idxc12, int fi0){
  const int fi = fi0 + blockIdx.y;
  int c = blockIdx.x*256+threadIdx.x;
  if(c < aggnum[fi]) idxc12[(size_t)fi*N3 + centers12[fi*320 + c]]=c;
}

__global__ void k_allw_all(const int* __restrict__ idxc12, const float* __restrict__ ss_f,
                           float* __restrict__ allw12, int fi0){
  const int fi = fi0 + blockIdx.y;
  int t = blockIdx.x*256+threadIdx.x;
  atomicAdd(&allw12[fi*320 + idxc12[(size_t)fi*N3 + t]], ss_f[(size_t)fi*N3 + t]);
}

__global__ void k_scatter_all(const float* __restrict__ xs, const int* __restrict__ idxc12,
                              const float* __restrict__ ss_f, const float* __restrict__ allw12,
                              float* __restrict__ agg, const int* __restrict__ offs, int fi0){
  const int fi = fi0 + blockIdx.y;
  int idx = blockIdx.x*256+threadIdx.x;
  int t = idx / CC, c = idx % CC;
  int cl = idxc12[(size_t)fi*N3 + t];
  float wgt = ss_f[(size_t)fi*N3 + t]/(allw12[fi*320 + cl]+1e-6f);
  float* aggb = agg + (size_t)(fi/3)*MAXTOT*CC;
  atomicAdd(&aggb[(size_t)(offs[fi] + cl)*CC + c], xs[(size_t)fi*N3*CC + idx]*wgt);
}

// ---------------- attention: thread = (b,h,n), online softmax over <=960 keys ----------------
__global__ void k_attn(const float* __restrict__ q, const float* __restrict__ kv,
                       const int* __restrict__ numtot, const float* __restrict__ wts,
                       const int* __restrict__ topk, float* __restrict__ res){
  int b = blockIdx.z, h = blockIdx.y;
  int n = blockIdx.x*256 + threadIdx.x;
  int ntot = numtot[b];
  __shared__ float4 kt4[32][12];
  __shared__ float4 vt4[32][12];
  float qv[48];
  const float* qp = q + ((size_t)b*NN + n)*CC + h*DH;
#pragma unroll
  for(int d=0;d<48;d++) qv[d]=qp[d];
  float outa[48];
#pragma unroll
  for(int d=0;d<48;d++) outa[d]=0.f;
  const float sc = 0.14433756729740643f;   // 48^-0.5
  for(int j=0;j<2;j++){
    const float* kvb = kv + (size_t)(b*2+j)*MAXTOT*768;
    float wexp = wts[b*EE + topk[b*2+j]];
    float mrun=-3.4e38f, lrun=0.f;
    float acc[48];
#pragma unroll
    for(int d=0;d<48;d++) acc[d]=0.f;
    for(int m0=0;m0<ntot;m0+=32){
      __syncthreads();
      for(int l=threadIdx.x;l<384;l+=256){
        int mm=l/12, d4=l%12;
        int m=m0+mm;
        float4 kf=make_float4(0,0,0,0), vf=make_float4(0,0,0,0);
        if(m<ntot){
          kf = *(const float4*)(kvb + (size_t)m*768 + h*DH + 4*d4);
          vf = *(const float4*)(kvb + (size_t)m*768 + 384 + h*DH + 4*d4);
        }
        kt4[mm][d4]=kf; vt4[mm][d4]=vf;
      }
      __syncthreads();
      int mcnt = min(32, ntot-m0);
      for(int mm=0;mm<mcnt;mm++){
        float s=0.f;
#pragma unroll
        for(int d4=0;d4<12;d4++){
          float4 kf = kt4[mm][d4];
          s += qv[4*d4+0]*kf.x; s += qv[4*d4+1]*kf.y;
          s += qv[4*d4+2]*kf.z; s += qv[4*d4+3]*kf.w;
        }
        s *= sc;
        if(s > mrun){
          float rs = expf(mrun - s);
          lrun *= rs;
#pragma unroll
          for(int d=0;d<48;d++) acc[d]*=rs;
          mrun = s;
        }
        float p = expf(s - mrun);
        lrun += p;
#pragma unroll
        for(int d4=0;d4<12;d4++){
          float4 vf = vt4[mm][d4];
          acc[4*d4+0]+=p*vf.x; acc[4*d4+1]+=p*vf.y;
          acc[4*d4+2]+=p*vf.z; acc[4*d4+3]+=p*vf.w;
        }
      }
    }
    float inv = 1.f/lrun;
#pragma unroll
    for(int d=0;d<48;d++) outa[d] += wexp*(acc[d]*inv);
  }
  float* rp = res + ((size_t)b*NN + n)*CC + h*DH;
#pragma unroll
  for(int d=0;d<48;d++) rp[d]=outa[d];
}

// ---------------- host ----------------
extern "C" void kernel_launch(void* const* d_in, const int* in_sizes, int n_in,
                              void* d_out, int out_size, void* d_ws, size_t ws_size,
                              hipStream_t stream){
  (void)in_sizes; (void)n_in; (void)out_size;
  const float* x       = (const float*)d_in[0];
  const float* q_w     = (const float*)d_in[1];
  const float* kv_w    = (const float*)d_in[2];
  const float* route_w = (const float*)d_in[3];
  const float* route_b = (const float*)d_in[4];
  const float* score_w = (const float*)d_in[5];
  const float* score_b = (const float*)d_in[6];
  const float* rscale_w= (const float*)d_in[7];
  const float* rscale_b= (const float*)d_in[8];
  const float* proj_w  = (const float*)d_in[9];
  const float* proj_b  = (const float*)d_in[10];
  float* out = (float*)d_out;

  char* w = (char*)d_ws;
  size_t o = 0;
  auto carve = [&](size_t bytes)->char*{
    char* p = w + o;
    o += (bytes + 255) & ~(size_t)255;
    return p;
  };
  double* score_d = (double*)carve((size_t)BB*NN*8);
  u64*   keys    = (u64*)carve((size_t)BB*NN*8);
  int*   order   = (int*)carve((size_t)BB*NN*4);
  double* ss_d   = (double*)carve((size_t)BB*NN*8);
  float* ss_f    = (float*)carve((size_t)BB*NN*4);
  double* meanx  = (double*)carve((size_t)BB*CC*8);
  double* scales = (double*)carve(12*8);
  int*   aggnum  = (int*)carve(12*4);
  int*   kknum   = (int*)carve(12*4);
  int*   offs    = (int*)carve(12*4);
  int*   numtot  = (int*)carve(BB*4);
  float* wts     = (float*)carve(BB*EE*4);
  int*   topk    = (int*)carve(BB*2*4);
  u64*   dmaxkey12 = (u64*)carve(12*8);
  double* dmaxd12  = (double*)carve(12*8);
  float* sumsq12   = (float*)carve((size_t)12*N3*4);
  double* dens12   = (double*)carve((size_t)12*N3*8);
  double* scorec12 = (double*)carve((size_t)12*N3*8);
  int*   centers12 = (int*)carve((size_t)12*320*4);
  int*   idxc12    = (int*)carve((size_t)12*N3*4);
  float* allw12    = (float*)carve((size_t)12*320*4);
  float* xs      = (float*)carve((size_t)BB*NN*CC*4);
  float* agg     = (float*)carve((size_t)BB*MAXTOT*CC*4);

  // union region: dist[NB] during clustering, then qbuf+kvb+res afterwards
  const size_t distB = (size_t)N3*N3*4;                 // 37,748,736
  const size_t qbufB = (size_t)BB*NN*CC*4;              // 56,623,104
  const size_t kvbB  = (size_t)BB*2*MAXTOT*768*4;       // 23,592,960
  const size_t resB  = qbufB;
  const size_t tailB = qbufB + kvbB + resB;
  size_t avail = (ws_size > o) ? (ws_size - o) : 0;
  if(avail < tailB) return;                             // workspace too small -> visible failure
  int NB = (int)(avail / distB); if(NB > 12) NB = 12;   // avail>=tailB => NB>=3
  size_t uB = (size_t)NB*distB; if(uB < tailB) uB = tailB;
  char* ub = carve(uB);
  float* dist_base = (float*)ub;
  float* qbuf = (float*)ub;
  float* kvb  = (float*)(ub + qbufB);
  float* res  = (float*)(ub + qbufB + kvbB);
  if(o > ws_size) return;

  dim3 b256(256);
  k_score <<<dim3(BB*NN/4), b256, 0, stream>>>(x, score_w, score_b, score_d, keys);
  k_rank  <<<dim3(NN/256, BB), b256, 0, stream>>>(keys, score_d, order, ss_d, ss_f);
  k_gather<<<dim3((unsigned)((size_t)BB*NN*96/256)), b256, 0, stream>>>(x, order, xs);
  k_zero_d<<<dim3((BB*CC+255)/256), b256, 0, stream>>>(meanx, BB*CC);
  k_meanx <<<dim3(BB*16), dim3(CC), 0, stream>>>(x, meanx);
  k_scales<<<dim3(12), b256, 0, stream>>>(ss_d, rscale_w, rscale_b, scales);
  k_aggnum<<<dim3(1), dim3(64), 0, stream>>>(scales, aggnum, kknum, offs, numtot);
  k_weights<<<dim3(1), dim3(64), 0, stream>>>(meanx, route_w, route_b, wts, topk);
  k_zero  <<<dim3((BB*MAXTOT*CC+255)/256), b256, 0, stream>>>(agg, BB*MAXTOT*CC);
  k_init12<<<dim3(15), b256, 0, stream>>>(dmaxkey12, allw12);

  for(int g=0; g<12; g+=NB){
    int ng = (12-g < NB) ? (12-g) : NB;
    k_sumsq_all <<<dim3(N3/4, ng), b256, 0, stream>>>(xs, sumsq12, g);
    k_gram_all  <<<dim3(NTRI, ng), b256, 0, stream>>>(xs, sumsq12, dist_base, dmaxkey12, g);
    k_dmax_fix_all<<<dim3(ng), dim3(64), 0, stream>>>(dmaxkey12, xs, dmaxd12, g);
    k_knn_all   <<<dim3(N3/4, ng), b256, 0, stream>>>(dist_base, xs, kknum, dens12, g);
    k_dmin_all  <<<dim3(N3/4, ng), b256, 0, stream>>>(dist_base, xs, dens12, dmaxd12, scorec12, g);
    k_centers_all<<<dim3(N3/256, ng), b256, 0, stream>>>(scorec12, aggnum, centers12, g);
    k_assign_all<<<dim3(N3/256, ng), b256, 0, stream>>>(dist_base, xs, centers12, aggnum, idxc12, g);
    k_fixcenters_all<<<dim3(2, ng), b256, 0, stream>>>(centers12, aggnum, idxc12, g);
    k_allw_all  <<<dim3(N3/256, ng), b256, 0, stream>>>(idxc12, ss_f, allw12, g);
    k_scatter_all<<<dim3(N3*CC/256, ng), b256, 0, stream>>>(xs, idxc12, ss_f, allw12, agg, offs, g);
  }

  k_gemm128<<<dim3(BB*NN/128, CC/128), b256, 0, stream>>>(x, q_w, nullptr, qbuf, CC, CC);
  k_gemm_kv<<<dim3(MAXTOT/64, 768/64, BB*2), b256, 0, stream>>>(agg, kv_w, topk, kvb);
  k_attn   <<<dim3(NN/256, HH, BB), b256, 0, stream>>>(qbuf, kvb, numtot, wts, topk, res);
  k_gemm128<<<dim3(BB*NN/128, CC/128), b256, 0, stream>>>(res, proj_w, proj_b, out, CC, CC);
}

// Round 7
// 4046.518 us; speedup vs baseline: 6.7867x; 1.0098x over previous
//
#include <hip/hip_runtime.h>
#include <stdint.h>

#define BB 4
#define NN 9216
#define CC 384
#define HH 8
#define DH 48
#define EE 4
#define N3 3072
#define MAXTOT 960
#define NT3 24          // N3/128
#define NTRI 300        // NT3*(NT3+1)/2

typedef unsigned long long u64;

// ---------------- wave helpers (wave64) ----------------
__device__ __forceinline__ float wave_sum(float v){
#pragma unroll
  for(int m=32;m>0;m>>=1) v += __shfl_xor(v,m,64);
  return v;
}
__device__ __forceinline__ double wave_sum_d(double v){
#pragma unroll
  for(int m=32;m>0;m>>=1) v += __shfl_xor(v,m,64);
  return v;
}
__device__ __forceinline__ u64 wave_min_u64(u64 k){
#pragma unroll
  for(int m=32;m>0;m>>=1){
    unsigned lo = __shfl_xor((unsigned)k, m, 64);
    unsigned hi = __shfl_xor((unsigned)(k>>32), m, 64);
    u64 o = ((u64)hi<<32)|lo;
    if(o < k) k = o;
  }
  return k;
}
__device__ __forceinline__ u64 wave_max_u64(u64 k){
#pragma unroll
  for(int m=32;m>0;m>>=1){
    unsigned lo = __shfl_xor((unsigned)k, m, 64);
    unsigned hi = __shfl_xor((unsigned)(k>>32), m, 64);
    u64 o = ((u64)hi<<32)|lo;
    if(o > k) k = o;
  }
  return k;
}

// exact f64 distance between token rows i,j of xr (f32 storage promoted)
__device__ double dist64(const float* __restrict__ xr, int i, int j){
  const float* a = xr + (size_t)i*CC;
  const float* b = xr + (size_t)j*CC;
  double s = 0.0;
  for(int c=0;c<CC;c++){
    double d = (double)a[c] - (double)b[c];
    s += d*d;
  }
  if(!(s > 0.0)) return 0.0;
  return sqrt(s) / 19.595917942265423;   // / sqrt(384), double
}

// ---------------- JAX threefry2x32 (20 rounds), bit-exact ----------------
__device__ __forceinline__ void threefry(uint32_t k0, uint32_t k1, uint32_t x0, uint32_t x1,
                                         uint32_t& o0, uint32_t& o1){
  const uint32_t ks0=k0, ks1=k1, ks2=k0^k1^0x1BD11BDAu;
  const int rotA[4]={13,15,26,6}, rotB[4]={17,29,16,24};
  x0 += ks0; x1 += ks1;
#pragma unroll
  for(int g=0; g<5; g++){
    const int* rot = (g&1)? rotB : rotA;
#pragma unroll
    for(int i=0;i<4;i++){
      x0 += x1;
      x1 = (x1<<rot[i])|(x1>>(32-rot[i]));
      x1 ^= x0;
    }
    uint32_t a = (g%3==0)?ks1:((g%3==1)?ks2:ks0);          // ks[(g+1)%3]
    uint32_t b = (g%3==0)?ks2:((g%3==1)?ks0:ks1);          // ks[(g+2)%3]
    x0 += a; x1 += b + (uint32_t)(g+1);
  }
  o0=x0; o1=x1;
}

// ---------------- score (f64) + sort keys ----------------
__global__ void k_score(const float* __restrict__ x, const float* __restrict__ sw,
                        const float* __restrict__ sb, double* __restrict__ score_d,
                        u64* __restrict__ keys){
  int row = blockIdx.x*4 + (threadIdx.x>>6);
  int lane = threadIdx.x & 63;
  const float* xr = x + (size_t)row*CC;
  double s = 0.0;
  for(int c=lane;c<CC;c+=64) s += (double)xr[c]*(double)sw[c];
  s = wave_sum_d(s);
  if(lane==0){
    double sc = exp(s + (double)sb[0]);    // > 0 -> double bits monotone
    score_d[row] = sc;
    keys[row] = (u64)__double_as_longlong(sc);
  }
}

// rank = stable-ascending position (score asc, index asc)
__global__ void k_rank(const u64* __restrict__ keys, const double* __restrict__ score_d,
                       int* __restrict__ order, double* __restrict__ ss_d,
                       float* __restrict__ ss_f){
  int b = blockIdx.y;
  int i = blockIdx.x*256 + threadIdx.x;
  __shared__ u64 tile[256];
  u64 ki = keys[(size_t)b*NN + i];
  int rank = 0;
  for(int j0=0;j0<NN;j0+=256){
    tile[threadIdx.x] = keys[(size_t)b*NN + j0 + threadIdx.x];
    __syncthreads();
#pragma unroll 8
    for(int jj=0;jj<256;jj++){
      u64 kj = tile[jj]; int j=j0+jj;
      rank += (kj < ki) || (kj == ki && j < i);
    }
    __syncthreads();
  }
  double sd = score_d[(size_t)b*NN + i];
  order[(size_t)b*NN + rank] = i;
  ss_d[(size_t)b*NN + rank] = sd;
  ss_f[(size_t)b*NN + rank] = (float)sd;
}

__global__ void k_gather(const float* __restrict__ x, const int* __restrict__ order,
                         float* __restrict__ xs){
  size_t idx = (size_t)blockIdx.x*256 + threadIdx.x;
  int c4 = (int)(idx % 96);
  size_t row = idx / 96;
  int b = (int)(row / NN);
  int src = order[row];
  ((float4*)xs)[row*96 + c4] = ((const float4*)x)[((size_t)b*NN + src)*96 + c4];
}

__global__ void k_zero(float* __restrict__ p, int n){
  int i = blockIdx.x*256 + threadIdx.x;
  if(i<n) p[i]=0.f;
}
__global__ void k_zero_d(double* __restrict__ p, int n){
  int i = blockIdx.x*256 + threadIdx.x;
  if(i<n) p[i]=0.0;
}

__global__ void k_meanx(const float* __restrict__ x, double* __restrict__ meanx){
  int b = blockIdx.x >> 4, chunk = blockIdx.x & 15;
  int c = threadIdx.x;   // 384 threads
  const float* base = x + ((size_t)b*NN + (size_t)chunk*576)*CC + c;
  double s=0.0;
  for(int n=0;n<576;n++) s += (double)base[(size_t)n*CC];
  atomicAdd(&meanx[b*CC+c], s);
}

__global__ void k_scales(const double* __restrict__ ss_d, const float* __restrict__ rw,
                         const float* __restrict__ rb, double* __restrict__ scales){
  int b = blockIdx.x/3, r = blockIdx.x%3;
  double s=0.0;
  for(int t=threadIdx.x;t<N3;t+=256) s += ss_d[(size_t)b*NN + r*N3 + t]*(double)rw[r*N3+t];
  __shared__ double red[4];
  s = wave_sum_d(s);
  if((threadIdx.x&63)==0) red[threadIdx.x>>6]=s;
  __syncthreads();
  if(threadIdx.x==0) scales[b*3+r] = red[0]+red[1]+red[2]+red[3] + (double)rb[r];
}

__global__ void k_aggnum(const double* __restrict__ scales, int* aggnum, int* kknum,
                         int* offs, int* numtot){
  int b = threadIdx.x;
  if(b >= BB) return;
  double s0=scales[b*3+0], s1=scales[b*3+1], s2=scales[b*3+2];
  double m = fmax(s0, fmax(s1,s2));
  double e0=exp(s0-m), e1=exp(s1-m), e2=exp(s2-m);
  double den=e0+e1+e2;
  int off=0;
  for(int r=0;r<3;r++){
    double e = (r==0)?e0:((r==1)?e1:e2);
    double v = 320.0*(e/den);
    v = fmin(fmax(v,16.0),320.0);
    int num=(int)v;                      // trunc toward 0, positive
    int kk=(int)sqrt((double)num);
    while((kk+1)*(kk+1)<=num) kk++;
    while(kk>1 && kk*kk>num) kk--;
    if(kk<1) kk=1;
    aggnum[b*3+r]=num; kknum[b*3+r]=kk; offs[b*3+r]=off; off+=num;
  }
  numtot[b]=off;
}

__global__ void k_weights(const double* __restrict__ meanx, const float* __restrict__ route_w,
                          const float* __restrict__ route_b, float* __restrict__ wts,
                          int* __restrict__ topk){
  __shared__ double wd[BB*EE];
  int t = threadIdx.x;
  if(t < BB*EE){
    int b=t/EE, e=t%EE;
    double s=0.0;
    for(int c=0;c<CC;c++) s += (meanx[b*CC+c]*(1.0/NN))*(double)route_w[e*CC+c];
    double w = 1.0/(1.0+exp(-(s+(double)route_b[e])));
    wd[t]=w;
    wts[t]=(float)w;
  }
  __syncthreads();
  if(t<BB){
    int b=t; int i1=0; double best=-1e300;
    for(int e=0;e<EE;e++){ double w=wd[b*EE+e]; if(w>best){best=w;i1=e;} }
    int i2=-1; double b2=-1e300;
    for(int e=0;e<EE;e++){ if(e==i1) continue; double w=wd[b*EE+e]; if(w>b2){b2=w;i2=e;} }
    topk[b*2]=i1; topk[b*2+1]=i2;
  }
}

// ---------------- small fp32 C = A * W^T (64 tile, guarded) ----------------
__device__ __forceinline__ void gemm_abt_tile(const float* __restrict__ A, const float* __restrict__ W,
    const float* __restrict__ bias, float* __restrict__ Cm,
    int M, int Nn, int K, int bx, int by){
  __shared__ float As[16][68];
  __shared__ float Ws[16][68];
  const int tx = threadIdx.x & 15, ty = threadIdx.x >> 4;
  const int tm = bx*64, tn = by*64;
  float acc[4][4];
#pragma unroll
  for(int i=0;i<4;i++)
#pragma unroll
    for(int j=0;j<4;j++) acc[i][j]=0.f;
  for(int k0=0;k0<K;k0+=16){
#pragma unroll
    for(int t=0;t<4;t++){
      int l = threadIdx.x + t*256;
      int r = l>>4, kk=l&15;
      int gm = tm+r;
      As[kk][r] = (gm<M)? A[(size_t)gm*K + k0+kk] : 0.f;
    }
#pragma unroll
    for(int t=0;t<4;t++){
      int l = threadIdx.x + t*256;
      int r=l>>4, kk=l&15;
      int gn = tn+r;
      Ws[kk][r] = (gn<Nn)? W[(size_t)gn*K + k0+kk] : 0.f;
    }
    __syncthreads();
#pragma unroll
    for(int kk=0;kk<16;kk++){
      float a0=As[kk][ty*4+0],a1=As[kk][ty*4+1],a2=As[kk][ty*4+2],a3=As[kk][ty*4+3];
      float b0=Ws[kk][tx*4+0],b1=Ws[kk][tx*4+1],b2=Ws[kk][tx*4+2],b3=Ws[kk][tx*4+3];
      acc[0][0]+=a0*b0; acc[0][1]+=a0*b1; acc[0][2]+=a0*b2; acc[0][3]+=a0*b3;
      acc[1][0]+=a1*b0; acc[1][1]+=a1*b1; acc[1][2]+=a1*b2; acc[1][3]+=a1*b3;
      acc[2][0]+=a2*b0; acc[2][1]+=a2*b1; acc[2][2]+=a2*b2; acc[2][3]+=a2*b3;
      acc[3][0]+=a3*b0; acc[3][1]+=a3*b1; acc[3][2]+=a3*b2; acc[3][3]+=a3*b3;
    }
    __syncthreads();
  }
#pragma unroll
  for(int i=0;i<4;i++){
    int gm=tm+ty*4+i; if(gm>=M) continue;
#pragma unroll
    for(int j=0;j<4;j++){
      int gn=tn+tx*4+j; if(gn>=Nn) continue;
      float v=acc[i][j];
      if(bias) v += bias[gn];
      Cm[(size_t)gm*Nn+gn]=v;
    }
  }
}

__global__ __launch_bounds__(256, 2)
void k_gemm_kv(const float* __restrict__ agg, const float* __restrict__ kv_w,
               const int* __restrict__ topk, float* __restrict__ kvb){
  int z = blockIdx.z;                  // b*2+j
  int e = topk[z];
  gemm_abt_tile(agg + (size_t)(z>>1)*MAXTOT*CC, kv_w + (size_t)e*768*CC, nullptr,
                kvb + (size_t)z*MAXTOT*768, MAXTOT, 768, CC, blockIdx.x, blockIdx.y);
}

// ---------------- big fp32 GEMM: 128x128 tile, dims must be multiples ----------------
__global__ __launch_bounds__(256, 2)
void k_gemm128(const float* __restrict__ A, const float* __restrict__ W,
               const float* __restrict__ bias, float* __restrict__ Cm,
               int Nn, int K){
  __shared__ float As[16][132];
  __shared__ float Ws[16][132];
  const int tx = threadIdx.x & 15, ty = threadIdx.x >> 4;
  const int tm = blockIdx.x*128, tn = blockIdx.y*128;
  const int lrow = threadIdx.x >> 1;
  const int lk = (threadIdx.x & 1)*8;
  float acc[8][8];
#pragma unroll
  for(int i=0;i<8;i++)
#pragma unroll
    for(int j=0;j<8;j++) acc[i][j]=0.f;
  for(int k0=0;k0<K;k0+=16){
    float4 a0 = *(const float4*)(A + (size_t)(tm+lrow)*K + k0+lk);
    float4 a1 = *(const float4*)(A + (size_t)(tm+lrow)*K + k0+lk+4);
    float4 b0 = *(const float4*)(W + (size_t)(tn+lrow)*K + k0+lk);
    float4 b1 = *(const float4*)(W + (size_t)(tn+lrow)*K + k0+lk+4);
    __syncthreads();
    As[lk+0][lrow]=a0.x; As[lk+1][lrow]=a0.y; As[lk+2][lrow]=a0.z; As[lk+3][lrow]=a0.w;
    As[lk+4][lrow]=a1.x; As[lk+5][lrow]=a1.y; As[lk+6][lrow]=a1.z; As[lk+7][lrow]=a1.w;
    Ws[lk+0][lrow]=b0.x; Ws[lk+1][lrow]=b0.y; Ws[lk+2][lrow]=b0.z; Ws[lk+3][lrow]=b0.w;
    Ws[lk+4][lrow]=b1.x; Ws[lk+5][lrow]=b1.y; Ws[lk+6][lrow]=b1.z; Ws[lk+7][lrow]=b1.w;
    __syncthreads();
#pragma unroll
    for(int kk=0;kk<16;kk++){
      float a[8], b[8];
#pragma unroll
      for(int i=0;i<8;i++) a[i]=As[kk][ty*8+i];
#pragma unroll
      for(int j=0;j<8;j++) b[j]=Ws[kk][tx*8+j];
#pragma unroll
      for(int i=0;i<8;i++)
#pragma unroll
        for(int j=0;j<8;j++) acc[i][j]+=a[i]*b[j];
    }
  }
  float bs[8];
#pragma unroll
  for(int j=0;j<8;j++) bs[j] = bias? bias[tn+tx*8+j] : 0.f;
#pragma unroll
  for(int i=0;i<8;i++){
    int gm = tm+ty*8+i;
    float* cp = Cm + (size_t)gm*Nn + tn + tx*8;
    *(float4*)(cp)   = make_float4(acc[i][0]+bs[0],acc[i][1]+bs[1],acc[i][2]+bs[2],acc[i][3]+bs[3]);
    *(float4*)(cp+4) = make_float4(acc[i][4]+bs[4],acc[i][5]+bs[5],acc[i][6]+bs[6],acc[i][7]+bs[7]);
  }
}

// ---------------- batched clustering ----------------
__global__ void k_init12(u64* __restrict__ dmaxkey12, float* __restrict__ allw12){
  int t = blockIdx.x*256 + threadIdx.x;
  if(t < 12) dmaxkey12[t] = 0ull;
  if(t < 12*320) allw12[t] = 0.f;
}

__global__ void k_sumsq_all(const float* __restrict__ xs, float* __restrict__ sumsq12, int fi0){
  int fi = fi0 + blockIdx.y;
  int row = blockIdx.x*4 + (threadIdx.x>>6);
  int lane = threadIdx.x & 63;
  const float* p = xs + (size_t)fi*N3*CC + (size_t)row*CC;
  float s=0.f;
  for(int c=lane;c<CC;c+=64){ float v=p[c]; s+=v*v; }
  s = wave_sum(s);
  if(lane==0) sumsq12[(size_t)fi*N3 + row]=s;
}

// fused symmetric Gram -> distance; upper-triangular 128-blocks, mirrored writes.
// Accumulation over k in the same order as before -> dist values bit-identical.
__global__ __launch_bounds__(256, 2)
void k_gram_all(const float* __restrict__ xs, const float* __restrict__ sumsq12,
                float* __restrict__ dist_base, u64* __restrict__ dmaxkey12, int fi0){
  const int fiL = blockIdx.y, fi = fi0 + fiL;
  const float* xr = xs + (size_t)fi*N3*CC;
  const float* sq = sumsq12 + (size_t)fi*N3;
  float* dist = dist_base + (size_t)fiL*N3*N3;
  int t = blockIdx.x, bi = 0;
  while(t >= NT3 - bi){ t -= NT3 - bi; bi++; }
  const int bj = bi + t;
  const int tm = bi*128, tn = bj*128;
  __shared__ float As[16][132];
  __shared__ float Ws[16][132];
  const int tx = threadIdx.x & 15, ty = threadIdx.x >> 4;
  const int lrow = threadIdx.x >> 1;
  const int lk = (threadIdx.x & 1)*8;
  float acc[8][8];
#pragma unroll
  for(int i=0;i<8;i++)
#pragma unroll
    for(int j=0;j<8;j++) acc[i][j]=0.f;
  for(int k0=0;k0<CC;k0+=16){
    float4 a0 = *(const float4*)(xr + (size_t)(tm+lrow)*CC + k0+lk);
    float4 a1 = *(const float4*)(xr + (size_t)(tm+lrow)*CC + k0+lk+4);
    float4 b0 = *(const float4*)(xr + (size_t)(tn+lrow)*CC + k0+lk);
    float4 b1 = *(const float4*)(xr + (size_t)(tn+lrow)*CC + k0+lk+4);
    __syncthreads();
    As[lk+0][lrow]=a0.x; As[lk+1][lrow]=a0.y; As[lk+2][lrow]=a0.z; As[lk+3][lrow]=a0.w;
    As[lk+4][lrow]=a1.x; As[lk+5][lrow]=a1.y; As[lk+6][lrow]=a1.z; As[lk+7][lrow]=a1.w;
    Ws[lk+0][lrow]=b0.x; Ws[lk+1][lrow]=b0.y; Ws[lk+2][lrow]=b0.z; Ws[lk+3][lrow]=b0.w;
    Ws[lk+4][lrow]=b1.x; Ws[lk+5][lrow]=b1.y; Ws[lk+6][lrow]=b1.z; Ws[lk+7][lrow]=b1.w;
    __syncthreads();
#pragma unroll
    for(int kk=0;kk<16;kk++){
      float a[8], b[8];
#pragma unroll
      for(int i=0;i<8;i++) a[i]=As[kk][ty*8+i];
#pragma unroll
      for(int j=0;j<8;j++) b[j]=Ws[kk][tx*8+j];
#pragma unroll
      for(int i=0;i<8;i++)
#pragma unroll
        for(int j=0;j<8;j++) acc[i][j]+=a[i]*b[j];
    }
  }
  u64 best = 0ull;
  float sqn[8];
#pragma unroll
  for(int j=0;j<8;j++) sqn[j] = sq[tn+tx*8+j];
#pragma unroll
  for(int i=0;i<8;i++){
    int gm = tm+ty*8+i;
    float sqm = sq[gm];
    float row[8];
#pragma unroll
    for(int j=0;j<8;j++){
      int gn = tn+tx*8+j;
      float d2 = (sqm + sqn[j]) - 2.f*acc[i][j];
      d2 = fmaxf(d2, 0.f);
      float dv = (d2 > 0.f) ? (sqrtf(d2) / 19.595917942265423f) : 0.f;
      row[j]=dv;
      unsigned u1=(unsigned)(gm*N3+gn), u2=(unsigned)(gn*N3+gm);
      u64 key = (((u64)__float_as_uint(dv))<<32) | (u1>u2?u1:u2);
      if(key > best) best = key;
    }
    float* dp = dist + (size_t)gm*N3 + tn + tx*8;
    *(float4*)(dp)   = make_float4(row[0],row[1],row[2],row[3]);
    *(float4*)(dp+4) = make_float4(row[4],row[5],row[6],row[7]);
  }
  if(bi != bj){
#pragma unroll
    for(int j=0;j<8;j++){
      int gn = tn+tx*8+j;
      float col[8];
#pragma unroll
      for(int i=0;i<8;i++){
        float d2 = (sq[tm+ty*8+i] + sqn[j]) - 2.f*acc[i][j];
        d2 = fmaxf(d2, 0.f);
        col[i] = (d2 > 0.f) ? (sqrtf(d2) / 19.595917942265423f) : 0.f;
      }
      float* dp = dist + (size_t)gn*N3 + tm + ty*8;
      *(float4*)(dp)   = make_float4(col[0],col[1],col[2],col[3]);
      *(float4*)(dp+4) = make_float4(col[4],col[5],col[6],col[7]);
    }
  }
  best = wave_max_u64(best);
  __shared__ u64 red[4];
  if((threadIdx.x&63)==0) red[threadIdx.x>>6]=best;
  __syncthreads();
  if(threadIdx.x==0){
    u64 m = red[0];
    if(red[1]>m) m=red[1];
    if(red[2]>m) m=red[2];
    if(red[3]>m) m=red[3];
    atomicMax(&dmaxkey12[fi], m);
  }
}

__global__ void k_dmax_fix_all(const u64* __restrict__ dmaxkey12, const float* __restrict__ xs,
                               double* __restrict__ dmaxd12, int fi0){
  if(threadIdx.x!=0) return;
  int fi = fi0 + blockIdx.x;
  unsigned pair = (unsigned)(dmaxkey12[fi] & 0xFFFFFFFFull);
  int i = pair / N3, j = pair % N3;
  dmaxd12[fi] = dist64(xs + (size_t)fi*N3*CC, i, j);
}

// wave per row: kk-NN via f32 keys, exact f64 recompute of selected distances
__global__ __launch_bounds__(256, 2)
void k_knn_all(const float* __restrict__ dist_base, const float* __restrict__ xs,
               const int* __restrict__ kknum, double* __restrict__ dens12, int fi0){
  const int fiL = blockIdx.y, fi = fi0 + fiL;
  const float* xr = xs + (size_t)fi*N3*CC;
  const float* dist = dist_base + (size_t)fiL*N3*N3;
  int row = blockIdx.x*4 + (threadIdx.x>>6);
  int lane = threadIdx.x & 63;
  int kk = kknum[fi];
  const float* dr = dist + (size_t)row*N3;
  u64 loc[17];
#pragma unroll
  for(int i=0;i<17;i++) loc[i]=~0ull;
  for(int j=lane;j<N3;j+=64){
    u64 key = (((u64)__float_as_uint(dr[j]))<<32) | (unsigned)j;
    if(key < loc[16]){
      u64 cur=key;
#pragma unroll
      for(int p=0;p<17;p++){
        u64 old=loc[p];
        bool ins = cur<old;
        loc[p] = ins?cur:old;
        cur    = ins?old:cur;
      }
    }
  }
  int myj = -1;
  for(int it=0; it<kk; it++){
    u64 k = wave_min_u64(loc[0]);
    int owner = (int)(k & 63u);          // j was loaded by lane j%64
    if(lane==owner){
#pragma unroll
      for(int p=0;p<16;p++) loc[p]=loc[p+1];
      loc[16]=~0ull;
    }
    if(it==lane) myj = (int)(k & 0xFFFFFFFFull);
  }
  double nd2 = 0.0;
  if(lane < kk && myj >= 0){
    double dd = dist64(xr, row, myj);
    nd2 = dd*dd;
  }
  double ssum = wave_sum_d(nd2);
  if(lane==0){
    double mean = ssum/(double)kk;
    double d = exp(-mean);
    // modern JAX (jax_threefry_partitionable=True): bits[i] = o0 ^ o1,
    // (o0,o1) = threefry(fold_in(key(42), fi), (0, i))
    uint32_t k0,k1,o0,o1;
    threefry(0u,42u, 0u,(uint32_t)fi, k0,k1);
    threefry(k0,k1, 0u,(uint32_t)row, o0,o1);
    uint32_t bits = o0 ^ o1;
    float u = __uint_as_float((bits>>9)|0x3F800000u) - 1.0f;
    dens12[(size_t)fi*N3 + row] = d + (double)u*1e-6;
  }
}

__global__ void k_dmin_all(const float* __restrict__ dist_base, const float* __restrict__ xs,
                           const double* __restrict__ dens12, const double* __restrict__ dmaxd12,
                           double* __restrict__ scorec12, int fi0){
  const int fiL = blockIdx.y, fi = fi0 + fiL;
  const float* xr = xs + (size_t)fi*N3*CC;
  const float* dist = dist_base + (size_t)fiL*N3*N3;
  const double* dens = dens12 + (size_t)fi*N3;
  int row = blockIdx.x*4+(threadIdx.x>>6);
  int lane = threadIdx.x & 63;
  double di = dens[row];
  const float* dr = dist + (size_t)row*N3;
  u64 best = ~0ull;
  for(int j=lane;j<N3;j+=64){
    if(dens[j] > di){
      u64 key = (((u64)__float_as_uint(dr[j]))<<32) | (unsigned)j;
      if(key < best) best = key;
    }
  }
  best = wave_min_u64(best);
  if(lane==0){
    double dm;
    if(best == ~0ull) dm = dmaxd12[fi];
    else dm = dist64(xr, row, (int)(best & 0xFFFFFFFFull));
    scorec12[(size_t)fi*N3 + row] = dm*di;
  }
}

// rank among scores (desc, tie -> lower index) == lax.top_k order
__global__ void k_centers_all(const double* __restrict__ scorec12, const int* __restrict__ aggnum,
                              int* __restrict__ centers12, int fi0){
  const int fi = fi0 + blockIdx.y;
  const double* scorec = scorec12 + (size_t)fi*N3;
  int t = blockIdx.x*256+threadIdx.x;
  int num = aggnum[fi];
  double si = scorec[t];
  __shared__ double tile[256];
  int rank=0;
  for(int j0=0;j0<N3;j0+=256){
    tile[threadIdx.x]=scorec[j0+threadIdx.x];
    __syncthreads();
#pragma unroll 8
    for(int jj=0;jj<256;jj++){
      double sj=tile[jj]; int j=j0+jj;
      rank += (sj>si) || (sj==si && j<t);
    }
    __syncthreads();
  }
  if(rank<num) centers12[fi*320 + rank]=t;
}

__global__ void k_assign_all(const float* __restrict__ dist_base, const float* __restrict__ xs,
                             const int* __restrict__ centers12, const int* __restrict__ aggnum,
                             int* __restrict__ idxc12, int fi0){
  const int fiL = blockIdx.y, fi = fi0 + fiL;
  const float* xr = xs + (size_t)fi*N3*CC;
  const float* dist = dist_base + (size_t)fiL*N3*N3;
  const int* centers = centers12 + fi*320;
  int t = blockIdx.x*256+threadIdx.x;
  int num = aggnum[fi];
  float bd=3.4e38f; int bc=0;
  float rd=3.4e38f; int rc=-1;
  for(int c=0;c<num;c++){
    float v = dist[(size_t)centers[c]*N3 + t];
    if(v<bd){ rd=bd; rc=bc; bd=v; bc=c; }
    else if(v<rd){ rd=v; rc=c; }
  }
  // f64 refine: compare best vs runner-up exactly (argmin-first semantics)
  if(rc>=0 && (rd-bd) < 1e-3f){
    double d1 = dist64(xr, centers[bc], t);
    double d2 = dist64(xr, centers[rc], t);
    if(d2 < d1 || (d2==d1 && rc<bc)) bc = rc;
  }
  idxc12[(size_t)fi*N3 + t]=bc;
}

__global__ void k_fixcenters_all(const int* __restrict__ centers12, const int* __restrict__ aggnum,
                                 int* __restrict__ idxc12, int fi0){
  const int fi = fi0 + blockIdx.y;
  int c = blockIdx.x*256+threadIdx.x;
  if(c < aggnum[fi]) idxc12[(size_t)fi*N3 + centers12[fi*320 + c]]=c;
}

__global__ void k_allw_all(const int* __restrict__ idxc12, const float* __restrict__ ss_f,
                           float* __restrict__ allw12, int fi0){
  const int fi = fi0 + blockIdx.y;
  int t = blockIdx.x*256+threadIdx.x;
  atomicAdd(&allw12[fi*320 + idxc12[(size_t)fi*N3 + t]], ss_f[(size_t)fi*N3 + t]);
}

__global__ void k_scatter_all(const float* __restrict__ xs, const int* __restrict__ idxc12,
                              const float* __restrict__ ss_f, const float* __restrict__ allw12,
                              float* __restrict__ agg, const int* __restrict__ offs, int fi0){
  const int fi = fi0 + blockIdx.y;
  int idx = blockIdx.x*256+threadIdx.x;
  int t = idx / CC, c = idx % CC;
  int cl = idxc12[(size_t)fi*N3 + t];
  float wgt = ss_f[(size_t)fi*N3 + t]/(allw12[fi*320 + cl]+1e-6f);
  float* aggb = agg + (size_t)(fi/3)*MAXTOT*CC;
  atomicAdd(&aggb[(size_t)(offs[fi] + cl)*CC + c], xs[(size_t)fi*N3*CC + idx]*wgt);
}

// ---------------- attention: thread = (b,h,n), online softmax over <=960 keys ----------------
// __launch_bounds__(256,2): VGPR cap 256 — keeps qv/acc/outa (~180 regs) in registers,
// no scratch spill (r6 showed VGPR=64 + 110MB excess HBM writes = spill traffic).
__global__ __launch_bounds__(256, 2)
void k_attn(const float* __restrict__ q, const float* __restrict__ kv,
            const int* __restrict__ numtot, const float* __restrict__ wts,
            const int* __restrict__ topk, float* __restrict__ res){
  int b = blockIdx.z, h = blockIdx.y;
  int n = blockIdx.x*256 + threadIdx.x;
  int ntot = numtot[b];
  __shared__ float4 kt4[64][12];
  __shared__ float4 vt4[64][12];
  float qv[48];
  const float* qp = q + ((size_t)b*NN + n)*CC + h*DH;
#pragma unroll
  for(int d=0;d<48;d++) qv[d]=qp[d];
  float outa[48];
#pragma unroll
  for(int d=0;d<48;d++) outa[d]=0.f;
  const float sc = 0.14433756729740643f;   // 48^-0.5
  for(int j=0;j<2;j++){
    const float* kvb = kv + (size_t)(b*2+j)*MAXTOT*768;
    float wexp = wts[b*EE + topk[b*2+j]];
    float mrun=-3.4e38f, lrun=0.f;
    float acc[48];
#pragma unroll
    for(int d=0;d<48;d++) acc[d]=0.f;
    for(int m0=0;m0<ntot;m0+=64){
      __syncthreads();
      for(int l=threadIdx.x;l<768;l+=256){
        int mm=l/12, d4=l%12;
        int m=m0+mm;
        float4 kf=make_float4(0,0,0,0), vf=make_float4(0,0,0,0);
        if(m<ntot){
          kf = *(const float4*)(kvb + (size_t)m*768 + h*DH + 4*d4);
          vf = *(const float4*)(kvb + (size_t)m*768 + 384 + h*DH + 4*d4);
        }
        kt4[mm][d4]=kf; vt4[mm][d4]=vf;
      }
      __syncthreads();
      int mcnt = min(64, ntot-m0);
      for(int mm=0;mm<mcnt;mm++){
        float s=0.f;
#pragma unroll
        for(int d4=0;d4<12;d4++){
          float4 kf = kt4[mm][d4];
          s += qv[4*d4+0]*kf.x; s += qv[4*d4+1]*kf.y;
          s += qv[4*d4+2]*kf.z; s += qv[4*d4+3]*kf.w;
        }
        s *= sc;
        if(s > mrun){
          float rs = expf(mrun - s);
          lrun *= rs;
#pragma unroll
          for(int d=0;d<48;d++) acc[d]*=rs;
          mrun = s;
        }
        float p = expf(s - mrun);
        lrun += p;
#pragma unroll
        for(int d4=0;d4<12;d4++){
          float4 vf = vt4[mm][d4];
          acc[4*d4+0]+=p*vf.x; acc[4*d4+1]+=p*vf.y;
          acc[4*d4+2]+=p*vf.z; acc[4*d4+3]+=p*vf.w;
        }
      }
    }
    float inv = 1.f/lrun;
#pragma unroll
    for(int d=0;d<48;d++) outa[d] += wexp*(acc[d]*inv);
  }
  float* rp = res + ((size_t)b*NN + n)*CC + h*DH;
#pragma unroll
  for(int d=0;d<48;d++) rp[d]=outa[d];
}

// ---------------- host ----------------
extern "C" void kernel_launch(void* const* d_in, const int* in_sizes, int n_in,
                              void* d_out, int out_size, void* d_ws, size_t ws_size,
                              hipStream_t stream){
  (void)in_sizes; (void)n_in; (void)out_size;
  const float* x       = (const float*)d_in[0];
  const float* q_w     = (const float*)d_in[1];
  const float* kv_w    = (const float*)d_in[2];
  const float* route_w = (const float*)d_in[3];
  const float* route_b = (const float*)d_in[4];
  const float* score_w = (const float*)d_in[5];
  const float* score_b = (const float*)d_in[6];
  const float* rscale_w= (const float*)d_in[7];
  const float* rscale_b= (const float*)d_in[8];
  const float* proj_w  = (const float*)d_in[9];
  const float* proj_b  = (const float*)d_in[10];
  float* out = (float*)d_out;

  char* w = (char*)d_ws;
  size_t o = 0;
  auto carve = [&](size_t bytes)->char*{
    char* p = w + o;
    o += (bytes + 255) & ~(size_t)255;
    return p;
  };
  double* score_d = (double*)carve((size_t)BB*NN*8);
  u64*   keys    = (u64*)carve((size_t)BB*NN*8);
  int*   order   = (int*)carve((size_t)BB*NN*4);
  double* ss_d   = (double*)carve((size_t)BB*NN*8);
  float* ss_f    = (float*)carve((size_t)BB*NN*4);
  double* meanx  = (double*)carve((size_t)BB*CC*8);
  double* scales = (double*)carve(12*8);
  int*   aggnum  = (int*)carve(12*4);
  int*   kknum   = (int*)carve(12*4);
  int*   offs    = (int*)carve(12*4);
  int*   numtot  = (int*)carve(BB*4);
  float* wts     = (float*)carve(BB*EE*4);
  int*   topk    = (int*)carve(BB*2*4);
  u64*   dmaxkey12 = (u64*)carve(12*8);
  double* dmaxd12  = (double*)carve(12*8);
  float* sumsq12   = (float*)carve((size_t)12*N3*4);
  double* dens12   = (double*)carve((size_t)12*N3*8);
  double* scorec12 = (double*)carve((size_t)12*N3*8);
  int*   centers12 = (int*)carve((size_t)12*320*4);
  int*   idxc12    = (int*)carve((size_t)12*N3*4);
  float* allw12    = (float*)carve((size_t)12*320*4);
  float* xs      = (float*)carve((size_t)BB*NN*CC*4);
  float* agg     = (float*)carve((size_t)BB*MAXTOT*CC*4);

  // union region: dist[NB] during clustering, then qbuf+kvb+res afterwards
  const size_t distB = (size_t)N3*N3*4;                 // 37,748,736
  const size_t qbufB = (size_t)BB*NN*CC*4;              // 56,623,104
  const size_t kvbB  = (size_t)BB*2*MAXTOT*768*4;       // 23,592,960
  const size_t resB  = qbufB;
  const size_t tailB = qbufB + kvbB + resB;
  size_t avail = (ws_size > o) ? (ws_size - o) : 0;
  if(avail < tailB) return;                             // workspace too small -> visible failure
  int NB = (int)(avail / distB); if(NB > 12) NB = 12;   // avail>=tailB => NB>=3
  size_t uB = (size_t)NB*distB; if(uB < tailB) uB = tailB;
  char* ub = carve(uB);
  float* dist_base = (float*)ub;
  float* qbuf = (float*)ub;
  float* kvb  = (float*)(ub + qbufB);
  float* res  = (float*)(ub + qbufB + kvbB);
  if(o > ws_size) return;

  dim3 b256(256);
  k_score <<<dim3(BB*NN/4), b256, 0, stream>>>(x, score_w, score_b, score_d, keys);
  k_rank  <<<dim3(NN/256, BB), b256, 0, stream>>>(keys, score_d, order, ss_d, ss_f);
  k_gather<<<dim3((unsigned)((size_t)BB*NN*96/256)), b256, 0, stream>>>(x, order, xs);
  k_zero_d<<<dim3((BB*CC+255)/256), b256, 0, stream>>>(meanx, BB*CC);
  k_meanx <<<dim3(BB*16), dim3(CC), 0, stream>>>(x, meanx);
  k_scales<<<dim3(12), b256, 0, stream>>>(ss_d, rscale_w, rscale_b, scales);
  k_aggnum<<<dim3(1), dim3(64), 0, stream>>>(scales, aggnum, kknum, offs, numtot);
  k_weights<<<dim3(1), dim3(64), 0, stream>>>(meanx, route_w, route_b, wts, topk);
  k_zero  <<<dim3((BB*MAXTOT*CC+255)/256), b256, 0, stream>>>(agg, BB*MAXTOT*CC);
  k_init12<<<dim3(15), b256, 0, stream>>>(dmaxkey12, allw12);

  for(int g=0; g<12; g+=NB){
    int ng = (12-g < NB) ? (12-g) : NB;
    k_sumsq_all <<<dim3(N3/4, ng), b256, 0, stream>>>(xs, sumsq12, g);
    k_gram_all  <<<dim3(NTRI, ng), b256, 0, stream>>>(xs, sumsq12, dist_base, dmaxkey12, g);
    k_dmax_fix_all<<<dim3(ng), dim3(64), 0, stream>>>(dmaxkey12, xs, dmaxd12, g);
    k_knn_all   <<<dim3(N3/4, ng), b256, 0, stream>>>(dist_base, xs, kknum, dens12, g);
    k_dmin_all  <<<dim3(N3/4, ng), b256, 0, stream>>>(dist_base, xs, dens12, dmaxd12, scorec12, g);
    k_centers_all<<<dim3(N3/256, ng), b256, 0, stream>>>(scorec12, aggnum, centers12, g);
    k_assign_all<<<dim3(N3/256, ng), b256, 0, stream>>>(dist_base, xs, centers12, aggnum, idxc12, g);
    k_fixcenters_all<<<dim3(2, ng), b256, 0, stream>>>(centers12, aggnum, idxc12, g);
    k_allw_all  <<<dim3(N3/256, ng), b256, 0, stream>>>(idxc12, ss_f, allw12, g);
    k_scatter_all<<<dim3(N3*CC/256, ng), b256, 0, stream>>>(xs, idxc12, ss_f, allw12, agg, offs, g);
  }

  k_gemm128<<<dim3(BB*NN/128, CC/128), b256, 0, stream>>>(x, q_w, nullptr, qbuf, CC, CC);
  k_gemm_kv<<<dim3(MAXTOT/64, 768/64, BB*2), b256, 0, stream>>>(agg, kv_w, topk, kvb);
  k_attn   <<<dim3(NN/256, HH, BB), b256, 0, stream>>>(qbuf, kvb, numtot, wts, topk, res);
  k_gemm128<<<dim3(BB*NN/128, CC/128), b256, 0, stream>>>(res, proj_w, proj_b, out, CC, CC);
}

// Round 9
// 3812.352 us; speedup vs baseline: 7.2036x; 1.0614x over previous
//
#include <hip/hip_runtime.h>
#include <stdint.h>

#define BB 4
#define NN 9216
#define CC 384
#define HH 8
#define DH 48
#define EE 4
#define N3 3072
#define MAXTOT 960
#define NT3 24          // N3/128
#define NTRI 300        // NT3*(NT3+1)/2

typedef unsigned long long u64;
typedef float v2f __attribute__((ext_vector_type(2)));

__device__ __forceinline__ v2f make2(float a, float b){ v2f r; r.x=a; r.y=b; return r; }

// ---------------- wave helpers (wave64) ----------------
__device__ __forceinline__ float wave_sum(float v){
#pragma unroll
  for(int m=32;m>0;m>>=1) v += __shfl_xor(v,m,64);
  return v;
}
__device__ __forceinline__ double wave_sum_d(double v){
#pragma unroll
  for(int m=32;m>0;m>>=1) v += __shfl_xor(v,m,64);
  return v;
}
__device__ __forceinline__ u64 wave_min_u64(u64 k){
#pragma unroll
  for(int m=32;m>0;m>>=1){
    unsigned lo = __shfl_xor((unsigned)k, m, 64);
    unsigned hi = __shfl_xor((unsigned)(k>>32), m, 64);
    u64 o = ((u64)hi<<32)|lo;
    if(o < k) k = o;
  }
  return k;
}
__device__ __forceinline__ u64 wave_max_u64(u64 k){
#pragma unroll
  for(int m=32;m>0;m>>=1){
    unsigned lo = __shfl_xor((unsigned)k, m, 64);
    unsigned hi = __shfl_xor((unsigned)(k>>32), m, 64);
    u64 o = ((u64)hi<<32)|lo;
    if(o > k) k = o;
  }
  return k;
}

// exact f64 distance between token rows i,j of xr (f32 storage promoted)
__device__ double dist64(const float* __restrict__ xr, int i, int j){
  const float* a = xr + (size_t)i*CC;
  const float* b = xr + (size_t)j*CC;
  double s = 0.0;
  for(int c=0;c<CC;c++){
    double d = (double)a[c] - (double)b[c];
    s += d*d;
  }
  if(!(s > 0.0)) return 0.0;
  return sqrt(s) / 19.595917942265423;   // / sqrt(384), double
}

// ---------------- JAX threefry2x32 (20 rounds), bit-exact ----------------
__device__ __forceinline__ void threefry(uint32_t k0, uint32_t k1, uint32_t x0, uint32_t x1,
                                         uint32_t& o0, uint32_t& o1){
  const uint32_t ks0=k0, ks1=k1, ks2=k0^k1^0x1BD11BDAu;
  const int rotA[4]={13,15,26,6}, rotB[4]={17,29,16,24};
  x0 += ks0; x1 += ks1;
#pragma unroll
  for(int g=0; g<5; g++){
    const int* rot = (g&1)? rotB : rotA;
#pragma unroll
    for(int i=0;i<4;i++){
      x0 += x1;
      x1 = (x1<<rot[i])|(x1>>(32-rot[i]));
      x1 ^= x0;
    }
    uint32_t a = (g%3==0)?ks1:((g%3==1)?ks2:ks0);          // ks[(g+1)%3]
    uint32_t b = (g%3==0)?ks2:((g%3==1)?ks0:ks1);          // ks[(g+2)%3]
    x0 += a; x1 += b + (uint32_t)(g+1);
  }
  o0=x0; o1=x1;
}

// ---------------- score (f64) + sort keys ----------------
__global__ void k_score(const float* __restrict__ x, const float* __restrict__ sw,
                        const float* __restrict__ sb, double* __restrict__ score_d,
                        u64* __restrict__ keys){
  int row = blockIdx.x*4 + (threadIdx.x>>6);
  int lane = threadIdx.x & 63;
  const float* xr = x + (size_t)row*CC;
  double s = 0.0;
  for(int c=lane;c<CC;c+=64) s += (double)xr[c]*(double)sw[c];
  s = wave_sum_d(s);
  if(lane==0){
    double sc = exp(s + (double)sb[0]);    // > 0 -> double bits monotone
    score_d[row] = sc;
    keys[row] = (u64)__double_as_longlong(sc);
  }
}

// rank = stable-ascending position (score asc, index asc)
__global__ void k_rank(const u64* __restrict__ keys, const double* __restrict__ score_d,
                       int* __restrict__ order, double* __restrict__ ss_d,
                       float* __restrict__ ss_f){
  int b = blockIdx.y;
  int i = blockIdx.x*256 + threadIdx.x;
  __shared__ u64 tile[256];
  u64 ki = keys[(size_t)b*NN + i];
  int rank = 0;
  for(int j0=0;j0<NN;j0+=256){
    tile[threadIdx.x] = keys[(size_t)b*NN + j0 + threadIdx.x];
    __syncthreads();
#pragma unroll 8
    for(int jj=0;jj<256;jj++){
      u64 kj = tile[jj]; int j=j0+jj;
      rank += (kj < ki) || (kj == ki && j < i);
    }
    __syncthreads();
  }
  double sd = score_d[(size_t)b*NN + i];
  order[(size_t)b*NN + rank] = i;
  ss_d[(size_t)b*NN + rank] = sd;
  ss_f[(size_t)b*NN + rank] = (float)sd;
}

__global__ void k_gather(const float* __restrict__ x, const int* __restrict__ order,
                         float* __restrict__ xs){
  size_t idx = (size_t)blockIdx.x*256 + threadIdx.x;
  int c4 = (int)(idx % 96);
  size_t row = idx / 96;
  int b = (int)(row / NN);
  int src = order[row];
  ((float4*)xs)[row*96 + c4] = ((const float4*)x)[((size_t)b*NN + src)*96 + c4];
}

__global__ void k_zero(float* __restrict__ p, int n){
  int i = blockIdx.x*256 + threadIdx.x;
  if(i<n) p[i]=0.f;
}
__global__ void k_zero_d(double* __restrict__ p, int n){
  int i = blockIdx.x*256 + threadIdx.x;
  if(i<n) p[i]=0.0;
}

__global__ void k_meanx(const float* __restrict__ x, double* __restrict__ meanx){
  int b = blockIdx.x >> 4, chunk = blockIdx.x & 15;
  int c = threadIdx.x;   // 384 threads
  const float* base = x + ((size_t)b*NN + (size_t)chunk*576)*CC + c;
  double s=0.0;
  for(int n=0;n<576;n++) s += (double)base[(size_t)n*CC];
  atomicAdd(&meanx[b*CC+c], s);
}

__global__ void k_scales(const double* __restrict__ ss_d, const float* __restrict__ rw,
                         const float* __restrict__ rb, double* __restrict__ scales){
  int b = blockIdx.x/3, r = blockIdx.x%3;
  double s=0.0;
  for(int t=threadIdx.x;t<N3;t+=256) s += ss_d[(size_t)b*NN + r*N3 + t]*(double)rw[r*N3+t];
  __shared__ double red[4];
  s = wave_sum_d(s);
  if((threadIdx.x&63)==0) red[threadIdx.x>>6]=s;
  __syncthreads();
  if(threadIdx.x==0) scales[b*3+r] = red[0]+red[1]+red[2]+red[3] + (double)rb[r];
}

__global__ void k_aggnum(const double* __restrict__ scales, int* aggnum, int* kknum,
                         int* offs, int* numtot){
  int b = threadIdx.x;
  if(b >= BB) return;
  double s0=scales[b*3+0], s1=scales[b*3+1], s2=scales[b*3+2];
  double m = fmax(s0, fmax(s1,s2));
  double e0=exp(s0-m), e1=exp(s1-m), e2=exp(s2-m);
  double den=e0+e1+e2;
  int off=0;
  for(int r=0;r<3;r++){
    double e = (r==0)?e0:((r==1)?e1:e2);
    double v = 320.0*(e/den);
    v = fmin(fmax(v,16.0),320.0);
    int num=(int)v;                      // trunc toward 0, positive
    int kk=(int)sqrt((double)num);
    while((kk+1)*(kk+1)<=num) kk++;
    while(kk>1 && kk*kk>num) kk--;
    if(kk<1) kk=1;
    aggnum[b*3+r]=num; kknum[b*3+r]=kk; offs[b*3+r]=off; off+=num;
  }
  numtot[b]=off;
}

__global__ void k_weights(const double* __restrict__ meanx, const float* __restrict__ route_w,
                          const float* __restrict__ route_b, float* __restrict__ wts,
                          int* __restrict__ topk){
  __shared__ double wd[BB*EE];
  int t = threadIdx.x;
  if(t < BB*EE){
    int b=t/EE, e=t%EE;
    double s=0.0;
    for(int c=0;c<CC;c++) s += (meanx[b*CC+c]*(1.0/NN))*(double)route_w[e*CC+c];
    double w = 1.0/(1.0+exp(-(s+(double)route_b[e])));
    wd[t]=w;
    wts[t]=(float)w;
  }
  __syncthreads();
  if(t<BB){
    int b=t; int i1=0; double best=-1e300;
    for(int e=0;e<EE;e++){ double w=wd[b*EE+e]; if(w>best){best=w;i1=e;} }
    int i2=-1; double b2=-1e300;
    for(int e=0;e<EE;e++){ if(e==i1) continue; double w=wd[b*EE+e]; if(w>b2){b2=w;i2=e;} }
    topk[b*2]=i1; topk[b*2+1]=i2;
  }
}

// ---------------- small fp32 C = A * W^T (64 tile, guarded) ----------------
__device__ __forceinline__ void gemm_abt_tile(const float* __restrict__ A, const float* __restrict__ W,
    const float* __restrict__ bias, float* __restrict__ Cm,
    int M, int Nn, int K, int bx, int by){
  __shared__ float As[16][68];
  __shared__ float Ws[16][68];
  const int tx = threadIdx.x & 15, ty = threadIdx.x >> 4;
  const int tm = bx*64, tn = by*64;
  float acc[4][4];
#pragma unroll
  for(int i=0;i<4;i++)
#pragma unroll
    for(int j=0;j<4;j++) acc[i][j]=0.f;
  for(int k0=0;k0<K;k0+=16){
#pragma unroll
    for(int t=0;t<4;t++){
      int l = threadIdx.x + t*256;
      int r = l>>4, kk=l&15;
      int gm = tm+r;
      As[kk][r] = (gm<M)? A[(size_t)gm*K + k0+kk] : 0.f;
    }
#pragma unroll
    for(int t=0;t<4;t++){
      int l = threadIdx.x + t*256;
      int r=l>>4, kk=l&15;
      int gn = tn+r;
      Ws[kk][r] = (gn<Nn)? W[(size_t)gn*K + k0+kk] : 0.f;
    }
    __syncthreads();
#pragma unroll
    for(int kk=0;kk<16;kk++){
      float a0=As[kk][ty*4+0],a1=As[kk][ty*4+1],a2=As[kk][ty*4+2],a3=As[kk][ty*4+3];
      float b0=Ws[kk][tx*4+0],b1=Ws[kk][tx*4+1],b2=Ws[kk][tx*4+2],b3=Ws[kk][tx*4+3];
      acc[0][0]+=a0*b0; acc[0][1]+=a0*b1; acc[0][2]+=a0*b2; acc[0][3]+=a0*b3;
      acc[1][0]+=a1*b0; acc[1][1]+=a1*b1; acc[1][2]+=a1*b2; acc[1][3]+=a1*b3;
      acc[2][0]+=a2*b0; acc[2][1]+=a2*b1; acc[2][2]+=a2*b2; acc[2][3]+=a2*b3;
      acc[3][0]+=a3*b0; acc[3][1]+=a3*b1; acc[3][2]+=a3*b2; acc[3][3]+=a3*b3;
    }
    __syncthreads();
  }
#pragma unroll
  for(int i=0;i<4;i++){
    int gm=tm+ty*4+i; if(gm>=M) continue;
#pragma unroll
    for(int j=0;j<4;j++){
      int gn=tn+tx*4+j; if(gn>=Nn) continue;
      float v=acc[i][j];
      if(bias) v += bias[gn];
      Cm[(size_t)gm*Nn+gn]=v;
    }
  }
}

__global__ __launch_bounds__(256, 2)
void k_gemm_kv(const float* __restrict__ agg, const float* __restrict__ kv_w,
               const int* __restrict__ topk, float* __restrict__ kvb){
  int z = blockIdx.z;                  // b*2+j
  int e = topk[z];
  gemm_abt_tile(agg + (size_t)(z>>1)*MAXTOT*CC, kv_w + (size_t)e*768*CC, nullptr,
                kvb + (size_t)z*MAXTOT*768, MAXTOT, 768, CC, blockIdx.x, blockIdx.y);
}

// ---------------- big fp32 GEMM: 128x128 tile, dims must be multiples ----------------
__global__ __launch_bounds__(256, 2)
void k_gemm128(const float* __restrict__ A, const float* __restrict__ W,
               const float* __restrict__ bias, float* __restrict__ Cm,
               int Nn, int K){
  __shared__ float As[16][132];
  __shared__ float Ws[16][132];
  const int tx = threadIdx.x & 15, ty = threadIdx.x >> 4;
  const int tm = blockIdx.x*128, tn = blockIdx.y*128;
  const int lrow = threadIdx.x >> 1;
  const int lk = (threadIdx.x & 1)*8;
  float acc[8][8];
#pragma unroll
  for(int i=0;i<8;i++)
#pragma unroll
    for(int j=0;j<8;j++) acc[i][j]=0.f;
  for(int k0=0;k0<K;k0+=16){
    float4 a0 = *(const float4*)(A + (size_t)(tm+lrow)*K + k0+lk);
    float4 a1 = *(const float4*)(A + (size_t)(tm+lrow)*K + k0+lk+4);
    float4 b0 = *(const float4*)(W + (size_t)(tn+lrow)*K + k0+lk);
    float4 b1 = *(const float4*)(W + (size_t)(tn+lrow)*K + k0+lk+4);
    __syncthreads();
    As[lk+0][lrow]=a0.x; As[lk+1][lrow]=a0.y; As[lk+2][lrow]=a0.z; As[lk+3][lrow]=a0.w;
    As[lk+4][lrow]=a1.x; As[lk+5][lrow]=a1.y; As[lk+6][lrow]=a1.z; As[lk+7][lrow]=a1.w;
    Ws[lk+0][lrow]=b0.x; Ws[lk+1][lrow]=b0.y; Ws[lk+2][lrow]=b0.z; Ws[lk+3][lrow]=b0.w;
    Ws[lk+4][lrow]=b1.x; Ws[lk+5][lrow]=b1.y; Ws[lk+6][lrow]=b1.z; Ws[lk+7][lrow]=b1.w;
    __syncthreads();
#pragma unroll
    for(int kk=0;kk<16;kk++){
      float a[8], b[8];
#pragma unroll
      for(int i=0;i<8;i++) a[i]=As[kk][ty*8+i];
#pragma unroll
      for(int j=0;j<8;j++) b[j]=Ws[kk][tx*8+j];
#pragma unroll
      for(int i=0;i<8;i++)
#pragma unroll
        for(int j=0;j<8;j++) acc[i][j]+=a[i]*b[j];
    }
  }
  float bs[8];
#pragma unroll
  for(int j=0;j<8;j++) bs[j] = bias? bias[tn+tx*8+j] : 0.f;
#pragma unroll
  for(int i=0;i<8;i++){
    int gm = tm+ty*8+i;
    float* cp = Cm + (size_t)gm*Nn + tn + tx*8;
    *(float4*)(cp)   = make_float4(acc[i][0]+bs[0],acc[i][1]+bs[1],acc[i][2]+bs[2],acc[i][3]+bs[3]);
    *(float4*)(cp+4) = make_float4(acc[i][4]+bs[4],acc[i][5]+bs[5],acc[i][6]+bs[6],acc[i][7]+bs[7]);
  }
}

// ---------------- batched clustering ----------------
__global__ void k_init12(u64* __restrict__ dmaxkey12, float* __restrict__ allw12){
  int t = blockIdx.x*256 + threadIdx.x;
  if(t < 12) dmaxkey12[t] = 0ull;
  if(t < 12*320) allw12[t] = 0.f;
}

__global__ void k_sumsq_all(const float* __restrict__ xs, float* __restrict__ sumsq12, int fi0){
  int fi = fi0 + blockIdx.y;
  int row = blockIdx.x*4 + (threadIdx.x>>6);
  int lane = threadIdx.x & 63;
  const float* p = xs + (size_t)fi*N3*CC + (size_t)row*CC;
  float s=0.f;
  for(int c=lane;c<CC;c+=64){ float v=p[c]; s+=v*v; }
  s = wave_sum(s);
  if(lane==0) sumsq12[(size_t)fi*N3 + row]=s;
}

// fused symmetric Gram -> distance; upper-triangular 128-blocks, mirrored writes.
// Accumulation over k in the same order as before -> dist values bit-identical.
__global__ __launch_bounds__(256, 2)
void k_gram_all(const float* __restrict__ xs, const float* __restrict__ sumsq12,
                float* __restrict__ dist_base, u64* __restrict__ dmaxkey12, int fi0){
  const int fiL = blockIdx.y, fi = fi0 + fiL;
  const float* xr = xs + (size_t)fi*N3*CC;
  const float* sq = sumsq12 + (size_t)fi*N3;
  float* dist = dist_base + (size_t)fiL*N3*N3;
  int t = blockIdx.x, bi = 0;
  while(t >= NT3 - bi){ t -= NT3 - bi; bi++; }
  const int bj = bi + t;
  const int tm = bi*128, tn = bj*128;
  __shared__ float As[16][132];
  __shared__ float Ws[16][132];
  const int tx = threadIdx.x & 15, ty = threadIdx.x >> 4;
  const int lrow = threadIdx.x >> 1;
  const int lk = (threadIdx.x & 1)*8;
  float acc[8][8];
#pragma unroll
  for(int i=0;i<8;i++)
#pragma unroll
    for(int j=0;j<8;j++) acc[i][j]=0.f;
  for(int k0=0;k0<CC;k0+=16){
    float4 a0 = *(const float4*)(xr + (size_t)(tm+lrow)*CC + k0+lk);
    float4 a1 = *(const float4*)(xr + (size_t)(tm+lrow)*CC + k0+lk+4);
    float4 b0 = *(const float4*)(xr + (size_t)(tn+lrow)*CC + k0+lk);
    float4 b1 = *(const float4*)(xr + (size_t)(tn+lrow)*CC + k0+lk+4);
    __syncthreads();
    As[lk+0][lrow]=a0.x; As[lk+1][lrow]=a0.y; As[lk+2][lrow]=a0.z; As[lk+3][lrow]=a0.w;
    As[lk+4][lrow]=a1.x; As[lk+5][lrow]=a1.y; As[lk+6][lrow]=a1.z; As[lk+7][lrow]=a1.w;
    Ws[lk+0][lrow]=b0.x; Ws[lk+1][lrow]=b0.y; Ws[lk+2][lrow]=b0.z; Ws[lk+3][lrow]=b0.w;
    Ws[lk+4][lrow]=b1.x; Ws[lk+5][lrow]=b1.y; Ws[lk+6][lrow]=b1.z; Ws[lk+7][lrow]=b1.w;
    __syncthreads();
#pragma unroll
    for(int kk=0;kk<16;kk++){
      float a[8], b[8];
#pragma unroll
      for(int i=0;i<8;i++) a[i]=As[kk][ty*8+i];
#pragma unroll
      for(int j=0;j<8;j++) b[j]=Ws[kk][tx*8+j];
#pragma unroll
      for(int i=0;i<8;i++)
#pragma unroll
        for(int j=0;j<8;j++) acc[i][j]+=a[i]*b[j];
    }
  }
  u64 best = 0ull;
  float sqn[8];
#pragma unroll
  for(int j=0;j<8;j++) sqn[j] = sq[tn+tx*8+j];
#pragma unroll
  for(int i=0;i<8;i++){
    int gm = tm+ty*8+i;
    float sqm = sq[gm];
    float row[8];
#pragma unroll
    for(int j=0;j<8;j++){
      int gn = tn+tx*8+j;
      float d2 = (sqm + sqn[j]) - 2.f*acc[i][j];
      d2 = fmaxf(d2, 0.f);
      float dv = (d2 > 0.f) ? (sqrtf(d2) / 19.595917942265423f) : 0.f;
      row[j]=dv;
      unsigned u1=(unsigned)(gm*N3+gn), u2=(unsigned)(gn*N3+gm);
      u64 key = (((u64)__float_as_uint(dv))<<32) | (u1>u2?u1:u2);
      if(key > best) best = key;
    }
    float* dp = dist + (size_t)gm*N3 + tn + tx*8;
    *(float4*)(dp)   = make_float4(row[0],row[1],row[2],row[3]);
    *(float4*)(dp+4) = make_float4(row[4],row[5],row[6],row[7]);
  }
  if(bi != bj){
#pragma unroll
    for(int j=0;j<8;j++){
      int gn = tn+tx*8+j;
      float col[8];
#pragma unroll
      for(int i=0;i<8;i++){
        float d2 = (sq[tm+ty*8+i] + sqn[j]) - 2.f*acc[i][j];
        d2 = fmaxf(d2, 0.f);
        col[i] = (d2 > 0.f) ? (sqrtf(d2) / 19.595917942265423f) : 0.f;
      }
      float* dp = dist + (size_t)gn*N3 + tm + ty*8;
      *(float4*)(dp)   = make_float4(col[0],col[1],col[2],col[3]);
      *(float4*)(dp+4) = make_float4(col[4],col[5],col[6],col[7]);
    }
  }
  best = wave_max_u64(best);
  __shared__ u64 red[4];
  if((threadIdx.x&63)==0) red[threadIdx.x>>6]=best;
  __syncthreads();
  if(threadIdx.x==0){
    u64 m = red[0];
    if(red[1]>m) m=red[1];
    if(red[2]>m) m=red[2];
    if(red[3]>m) m=red[3];
    atomicMax(&dmaxkey12[fi], m);
  }
}

__global__ void k_dmax_fix_all(const u64* __restrict__ dmaxkey12, const float* __restrict__ xs,
                               double* __restrict__ dmaxd12, int fi0){
  if(threadIdx.x!=0) return;
  int fi = fi0 + blockIdx.x;
  unsigned pair = (unsigned)(dmaxkey12[fi] & 0xFFFFFFFFull);
  int i = pair / N3, j = pair % N3;
  dmaxd12[fi] = dist64(xs + (size_t)fi*N3*CC, i, j);
}

// wave per row: kk-NN via f32 keys, exact f64 recompute of selected distances
__global__ __launch_bounds__(256, 2)
void k_knn_all(const float* __restrict__ dist_base, const float* __restrict__ xs,
               const int* __restrict__ kknum, double* __restrict__ dens12, int fi0){
  const int fiL = blockIdx.y, fi = fi0 + fiL;
  const float* xr = xs + (size_t)fi*N3*CC;
  const float* dist = dist_base + (size_t)fiL*N3*N3;
  int row = blockIdx.x*4 + (threadIdx.x>>6);
  int lane = threadIdx.x & 63;
  int kk = kknum[fi];
  const float* dr = dist + (size_t)row*N3;
  u64 loc[17];
#pragma unroll
  for(int i=0;i<17;i++) loc[i]=~0ull;
  for(int j=lane;j<N3;j+=64){
    u64 key = (((u64)__float_as_uint(dr[j]))<<32) | (unsigned)j;
    if(key < loc[16]){
      u64 cur=key;
#pragma unroll
      for(int p=0;p<17;p++){
        u64 old=loc[p];
        bool ins = cur<old;
        loc[p] = ins?cur:old;
        cur    = ins?old:cur;
      }
    }
  }
  int myj = -1;
  for(int it=0; it<kk; it++){
    u64 k = wave_min_u64(loc[0]);
    int owner = (int)(k & 63u);          // j was loaded by lane j%64
    if(lane==owner){
#pragma unroll
      for(int p=0;p<16;p++) loc[p]=loc[p+1];
      loc[16]=~0ull;
    }
    if(it==lane) myj = (int)(k & 0xFFFFFFFFull);
  }
  double nd2 = 0.0;
  if(lane < kk && myj >= 0){
    double dd = dist64(xr, row, myj);
    nd2 = dd*dd;
  }
  double ssum = wave_sum_d(nd2);
  if(lane==0){
    double mean = ssum/(double)kk;
    double d = exp(-mean);
    // modern JAX (jax_threefry_partitionable=True): bits[i] = o0 ^ o1,
    // (o0,o1) = threefry(fold_in(key(42), fi), (0, i))
    uint32_t k0,k1,o0,o1;
    threefry(0u,42u, 0u,(uint32_t)fi, k0,k1);
    threefry(k0,k1, 0u,(uint32_t)row, o0,o1);
    uint32_t bits = o0 ^ o1;
    float u = __uint_as_float((bits>>9)|0x3F800000u) - 1.0f;
    dens12[(size_t)fi*N3 + row] = d + (double)u*1e-6;
  }
}

__global__ void k_dmin_all(const float* __restrict__ dist_base, const float* __restrict__ xs,
                           const double* __restrict__ dens12, const double* __restrict__ dmaxd12,
                           double* __restrict__ scorec12, int fi0){
  const int fiL = blockIdx.y, fi = fi0 + fiL;
  const float* xr = xs + (size_t)fi*N3*CC;
  const float* dist = dist_base + (size_t)fiL*N3*N3;
  const double* dens = dens12 + (size_t)fi*N3;
  int row = blockIdx.x*4+(threadIdx.x>>6);
  int lane = threadIdx.x & 63;
  double di = dens[row];
  const float* dr = dist + (size_t)row*N3;
  u64 best = ~0ull;
  for(int j=lane;j<N3;j+=64){
    if(dens[j] > di){
      u64 key = (((u64)__float_as_uint(dr[j]))<<32) | (unsigned)j;
      if(key < best) best = key;
    }
  }
  best = wave_min_u64(best);
  if(lane==0){
    double dm;
    if(best == ~0ull) dm = dmaxd12[fi];
    else dm = dist64(xr, row, (int)(best & 0xFFFFFFFFull));
    scorec12[(size_t)fi*N3 + row] = dm*di;
  }
}

// rank among scores (desc, tie -> lower index) == lax.top_k order
__global__ void k_centers_all(const double* __restrict__ scorec12, const int* __restrict__ aggnum,
                              int* __restrict__ centers12, int fi0){
  const int fi = fi0 + blockIdx.y;
  const double* scorec = scorec12 + (size_t)fi*N3;
  int t = blockIdx.x*256+threadIdx.x;
  int num = aggnum[fi];
  double si = scorec[t];
  __shared__ double tile[256];
  int rank=0;
  for(int j0=0;j0<N3;j0+=256){
    tile[threadIdx.x]=scorec[j0+threadIdx.x];
    __syncthreads();
#pragma unroll 8
    for(int jj=0;jj<256;jj++){
      double sj=tile[jj]; int j=j0+jj;
      rank += (sj>si) || (sj==si && j<t);
    }
    __syncthreads();
  }
  if(rank<num) centers12[fi*320 + rank]=t;
}

__global__ void k_assign_all(const float* __restrict__ dist_base, const float* __restrict__ xs,
                             const int* __restrict__ centers12, const int* __restrict__ aggnum,
                             int* __restrict__ idxc12, int fi0){
  const int fiL = blockIdx.y, fi = fi0 + fiL;
  const float* xr = xs + (size_t)fi*N3*CC;
  const float* dist = dist_base + (size_t)fiL*N3*N3;
  const int* centers = centers12 + fi*320;
  int t = blockIdx.x*256+threadIdx.x;
  int num = aggnum[fi];
  float bd=3.4e38f; int bc=0;
  float rd=3.4e38f; int rc=-1;
  for(int c=0;c<num;c++){
    float v = dist[(size_t)centers[c]*N3 + t];
    if(v<bd){ rd=bd; rc=bc; bd=v; bc=c; }
    else if(v<rd){ rd=v; rc=c; }
  }
  // f64 refine: compare best vs runner-up exactly (argmin-first semantics)
  if(rc>=0 && (rd-bd) < 1e-3f){
    double d1 = dist64(xr, centers[bc], t);
    double d2 = dist64(xr, centers[rc], t);
    if(d2 < d1 || (d2==d1 && rc<bc)) bc = rc;
  }
  idxc12[(size_t)fi*N3 + t]=bc;
}

__global__ void k_fixcenters_all(const int* __restrict__ centers12, const int* __restrict__ aggnum,
                                 int* __restrict__ idxc12, int fi0){
  const int fi = fi0 + blockIdx.y;
  int c = blockIdx.x*256+threadIdx.x;
  if(c < aggnum[fi]) idxc12[(size_t)fi*N3 + centers12[fi*320 + c]]=c;
}

__global__ void k_allw_all(const int* __restrict__ idxc12, const float* __restrict__ ss_f,
                           float* __restrict__ allw12, int fi0){
  const int fi = fi0 + blockIdx.y;
  int t = blockIdx.x*256+threadIdx.x;
  atomicAdd(&allw12[fi*320 + idxc12[(size_t)fi*N3 + t]], ss_f[(size_t)fi*N3 + t]);
}

__global__ void k_scatter_all(const float* __restrict__ xs, const int* __restrict__ idxc12,
                              const float* __restrict__ ss_f, const float* __restrict__ allw12,
                              float* __restrict__ agg, const int* __restrict__ offs, int fi0){
  const int fi = fi0 + blockIdx.y;
  int idx = blockIdx.x*256+threadIdx.x;
  int t = idx / CC, c = idx % CC;
  int cl = idxc12[(size_t)fi*N3 + t];
  float wgt = ss_f[(size_t)fi*N3 + t]/(allw12[fi*320 + cl]+1e-6f);
  float* aggb = agg + (size_t)(fi/3)*MAXTOT*CC;
  atomicAdd(&aggb[(size_t)(offs[fi] + cl)*CC + c], xs[(size_t)fi*N3*CC + idx]*wgt);
}

// ---------------- attention v2: packed fp32 (v_pk_fma), 4-chain dot, no outa ----------------
// r7 lesson: allocator is occupancy-greedy; 144+ live floats at VGPR=88 -> spill+latency-bound
// (VALUBusy 56%, occupancy 18.8%). v2: live set ~112 regs, cap 128 via (256,4).
__global__ __launch_bounds__(256, 4)
void k_attn(const float* __restrict__ q, const float* __restrict__ kv,
            const int* __restrict__ numtot, const float* __restrict__ wts,
            const int* __restrict__ topk, float* __restrict__ res){
  int b = blockIdx.z, h = blockIdx.y;
  int n = blockIdx.x*256 + threadIdx.x;
  int ntot = numtot[b];
  __shared__ float4 kt4[64][12];
  __shared__ float4 vt4[64][12];
  v2f qv[24];
  const float* qp = q + ((size_t)b*NN + n)*CC + h*DH;
#pragma unroll
  for(int d=0;d<24;d++) qv[d] = make2(qp[2*d], qp[2*d+1]);
  const float sc = 0.14433756729740643f;   // 48^-0.5
  float* rp = res + ((size_t)b*NN + n)*CC + h*DH;
  for(int j=0;j<2;j++){
    const float* kvb = kv + (size_t)(b*2+j)*MAXTOT*768;
    float wexp = wts[b*EE + topk[b*2+j]];
    float mrun=-3.4e38f, lrun=0.f;
    v2f acc[24];
#pragma unroll
    for(int d=0;d<24;d++) acc[d]=make2(0.f,0.f);
    for(int m0=0;m0<ntot;m0+=64){
      __syncthreads();
      for(int l=threadIdx.x;l<768;l+=256){
        int mm=l/12, d4=l%12;
        int m=m0+mm;
        float4 kf=make_float4(0,0,0,0), vf=make_float4(0,0,0,0);
        if(m<ntot){
          kf = *(const float4*)(kvb + (size_t)m*768 + h*DH + 4*d4);
          vf = *(const float4*)(kvb + (size_t)m*768 + 384 + h*DH + 4*d4);
        }
        kt4[mm][d4]=kf; vt4[mm][d4]=vf;
      }
      __syncthreads();
      int mcnt = min(64, ntot-m0);
      for(int mm=0;mm<mcnt;mm++){
        // QK dot: 4 independent v2f chains (6 deep each) -> v_pk_fma_f32
        v2f p0=make2(0.f,0.f), p1=make2(0.f,0.f), p2=make2(0.f,0.f), p3=make2(0.f,0.f);
#pragma unroll
        for(int d4=0;d4<12;d4+=2){
          float4 ka = kt4[mm][d4];
          float4 kb = kt4[mm][d4+1];
          p0 += make2(ka.x,ka.y)*qv[2*d4];
          p1 += make2(ka.z,ka.w)*qv[2*d4+1];
          p2 += make2(kb.x,kb.y)*qv[2*d4+2];
          p3 += make2(kb.z,kb.w)*qv[2*d4+3];
        }
        v2f pt = (p0+p1)+(p2+p3);
        float s = (pt.x+pt.y)*sc;
        if(s > mrun){
          float rs = expf(mrun - s);
          lrun *= rs;
          v2f rv = make2(rs,rs);
#pragma unroll
          for(int d=0;d<24;d++) acc[d]*=rv;
          mrun = s;
        }
        float p = expf(s - mrun);
        lrun += p;
        v2f pv = make2(p,p);
#pragma unroll
        for(int d4=0;d4<12;d4++){
          float4 vf = vt4[mm][d4];
          acc[2*d4]   += make2(vf.x,vf.y)*pv;
          acc[2*d4+1] += make2(vf.z,vf.w)*pv;
        }
      }
    }
    float inv = wexp/lrun;
    if(j==0){
#pragma unroll
      for(int d=0;d<24;d++){ rp[2*d]=acc[d].x*inv; rp[2*d+1]=acc[d].y*inv; }
    }else{
#pragma unroll
      for(int d=0;d<24;d++){ rp[2*d]+=acc[d].x*inv; rp[2*d+1]+=acc[d].y*inv; }
    }
  }
}

// ---------------- host ----------------
extern "C" void kernel_launch(void* const* d_in, const int* in_sizes, int n_in,
                              void* d_out, int out_size, void* d_ws, size_t ws_size,
                              hipStream_t stream){
  (void)in_sizes; (void)n_in; (void)out_size;
  const float* x       = (const float*)d_in[0];
  const float* q_w     = (const float*)d_in[1];
  const float* kv_w    = (const float*)d_in[2];
  const float* route_w = (const float*)d_in[3];
  const float* route_b = (const float*)d_in[4];
  const float* score_w = (const float*)d_in[5];
  const float* score_b = (const float*)d_in[6];
  const float* rscale_w= (const float*)d_in[7];
  const float* rscale_b= (const float*)d_in[8];
  const float* proj_w  = (const float*)d_in[9];
  const float* proj_b  = (const float*)d_in[10];
  float* out = (float*)d_out;

  char* w = (char*)d_ws;
  size_t o = 0;
  auto carve = [&](size_t bytes)->char*{
    char* p = w + o;
    o += (bytes + 255) & ~(size_t)255;
    return p;
  };
  double* score_d = (double*)carve((size_t)BB*NN*8);
  u64*   keys    = (u64*)carve((size_t)BB*NN*8);
  int*   order   = (int*)carve((size_t)BB*NN*4);
  double* ss_d   = (double*)carve((size_t)BB*NN*8);
  float* ss_f    = (float*)carve((size_t)BB*NN*4);
  double* meanx  = (double*)carve((size_t)BB*CC*8);
  double* scales = (double*)carve(12*8);
  int*   aggnum  = (int*)carve(12*4);
  int*   kknum   = (int*)carve(12*4);
  int*   offs    = (int*)carve(12*4);
  int*   numtot  = (int*)carve(BB*4);
  float* wts     = (float*)carve(BB*EE*4);
  int*   topk    = (int*)carve(BB*2*4);
  u64*   dmaxkey12 = (u64*)carve(12*8);
  double* dmaxd12  = (double*)carve(12*8);
  float* sumsq12   = (float*)carve((size_t)12*N3*4);
  double* dens12   = (double*)carve((size_t)12*N3*8);
  double* scorec12 = (double*)carve((size_t)12*N3*8);
  int*   centers12 = (int*)carve((size_t)12*320*4);
  int*   idxc12    = (int*)carve((size_t)12*N3*4);
  float* allw12    = (float*)carve((size_t)12*320*4);
  float* xs      = (float*)carve((size_t)BB*NN*CC*4);
  float* agg     = (float*)carve((size_t)BB*MAXTOT*CC*4);

  // union region: dist[NB] during clustering, then qbuf+kvb+res afterwards
  const size_t distB = (size_t)N3*N3*4;                 // 37,748,736
  const size_t qbufB = (size_t)BB*NN*CC*4;              // 56,623,104
  const size_t kvbB  = (size_t)BB*2*MAXTOT*768*4;       // 23,592,960
  const size_t resB  = qbufB;
  const size_t tailB = qbufB + kvbB + resB;
  size_t avail = (ws_size > o) ? (ws_size - o) : 0;
  if(avail < tailB) return;                             // workspace too small -> visible failure
  int NB = (int)(avail / distB); if(NB > 12) NB = 12;   // avail>=tailB => NB>=3
  size_t uB = (size_t)NB*distB; if(uB < tailB) uB = tailB;
  char* ub = carve(uB);
  float* dist_base = (float*)ub;
  float* qbuf = (float*)ub;
  float* kvb  = (float*)(ub + qbufB);
  float* res  = (float*)(ub + qbufB + kvbB);
  if(o > ws_size) return;

  dim3 b256(256);
  k_score <<<dim3(BB*NN/4), b256, 0, stream>>>(x, score_w, score_b, score_d, keys);
  k_rank  <<<dim3(NN/256, BB), b256, 0, stream>>>(keys, score_d, order, ss_d, ss_f);
  k_gather<<<dim3((unsigned)((size_t)BB*NN*96/256)), b256, 0, stream>>>(x, order, xs);
  k_zero_d<<<dim3((BB*CC+255)/256), b256, 0, stream>>>(meanx, BB*CC);
  k_meanx <<<dim3(BB*16), dim3(CC), 0, stream>>>(x, meanx);
  k_scales<<<dim3(12), b256, 0, stream>>>(ss_d, rscale_w, rscale_b, scales);
  k_aggnum<<<dim3(1), dim3(64), 0, stream>>>(scales, aggnum, kknum, offs, numtot);
  k_weights<<<dim3(1), dim3(64), 0, stream>>>(meanx, route_w, route_b, wts, topk);
  k_zero  <<<dim3((BB*MAXTOT*CC+255)/256), b256, 0, stream>>>(agg, BB*MAXTOT*CC);
  k_init12<<<dim3(15), b256, 0, stream>>>(dmaxkey12, allw12);

  for(int g=0; g<12; g+=NB){
    int ng = (12-g < NB) ? (12-g) : NB;
    k_sumsq_all <<<dim3(N3/4, ng), b256, 0, stream>>>(xs, sumsq12, g);
    k_gram_all  <<<dim3(NTRI, ng), b256, 0, stream>>>(xs, sumsq12, dist_base, dmaxkey12, g);
    k_dmax_fix_all<<<dim3(ng), dim3(64), 0, stream>>>(dmaxkey12, xs, dmaxd12, g);
    k_knn_all   <<<dim3(N3/4, ng), b256, 0, stream>>>(dist_base, xs, kknum, dens12, g);
    k_dmin_all  <<<dim3(N3/4, ng), b256, 0, stream>>>(dist_base, xs, dens12, dmaxd12, scorec12, g);
    k_centers_all<<<dim3(N3/256, ng), b256, 0, stream>>>(scorec12, aggnum, centers12, g);
    k_assign_all<<<dim3(N3/256, ng), b256, 0, stream>>>(dist_base, xs, centers12, aggnum, idxc12, g);
    k_fixcenters_all<<<dim3(2, ng), b256, 0, stream>>>(centers12, aggnum, idxc12, g);
    k_allw_all  <<<dim3(N3/256, ng), b256, 0, stream>>>(idxc12, ss_f, allw12, g);
    k_scatter_all<<<dim3(N3*CC/256, ng), b256, 0, stream>>>(xs, idxc12, ss_f, allw12, agg, offs, g);
  }

  k_gemm128<<<dim3(BB*NN/128, CC/128), b256, 0, stream>>>(x, q_w, nullptr, qbuf, CC, CC);
  k_gemm_kv<<<dim3(MAXTOT/64, 768/64, BB*2), b256, 0, stream>>>(agg, kv_w, topk, kvb);
  k_attn   <<<dim3(NN/256, HH, BB), b256, 0, stream>>>(qbuf, kvb, numtot, wts, topk, res);
  k_gemm128<<<dim3(BB*NN/128, CC/128), b256, 0, stream>>>(res, proj_w, proj_b, out, CC, CC);
}

// Round 11
// 3707.459 us; speedup vs baseline: 7.4074x; 1.0283x over previous
//
#include <hip/hip_runtime.h>
#include <stdint.h>

#define BB 4
#define NN 9216
#define CC 384
#define HH 8
#define DH 48
#define EE 4
#define N3 3072
#define MAXTOT 960
#define NT3 24          // N3/128
#define NTRI 300        // NT3*(NT3+1)/2

typedef unsigned long long u64;
typedef float v2f __attribute__((ext_vector_type(2)));

__device__ __forceinline__ v2f make2(float a, float b){ v2f r; r.x=a; r.y=b; return r; }

// ---------------- wave helpers (wave64) ----------------
__device__ __forceinline__ float wave_sum(float v){
#pragma unroll
  for(int m=32;m>0;m>>=1) v += __shfl_xor(v,m,64);
  return v;
}
__device__ __forceinline__ double wave_sum_d(double v){
#pragma unroll
  for(int m=32;m>0;m>>=1) v += __shfl_xor(v,m,64);
  return v;
}
__device__ __forceinline__ u64 wave_min_u64(u64 k){
#pragma unroll
  for(int m=32;m>0;m>>=1){
    unsigned lo = __shfl_xor((unsigned)k, m, 64);
    unsigned hi = __shfl_xor((unsigned)(k>>32), m, 64);
    u64 o = ((u64)hi<<32)|lo;
    if(o < k) k = o;
  }
  return k;
}
__device__ __forceinline__ u64 wave_max_u64(u64 k){
#pragma unroll
  for(int m=32;m>0;m>>=1){
    unsigned lo = __shfl_xor((unsigned)k, m, 64);
    unsigned hi = __shfl_xor((unsigned)(k>>32), m, 64);
    u64 o = ((u64)hi<<32)|lo;
    if(o > k) k = o;
  }
  return k;
}

// exact f64 distance between token rows i,j of xr (f32 storage promoted)
__device__ double dist64(const float* __restrict__ xr, int i, int j){
  const float* a = xr + (size_t)i*CC;
  const float* b = xr + (size_t)j*CC;
  double s = 0.0;
  for(int c=0;c<CC;c++){
    double d = (double)a[c] - (double)b[c];
    s += d*d;
  }
  if(!(s > 0.0)) return 0.0;
  return sqrt(s) / 19.595917942265423;   // / sqrt(384), double
}

// ---------------- JAX threefry2x32 (20 rounds), bit-exact ----------------
__device__ __forceinline__ void threefry(uint32_t k0, uint32_t k1, uint32_t x0, uint32_t x1,
                                         uint32_t& o0, uint32_t& o1){
  const uint32_t ks0=k0, ks1=k1, ks2=k0^k1^0x1BD11BDAu;
  const int rotA[4]={13,15,26,6}, rotB[4]={17,29,16,24};
  x0 += ks0; x1 += ks1;
#pragma unroll
  for(int g=0; g<5; g++){
    const int* rot = (g&1)? rotB : rotA;
#pragma unroll
    for(int i=0;i<4;i++){
      x0 += x1;
      x1 = (x1<<rot[i])|(x1>>(32-rot[i]));
      x1 ^= x0;
    }
    uint32_t a = (g%3==0)?ks1:((g%3==1)?ks2:ks0);          // ks[(g+1)%3]
    uint32_t b = (g%3==0)?ks2:((g%3==1)?ks0:ks1);          // ks[(g+2)%3]
    x0 += a; x1 += b + (uint32_t)(g+1);
  }
  o0=x0; o1=x1;
}

// ---------------- score (f64) + sort keys ----------------
__global__ void k_score(const float* __restrict__ x, const float* __restrict__ sw,
                        const float* __restrict__ sb, double* __restrict__ score_d,
                        u64* __restrict__ keys){
  int row = blockIdx.x*4 + (threadIdx.x>>6);
  int lane = threadIdx.x & 63;
  const float* xr = x + (size_t)row*CC;
  double s = 0.0;
  for(int c=lane;c<CC;c+=64) s += (double)xr[c]*(double)sw[c];
  s = wave_sum_d(s);
  if(lane==0){
    double sc = exp(s + (double)sb[0]);    // > 0 -> double bits monotone
    score_d[row] = sc;
    keys[row] = (u64)__double_as_longlong(sc);
  }
}

// rank = stable-ascending position (score asc, index asc)
__global__ void k_rank(const u64* __restrict__ keys, const double* __restrict__ score_d,
                       int* __restrict__ order, double* __restrict__ ss_d,
                       float* __restrict__ ss_f){
  int b = blockIdx.y;
  int i = blockIdx.x*256 + threadIdx.x;
  __shared__ u64 tile[256];
  u64 ki = keys[(size_t)b*NN + i];
  int rank = 0;
  for(int j0=0;j0<NN;j0+=256){
    tile[threadIdx.x] = keys[(size_t)b*NN + j0 + threadIdx.x];
    __syncthreads();
#pragma unroll 8
    for(int jj=0;jj<256;jj++){
      u64 kj = tile[jj]; int j=j0+jj;
      rank += (kj < ki) || (kj == ki && j < i);
    }
    __syncthreads();
  }
  double sd = score_d[(size_t)b*NN + i];
  order[(size_t)b*NN + rank] = i;
  ss_d[(size_t)b*NN + rank] = sd;
  ss_f[(size_t)b*NN + rank] = (float)sd;
}

__global__ void k_gather(const float* __restrict__ x, const int* __restrict__ order,
                         float* __restrict__ xs){
  size_t idx = (size_t)blockIdx.x*256 + threadIdx.x;
  int c4 = (int)(idx % 96);
  size_t row = idx / 96;
  int b = (int)(row / NN);
  int src = order[row];
  ((float4*)xs)[row*96 + c4] = ((const float4*)x)[((size_t)b*NN + src)*96 + c4];
}

__global__ void k_zero(float* __restrict__ p, int n){
  int i = blockIdx.x*256 + threadIdx.x;
  if(i<n) p[i]=0.f;
}
__global__ void k_zero_d(double* __restrict__ p, int n){
  int i = blockIdx.x*256 + threadIdx.x;
  if(i<n) p[i]=0.0;
}

__global__ void k_meanx(const float* __restrict__ x, double* __restrict__ meanx){
  int b = blockIdx.x >> 4, chunk = blockIdx.x & 15;
  int c = threadIdx.x;   // 384 threads
  const float* base = x + ((size_t)b*NN + (size_t)chunk*576)*CC + c;
  double s=0.0;
  for(int n=0;n<576;n++) s += (double)base[(size_t)n*CC];
  atomicAdd(&meanx[b*CC+c], s);
}

__global__ void k_scales(const double* __restrict__ ss_d, const float* __restrict__ rw,
                         const float* __restrict__ rb, double* __restrict__ scales){
  int b = blockIdx.x/3, r = blockIdx.x%3;
  double s=0.0;
  for(int t=threadIdx.x;t<N3;t+=256) s += ss_d[(size_t)b*NN + r*N3 + t]*(double)rw[r*N3+t];
  __shared__ double red[4];
  s = wave_sum_d(s);
  if((threadIdx.x&63)==0) red[threadIdx.x>>6]=s;
  __syncthreads();
  if(threadIdx.x==0) scales[b*3+r] = red[0]+red[1]+red[2]+red[3] + (double)rb[r];
}

__global__ void k_aggnum(const double* __restrict__ scales, int* aggnum, int* kknum,
                         int* offs, int* numtot){
  int b = threadIdx.x;
  if(b >= BB) return;
  double s0=scales[b*3+0], s1=scales[b*3+1], s2=scales[b*3+2];
  double m = fmax(s0, fmax(s1,s2));
  double e0=exp(s0-m), e1=exp(s1-m), e2=exp(s2-m);
  double den=e0+e1+e2;
  int off=0;
  for(int r=0;r<3;r++){
    double e = (r==0)?e0:((r==1)?e1:e2);
    double v = 320.0*(e/den);
    v = fmin(fmax(v,16.0),320.0);
    int num=(int)v;                      // trunc toward 0, positive
    int kk=(int)sqrt((double)num);
    while((kk+1)*(kk+1)<=num) kk++;
    while(kk>1 && kk*kk>num) kk--;
    if(kk<1) kk=1;
    aggnum[b*3+r]=num; kknum[b*3+r]=kk; offs[b*3+r]=off; off+=num;
  }
  numtot[b]=off;
}

__global__ void k_weights(const double* __restrict__ meanx, const float* __restrict__ route_w,
                          const float* __restrict__ route_b, float* __restrict__ wts,
                          int* __restrict__ topk){
  __shared__ double wd[BB*EE];
  int t = threadIdx.x;
  if(t < BB*EE){
    int b=t/EE, e=t%EE;
    double s=0.0;
    for(int c=0;c<CC;c++) s += (meanx[b*CC+c]*(1.0/NN))*(double)route_w[e*CC+c];
    double w = 1.0/(1.0+exp(-(s+(double)route_b[e])));
    wd[t]=w;
    wts[t]=(float)w;
  }
  __syncthreads();
  if(t<BB){
    int b=t; int i1=0; double best=-1e300;
    for(int e=0;e<EE;e++){ double w=wd[b*EE+e]; if(w>best){best=w;i1=e;} }
    int i2=-1; double b2=-1e300;
    for(int e=0;e<EE;e++){ if(e==i1) continue; double w=wd[b*EE+e]; if(w>b2){b2=w;i2=e;} }
    topk[b*2]=i1; topk[b*2+1]=i2;
  }
}

// ---------------- small fp32 C = A * W^T (64 tile, guarded) ----------------
__device__ __forceinline__ void gemm_abt_tile(const float* __restrict__ A, const float* __restrict__ W,
    const float* __restrict__ bias, float* __restrict__ Cm,
    int M, int Nn, int K, int bx, int by){
  __shared__ float As[16][68];
  __shared__ float Ws[16][68];
  const int tx = threadIdx.x & 15, ty = threadIdx.x >> 4;
  const int tm = bx*64, tn = by*64;
  float acc[4][4];
#pragma unroll
  for(int i=0;i<4;i++)
#pragma unroll
    for(int j=0;j<4;j++) acc[i][j]=0.f;
  for(int k0=0;k0<K;k0+=16){
#pragma unroll
    for(int t=0;t<4;t++){
      int l = threadIdx.x + t*256;
      int r = l>>4, kk=l&15;
      int gm = tm+r;
      As[kk][r] = (gm<M)? A[(size_t)gm*K + k0+kk] : 0.f;
    }
#pragma unroll
    for(int t=0;t<4;t++){
      int l = threadIdx.x + t*256;
      int r=l>>4, kk=l&15;
      int gn = tn+r;
      Ws[kk][r] = (gn<Nn)? W[(size_t)gn*K + k0+kk] : 0.f;
    }
    __syncthreads();
#pragma unroll
    for(int kk=0;kk<16;kk++){
      float a0=As[kk][ty*4+0],a1=As[kk][ty*4+1],a2=As[kk][ty*4+2],a3=As[kk][ty*4+3];
      float b0=Ws[kk][tx*4+0],b1=Ws[kk][tx*4+1],b2=Ws[kk][tx*4+2],b3=Ws[kk][tx*4+3];
      acc[0][0]+=a0*b0; acc[0][1]+=a0*b1; acc[0][2]+=a0*b2; acc[0][3]+=a0*b3;
      acc[1][0]+=a1*b0; acc[1][1]+=a1*b1; acc[1][2]+=a1*b2; acc[1][3]+=a1*b3;
      acc[2][0]+=a2*b0; acc[2][1]+=a2*b1; acc[2][2]+=a2*b2; acc[2][3]+=a2*b3;
      acc[3][0]+=a3*b0; acc[3][1]+=a3*b1; acc[3][2]+=a3*b2; acc[3][3]+=a3*b3;
    }
    __syncthreads();
  }
#pragma unroll
  for(int i=0;i<4;i++){
    int gm=tm+ty*4+i; if(gm>=M) continue;
#pragma unroll
    for(int j=0;j<4;j++){
      int gn=tn+tx*4+j; if(gn>=Nn) continue;
      float v=acc[i][j];
      if(bias) v += bias[gn];
      Cm[(size_t)gm*Nn+gn]=v;
    }
  }
}

__global__ __launch_bounds__(256, 2)
void k_gemm_kv(const float* __restrict__ agg, const float* __restrict__ kv_w,
               const int* __restrict__ topk, float* __restrict__ kvb){
  int z = blockIdx.z;                  // b*2+j
  int e = topk[z];
  gemm_abt_tile(agg + (size_t)(z>>1)*MAXTOT*CC, kv_w + (size_t)e*768*CC, nullptr,
                kvb + (size_t)z*MAXTOT*768, MAXTOT, 768, CC, blockIdx.x, blockIdx.y);
}

// ---------------- big fp32 GEMM: 128x128 tile, dims must be multiples ----------------
__global__ __launch_bounds__(256, 2)
void k_gemm128(const float* __restrict__ A, const float* __restrict__ W,
               const float* __restrict__ bias, float* __restrict__ Cm,
               int Nn, int K){
  __shared__ float As[16][132];
  __shared__ float Ws[16][132];
  const int tx = threadIdx.x & 15, ty = threadIdx.x >> 4;
  const int tm = blockIdx.x*128, tn = blockIdx.y*128;
  const int lrow = threadIdx.x >> 1;
  const int lk = (threadIdx.x & 1)*8;
  float acc[8][8];
#pragma unroll
  for(int i=0;i<8;i++)
#pragma unroll
    for(int j=0;j<8;j++) acc[i][j]=0.f;
  for(int k0=0;k0<K;k0+=16){
    float4 a0 = *(const float4*)(A + (size_t)(tm+lrow)*K + k0+lk);
    float4 a1 = *(const float4*)(A + (size_t)(tm+lrow)*K + k0+lk+4);
    float4 b0 = *(const float4*)(W + (size_t)(tn+lrow)*K + k0+lk);
    float4 b1 = *(const float4*)(W + (size_t)(tn+lrow)*K + k0+lk+4);
    __syncthreads();
    As[lk+0][lrow]=a0.x; As[lk+1][lrow]=a0.y; As[lk+2][lrow]=a0.z; As[lk+3][lrow]=a0.w;
    As[lk+4][lrow]=a1.x; As[lk+5][lrow]=a1.y; As[lk+6][lrow]=a1.z; As[lk+7][lrow]=a1.w;
    Ws[lk+0][lrow]=b0.x; Ws[lk+1][lrow]=b0.y; Ws[lk+2][lrow]=b0.z; Ws[lk+3][lrow]=b0.w;
    Ws[lk+4][lrow]=b1.x; Ws[lk+5][lrow]=b1.y; Ws[lk+6][lrow]=b1.z; Ws[lk+7][lrow]=b1.w;
    __syncthreads();
#pragma unroll
    for(int kk=0;kk<16;kk++){
      float a[8], b[8];
#pragma unroll
      for(int i=0;i<8;i++) a[i]=As[kk][ty*8+i];
#pragma unroll
      for(int j=0;j<8;j++) b[j]=Ws[kk][tx*8+j];
#pragma unroll
      for(int i=0;i<8;i++)
#pragma unroll
        for(int j=0;j<8;j++) acc[i][j]+=a[i]*b[j];
    }
  }
  float bs[8];
#pragma unroll
  for(int j=0;j<8;j++) bs[j] = bias? bias[tn+tx*8+j] : 0.f;
#pragma unroll
  for(int i=0;i<8;i++){
    int gm = tm+ty*8+i;
    float* cp = Cm + (size_t)gm*Nn + tn + tx*8;
    *(float4*)(cp)   = make_float4(acc[i][0]+bs[0],acc[i][1]+bs[1],acc[i][2]+bs[2],acc[i][3]+bs[3]);
    *(float4*)(cp+4) = make_float4(acc[i][4]+bs[4],acc[i][5]+bs[5],acc[i][6]+bs[6],acc[i][7]+bs[7]);
  }
}

// ---------------- batched clustering ----------------
__global__ void k_init12(u64* __restrict__ dmaxkey12, float* __restrict__ allw12){
  int t = blockIdx.x*256 + threadIdx.x;
  if(t < 12) dmaxkey12[t] = 0ull;
  if(t < 12*320) allw12[t] = 0.f;
}

__global__ void k_sumsq_all(const float* __restrict__ xs, float* __restrict__ sumsq12, int fi0){
  int fi = fi0 + blockIdx.y;
  int row = blockIdx.x*4 + (threadIdx.x>>6);
  int lane = threadIdx.x & 63;
  const float* p = xs + (size_t)fi*N3*CC + (size_t)row*CC;
  float s=0.f;
  for(int c=lane;c<CC;c+=64){ float v=p[c]; s+=v*v; }
  s = wave_sum(s);
  if(lane==0) sumsq12[(size_t)fi*N3 + row]=s;
}

// fused symmetric Gram -> distance; upper-triangular 128-blocks, mirrored writes.
// Accumulation over k in the same order as before -> dist values bit-identical.
__global__ __launch_bounds__(256, 2)
void k_gram_all(const float* __restrict__ xs, const float* __restrict__ sumsq12,
                float* __restrict__ dist_base, u64* __restrict__ dmaxkey12, int fi0){
  const int fiL = blockIdx.y, fi = fi0 + fiL;
  const float* xr = xs + (size_t)fi*N3*CC;
  const float* sq = sumsq12 + (size_t)fi*N3;
  float* dist = dist_base + (size_t)fiL*N3*N3;
  int t = blockIdx.x, bi = 0;
  while(t >= NT3 - bi){ t -= NT3 - bi; bi++; }
  const int bj = bi + t;
  const int tm = bi*128, tn = bj*128;
  __shared__ float As[16][132];
  __shared__ float Ws[16][132];
  const int tx = threadIdx.x & 15, ty = threadIdx.x >> 4;
  const int lrow = threadIdx.x >> 1;
  const int lk = (threadIdx.x & 1)*8;
  float acc[8][8];
#pragma unroll
  for(int i=0;i<8;i++)
#pragma unroll
    for(int j=0;j<8;j++) acc[i][j]=0.f;
  for(int k0=0;k0<CC;k0+=16){
    float4 a0 = *(const float4*)(xr + (size_t)(tm+lrow)*CC + k0+lk);
    float4 a1 = *(const float4*)(xr + (size_t)(tm+lrow)*CC + k0+lk+4);
    float4 b0 = *(const float4*)(xr + (size_t)(tn+lrow)*CC + k0+lk);
    float4 b1 = *(const float4*)(xr + (size_t)(tn+lrow)*CC + k0+lk+4);
    __syncthreads();
    As[lk+0][lrow]=a0.x; As[lk+1][lrow]=a0.y; As[lk+2][lrow]=a0.z; As[lk+3][lrow]=a0.w;
    As[lk+4][lrow]=a1.x; As[lk+5][lrow]=a1.y; As[lk+6][lrow]=a1.z; As[lk+7][lrow]=a1.w;
    Ws[lk+0][lrow]=b0.x; Ws[lk+1][lrow]=b0.y; Ws[lk+2][lrow]=b0.z; Ws[lk+3][lrow]=b0.w;
    Ws[lk+4][lrow]=b1.x; Ws[lk+5][lrow]=b1.y; Ws[lk+6][lrow]=b1.z; Ws[lk+7][lrow]=b1.w;
    __syncthreads();
#pragma unroll
    for(int kk=0;kk<16;kk++){
      float a[8], b[8];
#pragma unroll
      for(int i=0;i<8;i++) a[i]=As[kk][ty*8+i];
#pragma unroll
      for(int j=0;j<8;j++) b[j]=Ws[kk][tx*8+j];
#pragma unroll
      for(int i=0;i<8;i++)
#pragma unroll
        for(int j=0;j<8;j++) acc[i][j]+=a[i]*b[j];
    }
  }
  u64 best = 0ull;
  float sqn[8];
#pragma unroll
  for(int j=0;j<8;j++) sqn[j] = sq[tn+tx*8+j];
#pragma unroll
  for(int i=0;i<8;i++){
    int gm = tm+ty*8+i;
    float sqm = sq[gm];
    float row[8];
#pragma unroll
    for(int j=0;j<8;j++){
      int gn = tn+tx*8+j;
      float d2 = (sqm + sqn[j]) - 2.f*acc[i][j];
      d2 = fmaxf(d2, 0.f);
      float dv = (d2 > 0.f) ? (sqrtf(d2) / 19.595917942265423f) : 0.f;
      row[j]=dv;
      unsigned u1=(unsigned)(gm*N3+gn), u2=(unsigned)(gn*N3+gm);
      u64 key = (((u64)__float_as_uint(dv))<<32) | (u1>u2?u1:u2);
      if(key > best) best = key;
    }
    float* dp = dist + (size_t)gm*N3 + tn + tx*8;
    *(float4*)(dp)   = make_float4(row[0],row[1],row[2],row[3]);
    *(float4*)(dp+4) = make_float4(row[4],row[5],row[6],row[7]);
  }
  if(bi != bj){
#pragma unroll
    for(int j=0;j<8;j++){
      int gn = tn+tx*8+j;
      float col[8];
#pragma unroll
      for(int i=0;i<8;i++){
        float d2 = (sq[tm+ty*8+i] + sqn[j]) - 2.f*acc[i][j];
        d2 = fmaxf(d2, 0.f);
        col[i] = (d2 > 0.f) ? (sqrtf(d2) / 19.595917942265423f) : 0.f;
      }
      float* dp = dist + (size_t)gn*N3 + tm + ty*8;
      *(float4*)(dp)   = make_float4(col[0],col[1],col[2],col[3]);
      *(float4*)(dp+4) = make_float4(col[4],col[5],col[6],col[7]);
    }
  }
  best = wave_max_u64(best);
  __shared__ u64 red[4];
  if((threadIdx.x&63)==0) red[threadIdx.x>>6]=best;
  __syncthreads();
  if(threadIdx.x==0){
    u64 m = red[0];
    if(red[1]>m) m=red[1];
    if(red[2]>m) m=red[2];
    if(red[3]>m) m=red[3];
    atomicMax(&dmaxkey12[fi], m);
  }
}

__global__ void k_dmax_fix_all(const u64* __restrict__ dmaxkey12, const float* __restrict__ xs,
                               double* __restrict__ dmaxd12, int fi0){
  if(threadIdx.x!=0) return;
  int fi = fi0 + blockIdx.x;
  unsigned pair = (unsigned)(dmaxkey12[fi] & 0xFFFFFFFFull);
  int i = pair / N3, j = pair % N3;
  dmaxd12[fi] = dist64(xs + (size_t)fi*N3*CC, i, j);
}

// wave per row: kk-NN via f32 keys, exact f64 recompute of selected distances
__global__ __launch_bounds__(256, 2)
void k_knn_all(const float* __restrict__ dist_base, const float* __restrict__ xs,
               const int* __restrict__ kknum, double* __restrict__ dens12, int fi0){
  const int fiL = blockIdx.y, fi = fi0 + fiL;
  const float* xr = xs + (size_t)fi*N3*CC;
  const float* dist = dist_base + (size_t)fiL*N3*N3;
  int row = blockIdx.x*4 + (threadIdx.x>>6);
  int lane = threadIdx.x & 63;
  int kk = kknum[fi];
  const float* dr = dist + (size_t)row*N3;
  u64 loc[17];
#pragma unroll
  for(int i=0;i<17;i++) loc[i]=~0ull;
  for(int j=lane;j<N3;j+=64){
    u64 key = (((u64)__float_as_uint(dr[j]))<<32) | (unsigned)j;
    if(key < loc[16]){
      u64 cur=key;
#pragma unroll
      for(int p=0;p<17;p++){
        u64 old=loc[p];
        bool ins = cur<old;
        loc[p] = ins?cur:old;
        cur    = ins?old:cur;
      }
    }
  }
  int myj = -1;
  for(int it=0; it<kk; it++){
    u64 k = wave_min_u64(loc[0]);
    int owner = (int)(k & 63u);          // j was loaded by lane j%64
    if(lane==owner){
#pragma unroll
      for(int p=0;p<16;p++) loc[p]=loc[p+1];
      loc[16]=~0ull;
    }
    if(it==lane) myj = (int)(k & 0xFFFFFFFFull);
  }
  double nd2 = 0.0;
  if(lane < kk && myj >= 0){
    double dd = dist64(xr, row, myj);
    nd2 = dd*dd;
  }
  double ssum = wave_sum_d(nd2);
  if(lane==0){
    double mean = ssum/(double)kk;
    double d = exp(-mean);
    // modern JAX (jax_threefry_partitionable=True): bits[i] = o0 ^ o1,
    // (o0,o1) = threefry(fold_in(key(42), fi), (0, i))
    uint32_t k0,k1,o0,o1;
    threefry(0u,42u, 0u,(uint32_t)fi, k0,k1);
    threefry(k0,k1, 0u,(uint32_t)row, o0,o1);
    uint32_t bits = o0 ^ o1;
    float u = __uint_as_float((bits>>9)|0x3F800000u) - 1.0f;
    dens12[(size_t)fi*N3 + row] = d + (double)u*1e-6;
  }
}

__global__ void k_dmin_all(const float* __restrict__ dist_base, const float* __restrict__ xs,
                           const double* __restrict__ dens12, const double* __restrict__ dmaxd12,
                           double* __restrict__ scorec12, int fi0){
  const int fiL = blockIdx.y, fi = fi0 + fiL;
  const float* xr = xs + (size_t)fi*N3*CC;
  const float* dist = dist_base + (size_t)fiL*N3*N3;
  const double* dens = dens12 + (size_t)fi*N3;
  int row = blockIdx.x*4+(threadIdx.x>>6);
  int lane = threadIdx.x & 63;
  double di = dens[row];
  const float* dr = dist + (size_t)row*N3;
  u64 best = ~0ull;
  for(int j=lane;j<N3;j+=64){
    if(dens[j] > di){
      u64 key = (((u64)__float_as_uint(dr[j]))<<32) | (unsigned)j;
      if(key < best) best = key;
    }
  }
  best = wave_min_u64(best);
  if(lane==0){
    double dm;
    if(best == ~0ull) dm = dmaxd12[fi];
    else dm = dist64(xr, row, (int)(best & 0xFFFFFFFFull));
    scorec12[(size_t)fi*N3 + row] = dm*di;
  }
}

// rank among scores (desc, tie -> lower index) == lax.top_k order
__global__ void k_centers_all(const double* __restrict__ scorec12, const int* __restrict__ aggnum,
                              int* __restrict__ centers12, int fi0){
  const int fi = fi0 + blockIdx.y;
  const double* scorec = scorec12 + (size_t)fi*N3;
  int t = blockIdx.x*256+threadIdx.x;
  int num = aggnum[fi];
  double si = scorec[t];
  __shared__ double tile[256];
  int rank=0;
  for(int j0=0;j0<N3;j0+=256){
    tile[threadIdx.x]=scorec[j0+threadIdx.x];
    __syncthreads();
#pragma unroll 8
    for(int jj=0;jj<256;jj++){
      double sj=tile[jj]; int j=j0+jj;
      rank += (sj>si) || (sj==si && j<t);
    }
    __syncthreads();
  }
  if(rank<num) centers12[fi*320 + rank]=t;
}

__global__ void k_assign_all(const float* __restrict__ dist_base, const float* __restrict__ xs,
                             const int* __restrict__ centers12, const int* __restrict__ aggnum,
                             int* __restrict__ idxc12, int fi0){
  const int fiL = blockIdx.y, fi = fi0 + fiL;
  const float* xr = xs + (size_t)fi*N3*CC;
  const float* dist = dist_base + (size_t)fiL*N3*N3;
  const int* centers = centers12 + fi*320;
  int t = blockIdx.x*256+threadIdx.x;
  int num = aggnum[fi];
  float bd=3.4e38f; int bc=0;
  float rd=3.4e38f; int rc=-1;
  for(int c=0;c<num;c++){
    float v = dist[(size_t)centers[c]*N3 + t];
    if(v<bd){ rd=bd; rc=bc; bd=v; bc=c; }
    else if(v<rd){ rd=v; rc=c; }
  }
  // f64 refine: compare best vs runner-up exactly (argmin-first semantics)
  if(rc>=0 && (rd-bd) < 1e-3f){
    double d1 = dist64(xr, centers[bc], t);
    double d2 = dist64(xr, centers[rc], t);
    if(d2 < d1 || (d2==d1 && rc<bc)) bc = rc;
  }
  idxc12[(size_t)fi*N3 + t]=bc;
}

__global__ void k_fixcenters_all(const int* __restrict__ centers12, const int* __restrict__ aggnum,
                                 int* __restrict__ idxc12, int fi0){
  const int fi = fi0 + blockIdx.y;
  int c = blockIdx.x*256+threadIdx.x;
  if(c < aggnum[fi]) idxc12[(size_t)fi*N3 + centers12[fi*320 + c]]=c;
}

__global__ void k_allw_all(const int* __restrict__ idxc12, const float* __restrict__ ss_f,
                           float* __restrict__ allw12, int fi0){
  const int fi = fi0 + blockIdx.y;
  int t = blockIdx.x*256+threadIdx.x;
  atomicAdd(&allw12[fi*320 + idxc12[(size_t)fi*N3 + t]], ss_f[(size_t)fi*N3 + t]);
}

__global__ void k_scatter_all(const float* __restrict__ xs, const int* __restrict__ idxc12,
                              const float* __restrict__ ss_f, const float* __restrict__ allw12,
                              float* __restrict__ agg, const int* __restrict__ offs, int fi0){
  const int fi = fi0 + blockIdx.y;
  int idx = blockIdx.x*256+threadIdx.x;
  int t = idx / CC, c = idx % CC;
  int cl = idxc12[(size_t)fi*N3 + t];
  float wgt = ss_f[(size_t)fi*N3 + t]/(allw12[fi*320 + cl]+1e-6f);
  float* aggb = agg + (size_t)(fi/3)*MAXTOT*CC;
  atomicAdd(&aggb[(size_t)(offs[fi] + cl)*CC + c], xs[(size_t)fi*N3*CC + idx]*wgt);
}

// ---------------- attention v3: 2 lanes per query (d-halves), tiny register state ----------------
// r9 lesson: 96+ live floats/thread -> allocator parks state in AGPRs (VGPR=64, accvgpr
// shuffling, occupancy 32%, VALUBusy 59%). v3 halves per-thread state: lane pair (2n,2n+1)
// handles d[0,24)/d[24,48) of one query; QK dot joined by one shfl_xor (bitwise-commutative
// add -> identical s in both lanes, no divergence). ~55 live regs -> genuine 64-VGPR fit.
__global__ __launch_bounds__(256, 4)
void k_attn(const float* __restrict__ q, const float* __restrict__ kv,
            const int* __restrict__ numtot, const float* __restrict__ wts,
            const int* __restrict__ topk, float* __restrict__ res){
  int b = blockIdx.z, h = blockIdx.y;
  int qloc = threadIdx.x >> 1;
  int half = threadIdx.x & 1;
  int n = blockIdx.x*128 + qloc;
  int ntot = numtot[b];
  __shared__ float4 kt4[64][12];
  __shared__ float4 vt4[64][12];
  v2f qv[12];
  const float* qp = q + ((size_t)b*NN + n)*CC + h*DH + half*24;
#pragma unroll
  for(int d=0;d<12;d++) qv[d] = make2(qp[2*d], qp[2*d+1]);
  const float sc = 0.14433756729740643f;   // 48^-0.5
  float* rp = res + ((size_t)b*NN + n)*CC + h*DH + half*24;
  for(int j=0;j<2;j++){
    const float* kvb = kv + (size_t)(b*2+j)*MAXTOT*768;
    float wexp = wts[b*EE + topk[b*2+j]];
    float mrun=-3.4e38f, lrun=0.f;
    v2f acc[12];
#pragma unroll
    for(int d=0;d<12;d++) acc[d]=make2(0.f,0.f);
    for(int m0=0;m0<ntot;m0+=64){
      __syncthreads();
      for(int l=threadIdx.x;l<768;l+=256){
        int mm=l/12, d4=l%12;
        int m=m0+mm;
        float4 kf=make_float4(0,0,0,0), vf=make_float4(0,0,0,0);
        if(m<ntot){
          kf = *(const float4*)(kvb + (size_t)m*768 + h*DH + 4*d4);
          vf = *(const float4*)(kvb + (size_t)m*768 + 384 + h*DH + 4*d4);
        }
        kt4[mm][d4]=kf; vt4[mm][d4]=vf;
      }
      __syncthreads();
      int mcnt = min(64, ntot-m0);
      for(int mm=0;mm<mcnt;mm++){
        // 24-dim half-dot: 2 independent v2f chains (6 deep), then pair-join via shfl
        v2f p0=make2(0.f,0.f), p1=make2(0.f,0.f);
#pragma unroll
        for(int t=0;t<6;t++){
          float4 kf = kt4[mm][half*6+t];
          p0 += make2(kf.x,kf.y)*qv[2*t];
          p1 += make2(kf.z,kf.w)*qv[2*t+1];
        }
        v2f pt = p0+p1;
        float sh = pt.x+pt.y;
        float s = (sh + __shfl_xor(sh,1,64))*sc;   // a+b bitwise == b+a -> pair-identical
        if(s > mrun){
          float rs = __expf(mrun - s);
          lrun *= rs;
          v2f rv = make2(rs,rs);
#pragma unroll
          for(int d=0;d<12;d++) acc[d]*=rv;
          mrun = s;
        }
        float p = __expf(s - mrun);
        lrun += p;
        v2f pv = make2(p,p);
#pragma unroll
        for(int t=0;t<6;t++){
          float4 vf = vt4[mm][half*6+t];
          acc[2*t]   += make2(vf.x,vf.y)*pv;
          acc[2*t+1] += make2(vf.z,vf.w)*pv;
        }
      }
    }
    float inv = wexp/lrun;
    if(j==0){
#pragma unroll
      for(int d=0;d<12;d++){ rp[2*d]=acc[d].x*inv; rp[2*d+1]=acc[d].y*inv; }
    }else{
#pragma unroll
      for(int d=0;d<12;d++){ rp[2*d]+=acc[d].x*inv; rp[2*d+1]+=acc[d].y*inv; }
    }
  }
}

// ---------------- host ----------------
extern "C" void kernel_launch(void* const* d_in, const int* in_sizes, int n_in,
                              void* d_out, int out_size, void* d_ws, size_t ws_size,
                              hipStream_t stream){
  (void)in_sizes; (void)n_in; (void)out_size;
  const float* x       = (const float*)d_in[0];
  const float* q_w     = (const float*)d_in[1];
  const float* kv_w    = (const float*)d_in[2];
  const float* route_w = (const float*)d_in[3];
  const float* route_b = (const float*)d_in[4];
  const float* score_w = (const float*)d_in[5];
  const float* score_b = (const float*)d_in[6];
  const float* rscale_w= (const float*)d_in[7];
  const float* rscale_b= (const float*)d_in[8];
  const float* proj_w  = (const float*)d_in[9];
  const float* proj_b  = (const float*)d_in[10];
  float* out = (float*)d_out;

  char* w = (char*)d_ws;
  size_t o = 0;
  auto carve = [&](size_t bytes)->char*{
    char* p = w + o;
    o += (bytes + 255) & ~(size_t)255;
    return p;
  };
  double* score_d = (double*)carve((size_t)BB*NN*8);
  u64*   keys    = (u64*)carve((size_t)BB*NN*8);
  int*   order   = (int*)carve((size_t)BB*NN*4);
  double* ss_d   = (double*)carve((size_t)BB*NN*8);
  float* ss_f    = (float*)carve((size_t)BB*NN*4);
  double* meanx  = (double*)carve((size_t)BB*CC*8);
  double* scales = (double*)carve(12*8);
  int*   aggnum  = (int*)carve(12*4);
  int*   kknum   = (int*)carve(12*4);
  int*   offs    = (int*)carve(12*4);
  int*   numtot  = (int*)carve(BB*4);
  float* wts     = (float*)carve(BB*EE*4);
  int*   topk    = (int*)carve(BB*2*4);
  u64*   dmaxkey12 = (u64*)carve(12*8);
  double* dmaxd12  = (double*)carve(12*8);
  float* sumsq12   = (float*)carve((size_t)12*N3*4);
  double* dens12   = (double*)carve((size_t)12*N3*8);
  double* scorec12 = (double*)carve((size_t)12*N3*8);
  int*   centers12 = (int*)carve((size_t)12*320*4);
  int*   idxc12    = (int*)carve((size_t)12*N3*4);
  float* allw12    = (float*)carve((size_t)12*320*4);
  float* xs      = (float*)carve((size_t)BB*NN*CC*4);
  float* agg     = (float*)carve((size_t)BB*MAXTOT*CC*4);

  // union region: dist[NB] during clustering, then qbuf+kvb+res afterwards
  const size_t distB = (size_t)N3*N3*4;                 // 37,748,736
  const size_t qbufB = (size_t)BB*NN*CC*4;              // 56,623,104
  const size_t kvbB  = (size_t)BB*2*MAXTOT*768*4;       // 23,592,960
  const size_t resB  = qbufB;
  const size_t tailB = qbufB + kvbB + resB;
  size_t avail = (ws_size > o) ? (ws_size - o) : 0;
  if(avail < tailB) return;                             // workspace too small -> visible failure
  int NB = (int)(avail / distB); if(NB > 12) NB = 12;   // avail>=tailB => NB>=3
  size_t uB = (size_t)NB*distB; if(uB < tailB) uB = tailB;
  char* ub = carve(uB);
  float* dist_base = (float*)ub;
  float* qbuf = (float*)ub;
  float* kvb  = (float*)(ub + qbufB);
  float* res  = (float*)(ub + qbufB + kvbB);
  if(o > ws_size) return;

  dim3 b256(256);
  k_score <<<dim3(BB*NN/4), b256, 0, stream>>>(x, score_w, score_b, score_d, keys);
  k_rank  <<<dim3(NN/256, BB), b256, 0, stream>>>(keys, score_d, order, ss_d, ss_f);
  k_gather<<<dim3((unsigned)((size_t)BB*NN*96/256)), b256, 0, stream>>>(x, order, xs);
  k_zero_d<<<dim3((BB*CC+255)/256), b256, 0, stream>>>(meanx, BB*CC);
  k_meanx <<<dim3(BB*16), dim3(CC), 0, stream>>>(x, meanx);
  k_scales<<<dim3(12), b256, 0, stream>>>(ss_d, rscale_w, rscale_b, scales);
  k_aggnum<<<dim3(1), dim3(64), 0, stream>>>(scales, aggnum, kknum, offs, numtot);
  k_weights<<<dim3(1), dim3(64), 0, stream>>>(meanx, route_w, route_b, wts, topk);
  k_zero  <<<dim3((BB*MAXTOT*CC+255)/256), b256, 0, stream>>>(agg, BB*MAXTOT*CC);
  k_init12<<<dim3(15), b256, 0, stream>>>(dmaxkey12, allw12);

  for(int g=0; g<12; g+=NB){
    int ng = (12-g < NB) ? (12-g) : NB;
    k_sumsq_all <<<dim3(N3/4, ng), b256, 0, stream>>>(xs, sumsq12, g);
    k_gram_all  <<<dim3(NTRI, ng), b256, 0, stream>>>(xs, sumsq12, dist_base, dmaxkey12, g);
    k_dmax_fix_all<<<dim3(ng), dim3(64), 0, stream>>>(dmaxkey12, xs, dmaxd12, g);
    k_knn_all   <<<dim3(N3/4, ng), b256, 0, stream>>>(dist_base, xs, kknum, dens12, g);
    k_dmin_all  <<<dim3(N3/4, ng), b256, 0, stream>>>(dist_base, xs, dens12, dmaxd12, scorec12, g);
    k_centers_all<<<dim3(N3/256, ng), b256, 0, stream>>>(scorec12, aggnum, centers12, g);
    k_assign_all<<<dim3(N3/256, ng), b256, 0, stream>>>(dist_base, xs, centers12, aggnum, idxc12, g);
    k_fixcenters_all<<<dim3(2, ng), b256, 0, stream>>>(centers12, aggnum, idxc12, g);
    k_allw_all  <<<dim3(N3/256, ng), b256, 0, stream>>>(idxc12, ss_f, allw12, g);
    k_scatter_all<<<dim3(N3*CC/256, ng), b256, 0, stream>>>(xs, idxc12, ss_f, allw12, agg, offs, g);
  }

  k_gemm128<<<dim3(BB*NN/128, CC/128), b256, 0, stream>>>(x, q_w, nullptr, qbuf, CC, CC);
  k_gemm_kv<<<dim3(MAXTOT/64, 768/64, BB*2), b256, 0, stream>>>(agg, kv_w, topk, kvb);
  k_attn   <<<dim3(NN/128, HH, BB), b256, 0, stream>>>(qbuf, kvb, numtot, wts, topk, res);
  k_gemm128<<<dim3(BB*NN/128, CC/128), b256, 0, stream>>>(res, proj_w, proj_b, out, CC, CC);
}